// Round 2
// baseline (570.323 us; speedup 1.0000x reference)
//
#include <hip/hip_runtime.h>
#include <hip/hip_bf16.h>

using bf16 = __hip_bfloat16;
typedef float f32;

static __device__ __forceinline__ f32 b2f(bf16 v){ return __bfloat162float(v); }
static __device__ __forceinline__ f32 siluf(f32 v){ return v / (1.f + __expf(-v)); }

// spatial position of sequence index p for scan direction dir (H=W=64, L=4096)
static __device__ __forceinline__ int pos_of(int dir, int p){
  if(dir==0) return p;
  if(dir==1) return ((p&63)<<6) | (p>>6);
  if(dir==2) return 4095-p;
  int q = 4095-p; return ((q&63)<<6) | (q>>6);
}

// ---------------- Kernel A: xz = x @ in_proj_w.T ; split -> xh_raw, z=silu ----
// M=32768, K=96, N=384. BM=64,BN=64,BK=32, 256 thr, 4x4 micro.
__global__ __launch_bounds__(256) void k_inproj(const f32* __restrict__ x, const f32* __restrict__ w,
                                                f32* __restrict__ xh_raw, f32* __restrict__ z){
  __shared__ f32 As[32][68];
  __shared__ f32 Bs[32][68];
  const int m0=blockIdx.x*64, n0=blockIdx.y*64;
  const int tid=threadIdx.x, tx=tid&15, ty=tid>>4;
  f32 acc[4][4]={};
  for(int k0=0;k0<96;k0+=32){
    for(int i=tid;i<2048;i+=256){int r=i>>5,kk=i&31; As[kk][r]=x[(size_t)(m0+r)*96+k0+kk]; }
    for(int i=tid;i<2048;i+=256){int r=i>>5,kk=i&31; Bs[kk][r]=w[(size_t)(n0+r)*96+k0+kk]; }
    __syncthreads();
    #pragma unroll
    for(int kk=0;kk<32;kk++){
      float4 a4=*(float4*)&As[kk][ty*4];
      float4 b4=*(float4*)&Bs[kk][tx*4];
      f32 a[4]={a4.x,a4.y,a4.z,a4.w}, b[4]={b4.x,b4.y,b4.z,b4.w};
      #pragma unroll
      for(int i=0;i<4;i++)
        #pragma unroll
        for(int j=0;j<4;j++) acc[i][j]+=a[i]*b[j];
    }
    __syncthreads();
  }
  #pragma unroll
  for(int i=0;i<4;i++){
    int row=m0+ty*4+i;
    #pragma unroll
    for(int j=0;j<4;j++){
      int col=n0+tx*4+j; f32 v=acc[i][j];
      if(col<192) xh_raw[(size_t)row*192+col]=v;
      else        z[(size_t)row*192+(col-192)]=siluf(v);
    }
  }
}

// ---------------- Kernel B: depthwise 3x3 conv + bias + silu --------------------
__global__ __launch_bounds__(256) void k_conv(const f32* __restrict__ xh_raw, const f32* __restrict__ cw,
                                              const f32* __restrict__ cb, f32* __restrict__ xh){
  __shared__ f32 wsm[192][9];
  __shared__ f32 bsm[192];
  const int tid=threadIdx.x;
  for(int i=tid;i<1728;i+=256) wsm[i/9][i%9]=cw[i];
  for(int i=tid;i<192;i+=256) bsm[i]=cb[i];
  __syncthreads();
  const int idx=blockIdx.x*256+tid;          // (b, i, j, c4), c4 fastest, 48 per pixel
  const int c4=idx%48, j=(idx/48)&63, ii0=(idx/3072)&63, b=idx/196608;
  const int c0=c4*4;
  f32 acc[4]={bsm[c0],bsm[c0+1],bsm[c0+2],bsm[c0+3]};
  #pragma unroll
  for(int a=0;a<3;a++){
    int ii=ii0+a-1; if(ii<0||ii>63) continue;
    #pragma unroll
    for(int bb=0;bb<3;bb++){
      int jj=j+bb-1; if(jj<0||jj>63) continue;
      float4 v=*(const float4*)&xh_raw[((size_t)(b*4096)+(ii*64+jj))*192 + c0];
      int t=a*3+bb;
      acc[0]+=v.x*wsm[c0][t]; acc[1]+=v.y*wsm[c0+1][t];
      acc[2]+=v.z*wsm[c0+2][t]; acc[3]+=v.w*wsm[c0+3][t];
    }
  }
  float4 o; o.x=siluf(acc[0]); o.y=siluf(acc[1]); o.z=siluf(acc[2]); o.w=siluf(acc[3]);
  ((float4*)xh)[idx]=o;
}

// ---------------- Kernel C: x_dbl = xs @ x_proj_w[k].T -> dt(softplus), B, C ----
// per (b, dir): M=4096, K=192, N=38 (padded 48). 192 thr (16x12), 4x4 micro.
__global__ __launch_bounds__(192) void k_xdbl(const f32* __restrict__ xh, const f32* __restrict__ xpw,
                                              const f32* __restrict__ dtb, f32* __restrict__ dt_sp,
                                              f32* __restrict__ Bg, f32* __restrict__ Cg){
  __shared__ f32 As[32][68];
  __shared__ f32 Ws[32][52];
  const int p0=blockIdx.x*64, dir=blockIdx.y, b=blockIdx.z;
  const int tid=threadIdx.x, tx=tid%12, ty=tid/12;
  f32 acc[4][4]={};
  for(int k0=0;k0<192;k0+=32){
    for(int i=tid;i<2048;i+=192){int r=i>>5,kk=i&31; As[kk][r]=xh[(size_t)(b*4096+pos_of(dir,p0+r))*192+k0+kk]; }
    for(int i=tid;i<1536;i+=192){int c=i>>5,kk=i&31; Ws[kk][c]=(c<38)? xpw[(size_t)dir*7296+c*192+k0+kk] : 0.f; }
    __syncthreads();
    #pragma unroll
    for(int kk=0;kk<32;kk++){
      float4 a4=*(float4*)&As[kk][ty*4];
      float4 b4=*(float4*)&Ws[kk][tx*4];
      f32 a[4]={a4.x,a4.y,a4.z,a4.w}, bb[4]={b4.x,b4.y,b4.z,b4.w};
      #pragma unroll
      for(int i=0;i<4;i++)
        #pragma unroll
        for(int j=0;j<4;j++) acc[i][j]+=a[i]*bb[j];
    }
    __syncthreads();
  }
  #pragma unroll
  for(int i=0;i<4;i++){
    int p=p0+ty*4+i; size_t gi=(size_t)b*4096+p;
    #pragma unroll
    for(int j=0;j<4;j++){
      int c=tx*4+j; if(c>=38) continue;
      f32 v=acc[i][j];
      if(c<6){ f32 xv=v+dtb[dir*6+c]; dt_sp[gi*24+dir*6+c]=(xv>20.f)? xv : log1pf(__expf(xv)); }
      else if(c<22){ Bg[(gi*4+dir)*16 + (c-6)]=v; }
      else         { Cg[(gi*4+dir)*16 + (c-22)]=v; }
    }
  }
}

// ---------------- Kernel D1: per (chunk, dir, b): cumsum, a_chunk, S_loc --------
__global__ __launch_bounds__(192) void k_chunk1(const f32* __restrict__ xh, const f32* __restrict__ Bg,
      const f32* __restrict__ dt_sp, const f32* __restrict__ Alogs, f32* __restrict__ S, f32* __restrict__ ach){
  __shared__ f32 xs[64][192];
  __shared__ f32 Bt[64][16];
  __shared__ f32 dtl[64][6], cuml[64][6], w3l[64][6];
  const int c=blockIdx.x, dir=blockIdx.y, b=blockIdx.z, c0=c*64, tid=threadIdx.x;
  for(int i=tid;i<3072;i+=192){int r=i/48,q=i%48; ((float4*)&xs[r][0])[q]=((const float4*)&xh[(size_t)(b*4096+pos_of(dir,c0+r))*192])[q]; }
  for(int i=tid;i<256;i+=192){int r=i>>2,q=i&3; ((float4*)&Bt[r][0])[q]=((const float4*)&Bg[((size_t)(b*4096+c0+r)*4+dir)*16])[q]; }
  for(int i=tid;i<384;i+=192){int r=i/6,q=i%6; dtl[r][q]=dt_sp[(size_t)(b*4096+c0+r)*24+dir*6+q]; }
  __syncthreads();
  if(tid<6){
    f32 A=-__expf(Alogs[dir*6+tid]);
    f32 run=0.f;
    for(int t=0;t<64;t++){ run+=dtl[t][tid]*A; cuml[t][tid]=run; }
    ach[((size_t)(b*64+c))*24+dir*6+tid]=__expf(run);
  }
  __syncthreads();
  for(int i=tid;i<384;i+=192){int t=i&63,r=i>>6; w3l[t][r]=__expf(cuml[63][r]-cuml[t][r])*dtl[t][r]; }
  __syncthreads();
  const int r=tid>>5, d=tid&31;
  f32 acc[16]={};
  for(int s=0;s<64;s++){
    f32 m=xs[s][r*32+d]*w3l[s][r];
    #pragma unroll
    for(int n4=0;n4<4;n4++){
      float4 b4=((float4*)&Bt[s][0])[n4];
      acc[n4*4+0]+=m*b4.x; acc[n4*4+1]+=m*b4.y; acc[n4*4+2]+=m*b4.z; acc[n4*4+3]+=m*b4.w;
    }
  }
  f32* o=&S[(((size_t)(b*64+c))*24+dir*6+r)*512 + d*16];
  #pragma unroll
  for(int n4=0;n4<4;n4++){ float4 v={acc[n4*4+0],acc[n4*4+1],acc[n4*4+2],acc[n4*4+3]}; ((float4*)o)[n4]=v; }
}

// ---------------- Kernel D2: serial inter-chunk scan (in-place S -> prev) ------
__global__ __launch_bounds__(256) void k_scan(f32* __restrict__ S, const f32* __restrict__ ach){
  const int g=blockIdx.x*256+threadIdx.x;        // 98304 = 8*24*32*16
  const int b=g/12288, rem=g%12288, h=rem/512;
  size_t base=(size_t)b*786432 + rem;
  const f32* ap=&ach[(size_t)b*1536 + h];
  f32 st=0.f;
  for(int c=0;c<64;c++){
    f32 a=ap[c*24];
    f32 s=S[base+(size_t)c*12288];
    S[base+(size_t)c*12288]=st;
    st=a*st+s;
  }
}

// ---------------- Kernel D3: per (chunk, b) for fixed dir: y tile -> merged -----
__global__ __launch_bounds__(192) void k_chunk2(const f32* __restrict__ xh, const f32* __restrict__ Bg,
      const f32* __restrict__ Cg, const f32* __restrict__ dt_sp, const f32* __restrict__ Sprev,
      const f32* __restrict__ Alogs, const f32* __restrict__ Dsw, f32* __restrict__ ym, const int dir){
  __shared__ bf16 xsb[64][192];     // 24.0 KB
  __shared__ f32 CB[64][68];        // 17.0 KB  zero-padded above diagonal
  __shared__ f32 Bt[64][16];
  __shared__ f32 CtP[64][21];       // stride-21: conflict-free strided reads
  __shared__ f32 Ct4[64][16];       // broadcast float4 reads
  __shared__ f32 dtl[64][6], cuml[64][6], w1l[64][6];
  const int c=blockIdx.x, b=blockIdx.y, c0=c*64, tid=threadIdx.x;
  for(int i=tid;i<3072;i+=192){
    int r=i/48,q=i%48;
    float4 v=((const float4*)&xh[(size_t)(b*4096+pos_of(dir,c0+r))*192])[q];
    xsb[r][q*4+0]=__float2bfloat16(v.x); xsb[r][q*4+1]=__float2bfloat16(v.y);
    xsb[r][q*4+2]=__float2bfloat16(v.z); xsb[r][q*4+3]=__float2bfloat16(v.w);
  }
  for(int i=tid;i<256;i+=192){
    int r=i>>2,q=i&3;
    ((float4*)&Bt[r][0])[q]=((const float4*)&Bg[((size_t)(b*4096+c0+r)*4+dir)*16])[q];
    float4 cv=((const float4*)&Cg[((size_t)(b*4096+c0+r)*4+dir)*16])[q];
    ((float4*)&Ct4[r][0])[q]=cv;
    CtP[r][q*4+0]=cv.x; CtP[r][q*4+1]=cv.y; CtP[r][q*4+2]=cv.z; CtP[r][q*4+3]=cv.w;
  }
  for(int i=tid;i<384;i+=192){int r=i/6,q=i%6; dtl[r][q]=dt_sp[(size_t)(b*4096+c0+r)*24+dir*6+q]; }
  __syncthreads();
  if(tid<6){
    f32 A=-__expf(Alogs[dir*6+tid]);
    f32 run=0.f;
    for(int t=0;t<64;t++){ run+=dtl[t][tid]*A; cuml[t][tid]=run; }
  }
  __syncthreads();
  for(int i=tid;i<384;i+=192){int t=i&63,r=i>>6; w1l[t][r]=__expf(-cuml[t][r])*dtl[t][r]; }
  for(int i=tid;i<4096;i+=192){
    int t=i&63, s=i>>6;
    f32 v=0.f;
    if(s<=t){
      #pragma unroll
      for(int n=0;n<16;n++) v+=CtP[t][n]*Bt[s][n];
    }
    CB[t][s]=v;
  }
  __syncthreads();
  const int r=tid>>5, d=tid&31, ch=r*32+d;
  const f32* pp=&Sprev[(((size_t)(b*64+c))*24+dir*6+r)*512 + d*16];
  f32 pv[16];
  #pragma unroll
  for(int n4=0;n4<4;n4++){ float4 v=((const float4*)pp)[n4]; pv[n4*4]=v.x; pv[n4*4+1]=v.y; pv[n4*4+2]=v.z; pv[n4*4+3]=v.w; }
  f32 y[64];
  #pragma unroll
  for(int t=0;t<64;t++) y[t]=0.f;
  for(int s0=0;s0<64;s0+=4){
    f32 m[4];
    #pragma unroll
    for(int j=0;j<4;j++) m[j]=b2f(xsb[s0+j][ch])*w1l[s0+j][r];
    #pragma unroll
    for(int t=0;t<64;t++){
      float4 cb=*(float4*)&CB[t][s0];
      y[t]+=cb.x*m[0]+cb.y*m[1]+cb.z*m[2]+cb.w*m[3];
    }
  }
  const f32 Dv=Dsw[(dir*6+r)*32+d];
  #pragma unroll
  for(int t=0;t<64;t++){
    f32 dc=0.f;
    #pragma unroll
    for(int n4=0;n4<4;n4++){
      float4 c4=((float4*)&Ct4[t][0])[n4];
      dc+=c4.x*pv[n4*4]+c4.y*pv[n4*4+1]+c4.z*pv[n4*4+2]+c4.w*pv[n4*4+3];
    }
    f32 val=__expf(cuml[t][r])*(y[t]+dc)+Dv*b2f(xsb[t][ch]);
    size_t o=((size_t)(b*4096+pos_of(dir,c0+t)))*192+ch;
    if(dir==0) ym[o]=val; else ym[o]+=val;
  }
}

// ---------------- Kernel E: layernorm(192) then * z (in place into z) ----------
__global__ __launch_bounds__(256) void k_ln(const f32* __restrict__ ym, f32* __restrict__ z,
                                            const f32* __restrict__ lw, const f32* __restrict__ lb){
  const int row=blockIdx.x*4+(threadIdx.x>>6), lane=threadIdx.x&63;
  const f32* yr=&ym[(size_t)row*192];
  f32 v0=yr[lane], v1=yr[lane+64], v2=yr[lane+128];
  f32 s=v0+v1+v2;
  #pragma unroll
  for(int off=32;off>0;off>>=1) s+=__shfl_xor(s,off,64);
  const f32 mu=s*(1.f/192.f);
  f32 d0=v0-mu,d1=v1-mu,d2=v2-mu;
  f32 q=d0*d0+d1*d1+d2*d2;
  #pragma unroll
  for(int off=32;off>0;off>>=1) q+=__shfl_xor(q,off,64);
  const f32 rs=rsqrtf(q*(1.f/192.f)+1e-5f);
  f32* zr=&z[(size_t)row*192];
  zr[lane]    =(d0*rs*lw[lane]    +lb[lane])    *zr[lane];
  zr[lane+64] =(d1*rs*lw[lane+64] +lb[lane+64]) *zr[lane+64];
  zr[lane+128]=(d2*rs*lw[lane+128]+lb[lane+128])*zr[lane+128];
}

// ---------------- Kernel F: out = u @ out_proj_w.T (fp32 out) ------------------
__global__ __launch_bounds__(256) void k_outproj(const f32* __restrict__ u, const f32* __restrict__ w,
                                                 f32* __restrict__ out){
  __shared__ f32 As[32][68];
  __shared__ f32 Bs[32][68];
  const int m0=blockIdx.x*64, n0=blockIdx.y*64;
  const int tid=threadIdx.x, tx=tid&15, ty=tid>>4;
  f32 acc[4][4]={};
  for(int k0=0;k0<192;k0+=32){
    for(int i=tid;i<2048;i+=256){int r=i>>5,kk=i&31; As[kk][r]=u[(size_t)(m0+r)*192+k0+kk]; }
    for(int i=tid;i<2048;i+=256){int r=i>>5,kk=i&31; int n=n0+r; Bs[kk][r]=(n<96)? w[(size_t)n*192+k0+kk] : 0.f; }
    __syncthreads();
    #pragma unroll
    for(int kk=0;kk<32;kk++){
      float4 a4=*(float4*)&As[kk][ty*4];
      float4 b4=*(float4*)&Bs[kk][tx*4];
      f32 a[4]={a4.x,a4.y,a4.z,a4.w}, bb[4]={b4.x,b4.y,b4.z,b4.w};
      #pragma unroll
      for(int i=0;i<4;i++)
        #pragma unroll
        for(int j=0;j<4;j++) acc[i][j]+=a[i]*bb[j];
    }
    __syncthreads();
  }
  #pragma unroll
  for(int i=0;i<4;i++){
    int row=m0+ty*4+i;
    #pragma unroll
    for(int j=0;j<4;j++){
      int col=n0+tx*4+j;
      if(col<96) out[(size_t)row*96+col]=acc[i][j];
    }
  }
}

extern "C" void kernel_launch(void* const* d_in, const int* in_sizes, int n_in,
                              void* d_out, int out_size, void* d_ws, size_t ws_size,
                              hipStream_t stream){
  const f32* x  =(const f32*)d_in[0];
  const f32* ipw=(const f32*)d_in[1];
  const f32* cw =(const f32*)d_in[2];
  const f32* cb =(const f32*)d_in[3];
  const f32* xpw=(const f32*)d_in[4];
  const f32* alg=(const f32*)d_in[5];
  const f32* dsw=(const f32*)d_in[6];
  const f32* dtb=(const f32*)d_in[7];
  const f32* lw =(const f32*)d_in[8];
  const f32* lb =(const f32*)d_in[9];
  const f32* opw=(const f32*)d_in[10];
  f32* out=(f32*)d_out;
  f32* ws=(f32*)d_ws;

  f32* xh_raw=ws;               // 6291456 floats (reused as ym)
  f32* z     =ws+ 6291456;      // 6291456 (silu(z), later LN(y)*z)
  f32* xh    =ws+12582912;      // 6291456
  f32* dt_sp =ws+18874368;      //  786432
  f32* Bg    =ws+19660800;      // 2097152
  f32* Cg    =ws+21757952;      // 2097152
  f32* S     =ws+23855104;      // 6291456 (S_loc, then prev_states in place)
  f32* ach   =ws+30146560;      //   12288
  f32* ym=xh_raw;

  k_inproj<<<dim3(512,6),256,0,stream>>>(x,ipw,xh_raw,z);
  k_conv<<<6144,256,0,stream>>>(xh_raw,cw,cb,xh);
  k_xdbl<<<dim3(64,4,8),192,0,stream>>>(xh,xpw,dtb,dt_sp,Bg,Cg);
  k_chunk1<<<dim3(64,4,8),192,0,stream>>>(xh,Bg,dt_sp,alg,S,ach);
  k_scan<<<384,256,0,stream>>>(S,ach);
  k_chunk2<<<dim3(64,8),192,0,stream>>>(xh,Bg,Cg,dt_sp,S,alg,dsw,ym,0);
  k_chunk2<<<dim3(64,8),192,0,stream>>>(xh,Bg,Cg,dt_sp,S,alg,dsw,ym,1);
  k_chunk2<<<dim3(64,8),192,0,stream>>>(xh,Bg,Cg,dt_sp,S,alg,dsw,ym,2);
  k_chunk2<<<dim3(64,8),192,0,stream>>>(xh,Bg,Cg,dt_sp,S,alg,dsw,ym,3);
  k_ln<<<8192,256,0,stream>>>(ym,z,lw,lb);
  k_outproj<<<dim3(512,2),256,0,stream>>>(z,opw,out);
}

// Round 3
// 536.416 us; speedup vs baseline: 1.0632x; 1.0632x over previous
//
#include <hip/hip_runtime.h>
#include <hip/hip_bf16.h>

using bf16 = __hip_bfloat16;
typedef float f32;

static __device__ __forceinline__ f32 b2f(bf16 v){ return __bfloat162float(v); }
static __device__ __forceinline__ f32 siluf(f32 v){ return v / (1.f + __expf(-v)); }

// spatial position of sequence index p for scan direction dir (H=W=64, L=4096)
static __device__ __forceinline__ int pos_of(int dir, int p){
  if(dir==0) return p;
  if(dir==1) return ((p&63)<<6) | (p>>6);
  if(dir==2) return 4095-p;
  int q = 4095-p; return ((q&63)<<6) | (q>>6);
}

// ---------------- Kernel A: xz = x @ in_proj_w.T ; split -> xh_raw, z=silu ----
__global__ __launch_bounds__(256) void k_inproj(const f32* __restrict__ x, const f32* __restrict__ w,
                                                f32* __restrict__ xh_raw, f32* __restrict__ z){
  __shared__ f32 As[32][68];
  __shared__ f32 Bs[32][68];
  const int m0=blockIdx.x*64, n0=blockIdx.y*64;
  const int tid=threadIdx.x, tx=tid&15, ty=tid>>4;
  f32 acc[4][4]={};
  for(int k0=0;k0<96;k0+=32){
    for(int i=tid;i<2048;i+=256){int r=i>>5,kk=i&31; As[kk][r]=x[(size_t)(m0+r)*96+k0+kk]; }
    for(int i=tid;i<2048;i+=256){int r=i>>5,kk=i&31; Bs[kk][r]=w[(size_t)(n0+r)*96+k0+kk]; }
    __syncthreads();
    #pragma unroll
    for(int kk=0;kk<32;kk++){
      float4 a4=*(float4*)&As[kk][ty*4];
      float4 b4=*(float4*)&Bs[kk][tx*4];
      f32 a[4]={a4.x,a4.y,a4.z,a4.w}, b[4]={b4.x,b4.y,b4.z,b4.w};
      #pragma unroll
      for(int i=0;i<4;i++)
        #pragma unroll
        for(int j=0;j<4;j++) acc[i][j]+=a[i]*b[j];
    }
    __syncthreads();
  }
  #pragma unroll
  for(int i=0;i<4;i++){
    int row=m0+ty*4+i;
    #pragma unroll
    for(int j=0;j<4;j++){
      int col=n0+tx*4+j; f32 v=acc[i][j];
      if(col<192) xh_raw[(size_t)row*192+col]=v;
      else        z[(size_t)row*192+(col-192)]=siluf(v);
    }
  }
}

// ---------------- Kernel B: depthwise 3x3 conv + bias + silu --------------------
__global__ __launch_bounds__(256) void k_conv(const f32* __restrict__ xh_raw, const f32* __restrict__ cw,
                                              const f32* __restrict__ cb, f32* __restrict__ xh){
  __shared__ f32 wsm[192][9];
  __shared__ f32 bsm[192];
  const int tid=threadIdx.x;
  for(int i=tid;i<1728;i+=256) wsm[i/9][i%9]=cw[i];
  for(int i=tid;i<192;i+=256) bsm[i]=cb[i];
  __syncthreads();
  const int idx=blockIdx.x*256+tid;
  const int c4=idx%48, j=(idx/48)&63, ii0=(idx/3072)&63, b=idx/196608;
  const int c0=c4*4;
  f32 acc[4]={bsm[c0],bsm[c0+1],bsm[c0+2],bsm[c0+3]};
  #pragma unroll
  for(int a=0;a<3;a++){
    int ii=ii0+a-1; if(ii<0||ii>63) continue;
    #pragma unroll
    for(int bb=0;bb<3;bb++){
      int jj=j+bb-1; if(jj<0||jj>63) continue;
      float4 v=*(const float4*)&xh_raw[((size_t)(b*4096)+(ii*64+jj))*192 + c0];
      int t=a*3+bb;
      acc[0]+=v.x*wsm[c0][t]; acc[1]+=v.y*wsm[c0+1][t];
      acc[2]+=v.z*wsm[c0+2][t]; acc[3]+=v.w*wsm[c0+3][t];
    }
  }
  float4 o; o.x=siluf(acc[0]); o.y=siluf(acc[1]); o.z=siluf(acc[2]); o.w=siluf(acc[3]);
  ((float4*)xh)[idx]=o;
}

// ---------------- Kernel C: x_dbl = xh @ [W0|W1|W2|W3]^T, pixel-indexed --------
// M=32768, K=192, N=160 (4 dirs x 40, cols 38/39 of each dir are pad).
__global__ __launch_bounds__(256) void k_xdbl(const f32* __restrict__ xh, const f32* __restrict__ xpw,
                                              const f32* __restrict__ dtb, f32* __restrict__ dt_sp,
                                              f32* __restrict__ Bg, f32* __restrict__ Cg){
  __shared__ f32 As[32][68];
  __shared__ f32 Ws[32][161];
  const int m0=blockIdx.x*64;
  const int tid=threadIdx.x, tx=tid&15, ty=tid>>4;
  f32 acc[4][10]={};
  for(int k0=0;k0<192;k0+=32){
    for(int i=tid;i<2048;i+=256){int r=i>>5,kk=i&31; As[kk][r]=xh[(size_t)(m0+r)*192+k0+kk]; }
    for(int i=tid;i<5120;i+=256){int n=i>>5,kk=i&31; int dir=n/40, cc=n-dir*40;
        Ws[kk][n]=(cc<38)? xpw[(size_t)dir*7296+cc*192+k0+kk] : 0.f; }
    __syncthreads();
    #pragma unroll
    for(int kk=0;kk<32;kk++){
      float4 a4=*(float4*)&As[kk][ty*4];
      f32 a[4]={a4.x,a4.y,a4.z,a4.w};
      f32 bv[10];
      #pragma unroll
      for(int j=0;j<10;j++) bv[j]=Ws[kk][tx*10+j];
      #pragma unroll
      for(int i=0;i<4;i++)
        #pragma unroll
        for(int j=0;j<10;j++) acc[i][j]+=a[i]*bv[j];
    }
    __syncthreads();
  }
  #pragma unroll
  for(int i=0;i<4;i++){
    size_t pix=(size_t)(m0+ty*4+i);
    #pragma unroll
    for(int j=0;j<10;j++){
      int n=tx*10+j; int dir=n/40, cc=n-dir*40;
      if(cc>=38) continue;
      f32 v=acc[i][j];
      if(cc<6){ f32 xv=v+dtb[dir*6+cc]; dt_sp[pix*24+dir*6+cc]=(xv>20.f)? xv : log1pf(__expf(xv)); }
      else if(cc<22){ Bg[(pix*4+dir)*16+(cc-6)]=v; }
      else          { Cg[(pix*4+dir)*16+(cc-22)]=v; }
    }
  }
}

// ---------------- Kernel D1: per (chunk, dir, b): cumsum, a_chunk, S_loc --------
__global__ __launch_bounds__(192) void k_chunk1(const f32* __restrict__ xh, const f32* __restrict__ Bg,
      const f32* __restrict__ dt_sp, const f32* __restrict__ Alogs, f32* __restrict__ S, f32* __restrict__ ach){
  __shared__ f32 xs[64][192];
  __shared__ f32 Bt[64][16];
  __shared__ f32 dtl[64][6], cuml[64][6], w3l[64][6];
  const int c=blockIdx.x, dir=blockIdx.y, b=blockIdx.z, c0=c*64, tid=threadIdx.x;
  for(int i=tid;i<3072;i+=192){int r=i/48,q=i%48; ((float4*)&xs[r][0])[q]=((const float4*)&xh[(size_t)(b*4096+pos_of(dir,c0+r))*192])[q]; }
  for(int i=tid;i<256;i+=192){int r=i>>2,q=i&3; size_t pix=(size_t)b*4096+pos_of(dir,c0+r);
      ((float4*)&Bt[r][0])[q]=((const float4*)&Bg[(pix*4+dir)*16])[q]; }
  for(int i=tid;i<384;i+=192){int r=i/6,q=i%6; size_t pix=(size_t)b*4096+pos_of(dir,c0+r);
      dtl[r][q]=dt_sp[pix*24+dir*6+q]; }
  __syncthreads();
  if(tid<6){
    f32 A=-__expf(Alogs[dir*6+tid]);
    f32 run=0.f;
    for(int t=0;t<64;t++){ run+=dtl[t][tid]*A; cuml[t][tid]=run; }
    ach[((size_t)(b*64+c))*24+dir*6+tid]=__expf(run);
  }
  __syncthreads();
  for(int i=tid;i<384;i+=192){int t=i&63,r=i>>6; w3l[t][r]=__expf(cuml[63][r]-cuml[t][r])*dtl[t][r]; }
  __syncthreads();
  const int r=tid>>5, d=tid&31;
  f32 acc[16]={};
  for(int s=0;s<64;s++){
    f32 m=xs[s][r*32+d]*w3l[s][r];
    #pragma unroll
    for(int n4=0;n4<4;n4++){
      float4 b4=((float4*)&Bt[s][0])[n4];
      acc[n4*4+0]+=m*b4.x; acc[n4*4+1]+=m*b4.y; acc[n4*4+2]+=m*b4.z; acc[n4*4+3]+=m*b4.w;
    }
  }
  f32* o=&S[(((size_t)(b*64+c))*24+dir*6+r)*512 + d*16];
  #pragma unroll
  for(int n4=0;n4<4;n4++){ float4 v={acc[n4*4+0],acc[n4*4+1],acc[n4*4+2],acc[n4*4+3]}; ((float4*)o)[n4]=v; }
}

// ---------------- Kernel D2: serial inter-chunk scan (in-place S -> prev) ------
__global__ __launch_bounds__(256) void k_scan(f32* __restrict__ S, const f32* __restrict__ ach){
  const int g=blockIdx.x*256+threadIdx.x;        // 98304 = 8*24*32*16
  const int b=g/12288, rem=g%12288, h=rem/512;
  size_t base=(size_t)b*786432 + rem;
  const f32* ap=&ach[(size_t)b*1536 + h];
  f32 st=0.f;
  for(int c=0;c<64;c++){
    f32 a=ap[c*24];
    f32 s=S[base+(size_t)c*12288];
    S[base+(size_t)c*12288]=st;
    st=a*st+s;
  }
}

// ---------------- Kernel D3: y tile for dirs (dirbase+z); dir even->ym0, odd->ym1
__global__ __launch_bounds__(192) void k_chunk2(const f32* __restrict__ xh, const f32* __restrict__ Bg,
      const f32* __restrict__ Cg, const f32* __restrict__ dt_sp, const f32* __restrict__ Sprev,
      const f32* __restrict__ Alogs, const f32* __restrict__ Dsw,
      f32* __restrict__ ym0, f32* __restrict__ ym1, const int dirbase){
  __shared__ bf16 xsb[64][192];
  __shared__ f32 CB[64][68];
  __shared__ f32 Bt[64][16];
  __shared__ f32 CtP[64][21];
  __shared__ f32 Ct4[64][16];
  __shared__ f32 dtl[64][6], cuml[64][6], w1l[64][6];
  const int c=blockIdx.x, b=blockIdx.y, dir=dirbase+blockIdx.z, c0=c*64, tid=threadIdx.x;
  f32* __restrict__ ym = (dir&1)? ym1 : ym0;
  for(int i=tid;i<3072;i+=192){
    int r=i/48,q=i%48;
    float4 v=((const float4*)&xh[(size_t)(b*4096+pos_of(dir,c0+r))*192])[q];
    xsb[r][q*4+0]=__float2bfloat16(v.x); xsb[r][q*4+1]=__float2bfloat16(v.y);
    xsb[r][q*4+2]=__float2bfloat16(v.z); xsb[r][q*4+3]=__float2bfloat16(v.w);
  }
  for(int i=tid;i<256;i+=192){
    int r=i>>2,q=i&3; size_t pix=(size_t)b*4096+pos_of(dir,c0+r);
    ((float4*)&Bt[r][0])[q]=((const float4*)&Bg[(pix*4+dir)*16])[q];
    float4 cv=((const float4*)&Cg[(pix*4+dir)*16])[q];
    ((float4*)&Ct4[r][0])[q]=cv;
    CtP[r][q*4+0]=cv.x; CtP[r][q*4+1]=cv.y; CtP[r][q*4+2]=cv.z; CtP[r][q*4+3]=cv.w;
  }
  for(int i=tid;i<384;i+=192){int r=i/6,q=i%6; size_t pix=(size_t)b*4096+pos_of(dir,c0+r);
      dtl[r][q]=dt_sp[pix*24+dir*6+q]; }
  __syncthreads();
  if(tid<6){
    f32 A=-__expf(Alogs[dir*6+tid]);
    f32 run=0.f;
    for(int t=0;t<64;t++){ run+=dtl[t][tid]*A; cuml[t][tid]=run; }
  }
  __syncthreads();
  for(int i=tid;i<384;i+=192){int t=i&63,r=i>>6; w1l[t][r]=__expf(-cuml[t][r])*dtl[t][r]; }
  for(int i=tid;i<4096;i+=192){
    int t=i&63, s=i>>6;
    f32 v=0.f;
    if(s<=t){
      #pragma unroll
      for(int n=0;n<16;n++) v+=CtP[t][n]*Bt[s][n];
    }
    CB[t][s]=v;
  }
  __syncthreads();
  const int r=tid>>5, d=tid&31, ch=r*32+d;
  const f32* pp=&Sprev[(((size_t)(b*64+c))*24+dir*6+r)*512 + d*16];
  f32 pv[16];
  #pragma unroll
  for(int n4=0;n4<4;n4++){ float4 v=((const float4*)pp)[n4]; pv[n4*4]=v.x; pv[n4*4+1]=v.y; pv[n4*4+2]=v.z; pv[n4*4+3]=v.w; }
  f32 y[64];
  #pragma unroll
  for(int t=0;t<64;t++) y[t]=0.f;
  for(int s0=0;s0<64;s0+=4){
    f32 m[4];
    #pragma unroll
    for(int j=0;j<4;j++) m[j]=b2f(xsb[s0+j][ch])*w1l[s0+j][r];
    #pragma unroll
    for(int t=0;t<64;t++){
      float4 cb=*(float4*)&CB[t][s0];
      y[t]+=cb.x*m[0]+cb.y*m[1]+cb.z*m[2]+cb.w*m[3];
    }
  }
  const f32 Dv=Dsw[(dir*6+r)*32+d];
  #pragma unroll
  for(int t=0;t<64;t++){
    f32 dc=0.f;
    #pragma unroll
    for(int n4=0;n4<4;n4++){
      float4 c4=((float4*)&Ct4[t][0])[n4];
      dc+=c4.x*pv[n4*4]+c4.y*pv[n4*4+1]+c4.z*pv[n4*4+2]+c4.w*pv[n4*4+3];
    }
    f32 val=__expf(cuml[t][r])*(y[t]+dc)+Dv*b2f(xsb[t][ch]);
    size_t o=((size_t)(b*4096+pos_of(dir,c0+t)))*192+ch;
    if(dirbase==0) ym[o]=val; else ym[o]+=val;
  }
}

// ---------------- Kernel E: layernorm(192) of (ym0+ym1) then * z ----------------
__global__ __launch_bounds__(256) void k_ln(const f32* __restrict__ ym0, const f32* __restrict__ ym1,
                                            f32* __restrict__ z,
                                            const f32* __restrict__ lw, const f32* __restrict__ lb){
  const int row=blockIdx.x*4+(threadIdx.x>>6), lane=threadIdx.x&63;
  const f32* yr0=&ym0[(size_t)row*192];
  const f32* yr1=&ym1[(size_t)row*192];
  f32 v0=yr0[lane]+yr1[lane], v1=yr0[lane+64]+yr1[lane+64], v2=yr0[lane+128]+yr1[lane+128];
  f32 s=v0+v1+v2;
  #pragma unroll
  for(int off=32;off>0;off>>=1) s+=__shfl_xor(s,off,64);
  const f32 mu=s*(1.f/192.f);
  f32 d0=v0-mu,d1=v1-mu,d2=v2-mu;
  f32 q=d0*d0+d1*d1+d2*d2;
  #pragma unroll
  for(int off=32;off>0;off>>=1) q+=__shfl_xor(q,off,64);
  const f32 rs=rsqrtf(q*(1.f/192.f)+1e-5f);
  f32* zr=&z[(size_t)row*192];
  zr[lane]    =(d0*rs*lw[lane]    +lb[lane])    *zr[lane];
  zr[lane+64] =(d1*rs*lw[lane+64] +lb[lane+64]) *zr[lane+64];
  zr[lane+128]=(d2*rs*lw[lane+128]+lb[lane+128])*zr[lane+128];
}

// ---------------- Kernel F: out = u @ out_proj_w.T (fp32 out) ------------------
__global__ __launch_bounds__(256) void k_outproj(const f32* __restrict__ u, const f32* __restrict__ w,
                                                 f32* __restrict__ out){
  __shared__ f32 As[32][68];
  __shared__ f32 Bs[32][68];
  const int m0=blockIdx.x*64, n0=blockIdx.y*64;
  const int tid=threadIdx.x, tx=tid&15, ty=tid>>4;
  f32 acc[4][4]={};
  for(int k0=0;k0<192;k0+=32){
    for(int i=tid;i<2048;i+=256){int r=i>>5,kk=i&31; As[kk][r]=u[(size_t)(m0+r)*192+k0+kk]; }
    for(int i=tid;i<2048;i+=256){int r=i>>5,kk=i&31; int n=n0+r; Bs[kk][r]=(n<96)? w[(size_t)n*192+k0+kk] : 0.f; }
    __syncthreads();
    #pragma unroll
    for(int kk=0;kk<32;kk++){
      float4 a4=*(float4*)&As[kk][ty*4];
      float4 b4=*(float4*)&Bs[kk][tx*4];
      f32 a[4]={a4.x,a4.y,a4.z,a4.w}, bb[4]={b4.x,b4.y,b4.z,b4.w};
      #pragma unroll
      for(int i=0;i<4;i++)
        #pragma unroll
        for(int j=0;j<4;j++) acc[i][j]+=a[i]*bb[j];
    }
    __syncthreads();
  }
  #pragma unroll
  for(int i=0;i<4;i++){
    int row=m0+ty*4+i;
    #pragma unroll
    for(int j=0;j<4;j++){
      int col=n0+tx*4+j;
      if(col<96) out[(size_t)row*96+col]=acc[i][j];
    }
  }
}

extern "C" void kernel_launch(void* const* d_in, const int* in_sizes, int n_in,
                              void* d_out, int out_size, void* d_ws, size_t ws_size,
                              hipStream_t stream){
  const f32* x  =(const f32*)d_in[0];
  const f32* ipw=(const f32*)d_in[1];
  const f32* cw =(const f32*)d_in[2];
  const f32* cb =(const f32*)d_in[3];
  const f32* xpw=(const f32*)d_in[4];
  const f32* alg=(const f32*)d_in[5];
  const f32* dsw=(const f32*)d_in[6];
  const f32* dtb=(const f32*)d_in[7];
  const f32* lw =(const f32*)d_in[8];
  const f32* lb =(const f32*)d_in[9];
  const f32* opw=(const f32*)d_in[10];
  f32* out=(f32*)d_out;
  f32* ws=(f32*)d_ws;

  f32* xh_raw=ws;               // 6291456 floats (reused as ym0)
  f32* z     =ws+ 6291456;      // 6291456
  f32* xh    =ws+12582912;      // 6291456
  f32* dt_sp =ws+18874368;      //  786432
  f32* Bg    =ws+19660800;      // 2097152
  f32* Cg    =ws+21757952;      // 2097152
  f32* S     =ws+23855104;      // 6291456
  f32* ach   =ws+30146560;      //   12288
  f32* ym1   =ws+30158848;      // 6291456  (total 36450304 floats = 145.8 MB)
  f32* ym0=xh_raw;

  k_inproj<<<dim3(512,6),256,0,stream>>>(x,ipw,xh_raw,z);
  k_conv<<<6144,256,0,stream>>>(xh_raw,cw,cb,xh);
  k_xdbl<<<dim3(512),256,0,stream>>>(xh,xpw,dtb,dt_sp,Bg,Cg);
  k_chunk1<<<dim3(64,4,8),192,0,stream>>>(xh,Bg,dt_sp,alg,S,ach);
  k_scan<<<384,256,0,stream>>>(S,ach);
  k_chunk2<<<dim3(64,8,2),192,0,stream>>>(xh,Bg,Cg,dt_sp,S,alg,dsw,ym0,ym1,0);
  k_chunk2<<<dim3(64,8,2),192,0,stream>>>(xh,Bg,Cg,dt_sp,S,alg,dsw,ym0,ym1,2);
  k_ln<<<8192,256,0,stream>>>(ym0,ym1,z,lw,lb);
  k_outproj<<<dim3(512,2),256,0,stream>>>(z,opw,out);
}

// Round 4
// 394.451 us; speedup vs baseline: 1.4459x; 1.3599x over previous
//
#include <hip/hip_runtime.h>
#include <hip/hip_bf16.h>

using bf16 = __hip_bfloat16;
typedef float f32;
typedef __attribute__((ext_vector_type(8))) short bf16x8;
typedef __attribute__((ext_vector_type(4))) float f32x4;
typedef __attribute__((ext_vector_type(4))) unsigned short u16x4;

static __device__ __forceinline__ f32 b2f(bf16 v){ return __bfloat162float(v); }
static __device__ __forceinline__ f32 siluf(f32 v){ return v / (1.f + __expf(-v)); }
static __device__ __forceinline__ unsigned short f2bf(f32 v){
  __hip_bfloat16 h=__float2bfloat16(v); return *(unsigned short*)&h;
}
static __device__ __forceinline__ f32 bfr2f(unsigned short u){
  unsigned int x=((unsigned int)u)<<16; return __uint_as_float(x);
}

// spatial position of sequence index p for scan direction dir (H=W=64, L=4096)
static __device__ __forceinline__ int pos_of(int dir, int p){
  if(dir==0) return p;
  if(dir==1) return ((p&63)<<6) | (p>>6);
  if(dir==2) return 4095-p;
  int q = 4095-p; return ((q&63)<<6) | (q>>6);
}

// ---------------- Kernel A: xz = x @ in_proj_w.T ; split -> xh_raw, z=silu ----
__global__ __launch_bounds__(256) void k_inproj(const f32* __restrict__ x, const f32* __restrict__ w,
                                                f32* __restrict__ xh_raw, f32* __restrict__ z){
  __shared__ f32 As[32][68];
  __shared__ f32 Bs[32][68];
  const int m0=blockIdx.x*64, n0=blockIdx.y*64;
  const int tid=threadIdx.x, tx=tid&15, ty=tid>>4;
  f32 acc[4][4]={};
  for(int k0=0;k0<96;k0+=32){
    for(int i=tid;i<2048;i+=256){int r=i>>5,kk=i&31; As[kk][r]=x[(size_t)(m0+r)*96+k0+kk]; }
    for(int i=tid;i<2048;i+=256){int r=i>>5,kk=i&31; Bs[kk][r]=w[(size_t)(n0+r)*96+k0+kk]; }
    __syncthreads();
    #pragma unroll
    for(int kk=0;kk<32;kk++){
      float4 a4=*(float4*)&As[kk][ty*4];
      float4 b4=*(float4*)&Bs[kk][tx*4];
      f32 a[4]={a4.x,a4.y,a4.z,a4.w}, b[4]={b4.x,b4.y,b4.z,b4.w};
      #pragma unroll
      for(int i=0;i<4;i++)
        #pragma unroll
        for(int j=0;j<4;j++) acc[i][j]+=a[i]*b[j];
    }
    __syncthreads();
  }
  #pragma unroll
  for(int i=0;i<4;i++){
    int row=m0+ty*4+i;
    #pragma unroll
    for(int j=0;j<4;j++){
      int col=n0+tx*4+j; f32 v=acc[i][j];
      if(col<192) xh_raw[(size_t)row*192+col]=v;
      else        z[(size_t)row*192+(col-192)]=siluf(v);
    }
  }
}

// ---------------- Kernel B: depthwise 3x3 conv + bias + silu --------------------
__global__ __launch_bounds__(256) void k_conv(const f32* __restrict__ xh_raw, const f32* __restrict__ cw,
                                              const f32* __restrict__ cb, f32* __restrict__ xh){
  __shared__ f32 wsm[192][9];
  __shared__ f32 bsm[192];
  const int tid=threadIdx.x;
  for(int i=tid;i<1728;i+=256) wsm[i/9][i%9]=cw[i];
  for(int i=tid;i<192;i+=256) bsm[i]=cb[i];
  __syncthreads();
  const int idx=blockIdx.x*256+tid;
  const int c4=idx%48, j=(idx/48)&63, ii0=(idx/3072)&63, b=idx/196608;
  const int c0=c4*4;
  f32 acc[4]={bsm[c0],bsm[c0+1],bsm[c0+2],bsm[c0+3]};
  #pragma unroll
  for(int a=0;a<3;a++){
    int ii=ii0+a-1; if(ii<0||ii>63) continue;
    #pragma unroll
    for(int bb=0;bb<3;bb++){
      int jj=j+bb-1; if(jj<0||jj>63) continue;
      float4 v=*(const float4*)&xh_raw[((size_t)(b*4096)+(ii*64+jj))*192 + c0];
      int t=a*3+bb;
      acc[0]+=v.x*wsm[c0][t]; acc[1]+=v.y*wsm[c0+1][t];
      acc[2]+=v.z*wsm[c0+2][t]; acc[3]+=v.w*wsm[c0+3][t];
    }
  }
  float4 o; o.x=siluf(acc[0]); o.y=siluf(acc[1]); o.z=siluf(acc[2]); o.w=siluf(acc[3]);
  ((float4*)xh)[idx]=o;
}

// ---------------- Kernel C: x_dbl = xh @ [W0|W1|W2|W3]^T, pixel-indexed --------
__global__ __launch_bounds__(256) void k_xdbl(const f32* __restrict__ xh, const f32* __restrict__ xpw,
                                              const f32* __restrict__ dtb, f32* __restrict__ dt_sp,
                                              f32* __restrict__ Bg, f32* __restrict__ Cg){
  __shared__ f32 As[32][68];
  __shared__ f32 Ws[32][161];
  const int m0=blockIdx.x*64;
  const int tid=threadIdx.x, tx=tid&15, ty=tid>>4;
  f32 acc[4][10]={};
  for(int k0=0;k0<192;k0+=32){
    for(int i=tid;i<2048;i+=256){int r=i>>5,kk=i&31; As[kk][r]=xh[(size_t)(m0+r)*192+k0+kk]; }
    for(int i=tid;i<5120;i+=256){int n=i>>5,kk=i&31; int dir=n/40, cc=n-dir*40;
        Ws[kk][n]=(cc<38)? xpw[(size_t)dir*7296+cc*192+k0+kk] : 0.f; }
    __syncthreads();
    #pragma unroll
    for(int kk=0;kk<32;kk++){
      float4 a4=*(float4*)&As[kk][ty*4];
      f32 a[4]={a4.x,a4.y,a4.z,a4.w};
      f32 bv[10];
      #pragma unroll
      for(int j=0;j<10;j++) bv[j]=Ws[kk][tx*10+j];
      #pragma unroll
      for(int i=0;i<4;i++)
        #pragma unroll
        for(int j=0;j<10;j++) acc[i][j]+=a[i]*bv[j];
    }
    __syncthreads();
  }
  #pragma unroll
  for(int i=0;i<4;i++){
    size_t pix=(size_t)(m0+ty*4+i);
    #pragma unroll
    for(int j=0;j<10;j++){
      int n=tx*10+j; int dir=n/40, cc=n-dir*40;
      if(cc>=38) continue;
      f32 v=acc[i][j];
      if(cc<6){ f32 xv=v+dtb[dir*6+cc]; dt_sp[pix*24+dir*6+cc]=(xv>20.f)? xv : log1pf(__expf(xv)); }
      else if(cc<22){ Bg[(pix*4+dir)*16+(cc-6)]=v; }
      else          { Cg[(pix*4+dir)*16+(cc-22)]=v; }
    }
  }
}

// ---------------- Kernel D1: per (chunk, dir, b): cumsum, a_chunk, S_loc --------
__global__ __launch_bounds__(192) void k_chunk1(const f32* __restrict__ xh, const f32* __restrict__ Bg,
      const f32* __restrict__ dt_sp, const f32* __restrict__ Alogs, f32* __restrict__ S, f32* __restrict__ ach){
  __shared__ f32 xs[64][192];
  __shared__ f32 Bt[64][16];
  __shared__ f32 dtl[64][6], cuml[64][6], w3l[64][6];
  const int c=blockIdx.x, dir=blockIdx.y, b=blockIdx.z, c0=c*64, tid=threadIdx.x;
  for(int i=tid;i<3072;i+=192){int r=i/48,q=i%48; ((float4*)&xs[r][0])[q]=((const float4*)&xh[(size_t)(b*4096+pos_of(dir,c0+r))*192])[q]; }
  for(int i=tid;i<256;i+=192){int r=i>>2,q=i&3; size_t pix=(size_t)b*4096+pos_of(dir,c0+r);
      ((float4*)&Bt[r][0])[q]=((const float4*)&Bg[(pix*4+dir)*16])[q]; }
  for(int i=tid;i<384;i+=192){int r=i/6,q=i%6; size_t pix=(size_t)b*4096+pos_of(dir,c0+r);
      dtl[r][q]=dt_sp[pix*24+dir*6+q]; }
  __syncthreads();
  if(tid<6){
    f32 A=-__expf(Alogs[dir*6+tid]);
    f32 run=0.f;
    for(int t=0;t<64;t++){ run+=dtl[t][tid]*A; cuml[t][tid]=run; }
    ach[((size_t)(b*64+c))*24+dir*6+tid]=__expf(run);
  }
  __syncthreads();
  for(int i=tid;i<384;i+=192){int t=i&63,r=i>>6; w3l[t][r]=__expf(cuml[63][r]-cuml[t][r])*dtl[t][r]; }
  __syncthreads();
  const int r=tid>>5, d=tid&31;
  f32 acc[16]={};
  for(int s=0;s<64;s++){
    f32 m=xs[s][r*32+d]*w3l[s][r];
    #pragma unroll
    for(int n4=0;n4<4;n4++){
      float4 b4=((float4*)&Bt[s][0])[n4];
      acc[n4*4+0]+=m*b4.x; acc[n4*4+1]+=m*b4.y; acc[n4*4+2]+=m*b4.z; acc[n4*4+3]+=m*b4.w;
    }
  }
  f32* o=&S[(((size_t)(b*64+c))*24+dir*6+r)*512 + d*16];
  #pragma unroll
  for(int n4=0;n4<4;n4++){ float4 v={acc[n4*4+0],acc[n4*4+1],acc[n4*4+2],acc[n4*4+3]}; ((float4*)o)[n4]=v; }
}

// ---------------- Kernel D2: serial inter-chunk scan (in-place S -> prev) ------
__global__ __launch_bounds__(256) void k_scan(f32* __restrict__ S, const f32* __restrict__ ach){
  const int g=blockIdx.x*256+threadIdx.x;        // 98304 = 8*24*32*16
  const int b=g/12288, rem=g%12288, h=rem/512;
  size_t base=(size_t)b*786432 + rem;
  const f32* ap=&ach[(size_t)b*1536 + h];
  f32 st=0.f;
  for(int c=0;c<64;c++){
    f32 a=ap[c*24];
    f32 s=S[base+(size_t)c*12288];
    S[base+(size_t)c*12288]=st;
    st=a*st+s;
  }
}

// ---------------- Kernel D3 (MFMA): y = [CBtri|C] @ [x.w1 ; prevT], row-scaled --
// grid (64 chunks, 8 batch, 2 dirs), 384 thr = 6 waves = 6 heads.
#define LDK 104
__global__ __launch_bounds__(384) void k_chunk2(const f32* __restrict__ xh, const f32* __restrict__ Bg,
      const f32* __restrict__ Cg, const f32* __restrict__ dt_sp, const f32* __restrict__ Sprev,
      const f32* __restrict__ Alogs, const f32* __restrict__ Dsw,
      f32* __restrict__ ym0, f32* __restrict__ ym1, const int dirbase){
  __shared__ unsigned short Alds[64*LDK];     // A[t][k] bf16, k<64: CB tri, 64..79: Ct, 80..95: 0
  __shared__ unsigned short Blds[192*LDK];    // B'[ch][k] bf16, k<64: x[k][ch]*w1, 64..79: prevT, 80..95: 0
  __shared__ f32 Bt[64][16];
  __shared__ f32 CtP[64][21];
  __shared__ f32 dtl[64][6], cuml[64][6], erowl[64][6];
  const int c=blockIdx.x, b=blockIdx.y, dir=dirbase+blockIdx.z, c0=c*64, tid=threadIdx.x;
  f32* __restrict__ ym = (dir&1)? ym1 : ym0;
  // ---- phase 1: stage dt, Bt, CtP
  { int r=tid/6, q=tid-r*6; size_t pix=(size_t)b*4096+pos_of(dir,c0+r);
    dtl[r][q]=dt_sp[pix*24+dir*6+q]; }               // 384 threads cover 64x6 exactly
  for(int i=tid;i<256;i+=384){
    int r=i>>2,q=i&3; size_t pix=(size_t)b*4096+pos_of(dir,c0+r);
    ((float4*)&Bt[r][0])[q]=((const float4*)&Bg[(pix*4+dir)*16])[q];
    float4 cv=((const float4*)&Cg[(pix*4+dir)*16])[q];
    CtP[r][q*4+0]=cv.x; CtP[r][q*4+1]=cv.y; CtP[r][q*4+2]=cv.z; CtP[r][q*4+3]=cv.w;
  }
  __syncthreads();
  // ---- phase 2: per-head cumsum
  if(tid<6){
    f32 A=-__expf(Alogs[dir*6+tid]);
    f32 run=0.f;
    for(int t=0;t<64;t++){ run+=dtl[t][tid]*A; cuml[t][tid]=run; }
  }
  __syncthreads();
  // ---- phase 3: build everything in LDS
  { int t=tid&63, r=tid>>6; erowl[t][r]=__expf(cuml[t][r]); }
  // zero A cols 80..95
  if(tid<256){ int t=tid>>2, g=tid&3; u16x4 zz={0,0,0,0}; *(u16x4*)&Alds[t*LDK+80+g*4]=zz; }
  // zero B rows(k) 80..95
  for(int i=tid;i<768;i+=384){ int ch=i>>2, g=i&3; u16x4 zz={0,0,0,0}; *(u16x4*)&Blds[ch*LDK+80+g*4]=zz; }
  // prevT rows 64..79
  {
    const size_t pbase=(((size_t)(b*64+c))*24 + dir*6)*512;
    for(int i=tid;i<768;i+=384){
      int ch=i>>2, ng=i&3, head=ch>>5, d=ch&31;
      float4 pv=*(const float4*)&Sprev[pbase + (size_t)head*512 + d*16 + ng*4];
      u16x4 w={f2bf(pv.x),f2bf(pv.y),f2bf(pv.z),f2bf(pv.w)};
      *(u16x4*)&Blds[ch*LDK+64+ng*4]=w;
    }
  }
  // A: CB triangular
  for(int i=tid;i<4096;i+=384){
    int t=i&63, s=i>>6;
    f32 v=0.f;
    if(s<=t){
      #pragma unroll
      for(int n=0;n<16;n++) v+=CtP[t][n]*Bt[s][n];
    }
    Alds[t*LDK+s]=f2bf(v);
  }
  // A: Ct columns 64..79
  for(int i=tid;i<1024;i+=384){ int t=i&63, n=i>>6; Alds[t*LDK+64+n]=f2bf(CtP[t][n]); }
  // B': x * w1 (reg-transpose, 4x4 blocks)
  for(int u=tid;u<768;u+=384){
    int sg=u/48, q=u-sg*48, head=q>>3;
    f32 v[4][4];
    #pragma unroll
    for(int j=0;j<4;j++){
      int s=sg*4+j;
      float4 xv=((const float4*)&xh[(size_t)(b*4096+pos_of(dir,c0+s))*192])[q];
      f32 w1=__expf(-cuml[s][head])*dtl[s][head];
      v[j][0]=xv.x*w1; v[j][1]=xv.y*w1; v[j][2]=xv.z*w1; v[j][3]=xv.w*w1;
    }
    #pragma unroll
    for(int cc=0;cc<4;cc++){
      int ch=4*q+cc;
      u16x4 w={f2bf(v[0][cc]),f2bf(v[1][cc]),f2bf(v[2][cc]),f2bf(v[3][cc])};
      *(u16x4*)&Blds[ch*LDK+sg*4]=w;
    }
  }
  __syncthreads();
  // ---- phase 4: MFMA 64x192x96 (per wave: 64x32)
  const int wv=tid>>6, lane=tid&63, l15=lane&15, l4=lane>>4;
  f32x4 acc[4][2];
  #pragma unroll
  for(int mt=0;mt<4;mt++){ f32x4 zz={0.f,0.f,0.f,0.f}; acc[mt][0]=zz; acc[mt][1]=zz; }
  #pragma unroll
  for(int ks=0;ks<3;ks++){
    const int kg=ks*4+l4;                       // granule = k/8
    bf16x8 af[4], bfr[2];
    #pragma unroll
    for(int mt=0;mt<4;mt++) af[mt]=*(const bf16x8*)&Alds[(mt*16+l15)*LDK + kg*8];
    #pragma unroll
    for(int nt=0;nt<2;nt++) bfr[nt]=*(const bf16x8*)&Blds[(wv*32+nt*16+l15)*LDK + kg*8];
    #pragma unroll
    for(int mt=0;mt<4;mt++){
      acc[mt][0]=__builtin_amdgcn_mfma_f32_16x16x32_bf16(af[mt],bfr[0],acc[mt][0],0,0,0);
      acc[mt][1]=__builtin_amdgcn_mfma_f32_16x16x32_bf16(af[mt],bfr[1],acc[mt][1],0,0,0);
    }
  }
  // ---- epilogue: row scale + D*x, store/accum
  const f32 Dv0=Dsw[(dir*6+wv)*32 + l15];
  const f32 Dv1=Dsw[(dir*6+wv)*32 + 16 + l15];
  const int ch0=wv*32+l15, ch1=ch0+16;
  #pragma unroll
  for(int mt=0;mt<4;mt++){
    #pragma unroll
    for(int r=0;r<4;r++){
      int t=mt*16+l4*4+r;
      f32 er=erowl[t][wv];
      f32 xr=er/dtl[t][wv];                     // 1/w1[t]
      size_t orow=((size_t)(b*4096+pos_of(dir,c0+t)))*192;
      f32 x0=bfr2f(Blds[ch0*LDK+t])*xr;
      f32 x1=bfr2f(Blds[ch1*LDK+t])*xr;
      f32 v0=acc[mt][0][r]*er + Dv0*x0;
      f32 v1=acc[mt][1][r]*er + Dv1*x1;
      if(dirbase==0){ ym[orow+ch0]=v0; ym[orow+ch1]=v1; }
      else          { ym[orow+ch0]+=v0; ym[orow+ch1]+=v1; }
    }
  }
}

// ---------------- Kernel E: layernorm(192) of (ym0+ym1) then * z ----------------
__global__ __launch_bounds__(256) void k_ln(const f32* __restrict__ ym0, const f32* __restrict__ ym1,
                                            f32* __restrict__ z,
                                            const f32* __restrict__ lw, const f32* __restrict__ lb){
  const int row=blockIdx.x*4+(threadIdx.x>>6), lane=threadIdx.x&63;
  const f32* yr0=&ym0[(size_t)row*192];
  const f32* yr1=&ym1[(size_t)row*192];
  f32 v0=yr0[lane]+yr1[lane], v1=yr0[lane+64]+yr1[lane+64], v2=yr0[lane+128]+yr1[lane+128];
  f32 s=v0+v1+v2;
  #pragma unroll
  for(int off=32;off>0;off>>=1) s+=__shfl_xor(s,off,64);
  const f32 mu=s*(1.f/192.f);
  f32 d0=v0-mu,d1=v1-mu,d2=v2-mu;
  f32 q=d0*d0+d1*d1+d2*d2;
  #pragma unroll
  for(int off=32;off>0;off>>=1) q+=__shfl_xor(q,off,64);
  const f32 rs=rsqrtf(q*(1.f/192.f)+1e-5f);
  f32* zr=&z[(size_t)row*192];
  zr[lane]    =(d0*rs*lw[lane]    +lb[lane])    *zr[lane];
  zr[lane+64] =(d1*rs*lw[lane+64] +lb[lane+64]) *zr[lane+64];
  zr[lane+128]=(d2*rs*lw[lane+128]+lb[lane+128])*zr[lane+128];
}

// ---------------- Kernel F: out = u @ out_proj_w.T (fp32 out) ------------------
__global__ __launch_bounds__(256) void k_outproj(const f32* __restrict__ u, const f32* __restrict__ w,
                                                 f32* __restrict__ out){
  __shared__ f32 As[32][68];
  __shared__ f32 Bs[32][68];
  const int m0=blockIdx.x*64, n0=blockIdx.y*64;
  const int tid=threadIdx.x, tx=tid&15, ty=tid>>4;
  f32 acc[4][4]={};
  for(int k0=0;k0<192;k0+=32){
    for(int i=tid;i<2048;i+=256){int r=i>>5,kk=i&31; As[kk][r]=u[(size_t)(m0+r)*192+k0+kk]; }
    for(int i=tid;i<2048;i+=256){int r=i>>5,kk=i&31; int n=n0+r; Bs[kk][r]=(n<96)? w[(size_t)n*192+k0+kk] : 0.f; }
    __syncthreads();
    #pragma unroll
    for(int kk=0;kk<32;kk++){
      float4 a4=*(float4*)&As[kk][ty*4];
      float4 b4=*(float4*)&Bs[kk][tx*4];
      f32 a[4]={a4.x,a4.y,a4.z,a4.w}, bb[4]={b4.x,b4.y,b4.z,b4.w};
      #pragma unroll
      for(int i=0;i<4;i++)
        #pragma unroll
        for(int j=0;j<4;j++) acc[i][j]+=a[i]*bb[j];
    }
    __syncthreads();
  }
  #pragma unroll
  for(int i=0;i<4;i++){
    int row=m0+ty*4+i;
    #pragma unroll
    for(int j=0;j<4;j++){
      int col=n0+tx*4+j;
      if(col<96) out[(size_t)row*96+col]=acc[i][j];
    }
  }
}

extern "C" void kernel_launch(void* const* d_in, const int* in_sizes, int n_in,
                              void* d_out, int out_size, void* d_ws, size_t ws_size,
                              hipStream_t stream){
  const f32* x  =(const f32*)d_in[0];
  const f32* ipw=(const f32*)d_in[1];
  const f32* cw =(const f32*)d_in[2];
  const f32* cb =(const f32*)d_in[3];
  const f32* xpw=(const f32*)d_in[4];
  const f32* alg=(const f32*)d_in[5];
  const f32* dsw=(const f32*)d_in[6];
  const f32* dtb=(const f32*)d_in[7];
  const f32* lw =(const f32*)d_in[8];
  const f32* lb =(const f32*)d_in[9];
  const f32* opw=(const f32*)d_in[10];
  f32* out=(f32*)d_out;
  f32* ws=(f32*)d_ws;

  f32* xh_raw=ws;               // 6291456 floats (reused as ym0)
  f32* z     =ws+ 6291456;      // 6291456
  f32* xh    =ws+12582912;      // 6291456
  f32* dt_sp =ws+18874368;      //  786432
  f32* Bg    =ws+19660800;      // 2097152
  f32* Cg    =ws+21757952;      // 2097152
  f32* S     =ws+23855104;      // 6291456
  f32* ach   =ws+30146560;      //   12288
  f32* ym1   =ws+30158848;      // 6291456  (total 36450304 floats = 145.8 MB)
  f32* ym0=xh_raw;

  k_inproj<<<dim3(512,6),256,0,stream>>>(x,ipw,xh_raw,z);
  k_conv<<<6144,256,0,stream>>>(xh_raw,cw,cb,xh);
  k_xdbl<<<dim3(512),256,0,stream>>>(xh,xpw,dtb,dt_sp,Bg,Cg);
  k_chunk1<<<dim3(64,4,8),192,0,stream>>>(xh,Bg,dt_sp,alg,S,ach);
  k_scan<<<384,256,0,stream>>>(S,ach);
  k_chunk2<<<dim3(64,8,2),384,0,stream>>>(xh,Bg,Cg,dt_sp,S,alg,dsw,ym0,ym1,0);
  k_chunk2<<<dim3(64,8,2),384,0,stream>>>(xh,Bg,Cg,dt_sp,S,alg,dsw,ym0,ym1,2);
  k_ln<<<8192,256,0,stream>>>(ym0,ym1,z,lw,lb);
  k_outproj<<<dim3(512,2),256,0,stream>>>(z,opw,out);
}

// Round 5
// 328.259 us; speedup vs baseline: 1.7374x; 1.2016x over previous
//
#include <hip/hip_runtime.h>
#include <hip/hip_bf16.h>

using bf16 = __hip_bfloat16;
typedef float f32;
typedef __attribute__((ext_vector_type(8))) short bf16x8;
typedef __attribute__((ext_vector_type(4))) float f32x4;
typedef __attribute__((ext_vector_type(4))) unsigned short u16x4;
typedef __attribute__((ext_vector_type(8))) unsigned short u16x8;

static __device__ __forceinline__ f32 b2f(bf16 v){ return __bfloat162float(v); }
static __device__ __forceinline__ f32 siluf(f32 v){ return v / (1.f + __expf(-v)); }
static __device__ __forceinline__ unsigned short f2bf(f32 v){
  __hip_bfloat16 h=__float2bfloat16(v); return *(unsigned short*)&h;
}
static __device__ __forceinline__ f32 bfr2f(unsigned short u){
  unsigned int x=((unsigned int)u)<<16; return __uint_as_float(x);
}

// spatial position of sequence index p for scan direction dir (H=W=64, L=4096)
static __device__ __forceinline__ int pos_of(int dir, int p){
  if(dir==0) return p;
  if(dir==1) return ((p&63)<<6) | (p>>6);
  if(dir==2) return 4095-p;
  int q = 4095-p; return ((q&63)<<6) | (q>>6);
}

// ---------------- Kernel A: xz = x @ in_proj_w.T ; split -> xh_raw, z=silu ----
__global__ __launch_bounds__(256) void k_inproj(const f32* __restrict__ x, const f32* __restrict__ w,
                                                f32* __restrict__ xh_raw, f32* __restrict__ z){
  __shared__ f32 As[32][68];
  __shared__ f32 Bs[32][68];
  const int m0=blockIdx.x*64, n0=blockIdx.y*64;
  const int tid=threadIdx.x, tx=tid&15, ty=tid>>4;
  f32 acc[4][4]={};
  for(int k0=0;k0<96;k0+=32){
    for(int i=tid;i<2048;i+=256){int r=i>>5,kk=i&31; As[kk][r]=x[(size_t)(m0+r)*96+k0+kk]; }
    for(int i=tid;i<2048;i+=256){int r=i>>5,kk=i&31; Bs[kk][r]=w[(size_t)(n0+r)*96+k0+kk]; }
    __syncthreads();
    #pragma unroll
    for(int kk=0;kk<32;kk++){
      float4 a4=*(float4*)&As[kk][ty*4];
      float4 b4=*(float4*)&Bs[kk][tx*4];
      f32 a[4]={a4.x,a4.y,a4.z,a4.w}, b[4]={b4.x,b4.y,b4.z,b4.w};
      #pragma unroll
      for(int i=0;i<4;i++)
        #pragma unroll
        for(int j=0;j<4;j++) acc[i][j]+=a[i]*b[j];
    }
    __syncthreads();
  }
  #pragma unroll
  for(int i=0;i<4;i++){
    int row=m0+ty*4+i;
    #pragma unroll
    for(int j=0;j<4;j++){
      int col=n0+tx*4+j; f32 v=acc[i][j];
      if(col<192) xh_raw[(size_t)row*192+col]=v;
      else        z[(size_t)row*192+(col-192)]=siluf(v);
    }
  }
}

// ---------------- Kernel B: depthwise 3x3 conv + bias + silu --------------------
__global__ __launch_bounds__(256) void k_conv(const f32* __restrict__ xh_raw, const f32* __restrict__ cw,
                                              const f32* __restrict__ cb, f32* __restrict__ xh){
  __shared__ f32 wsm[192][9];
  __shared__ f32 bsm[192];
  const int tid=threadIdx.x;
  for(int i=tid;i<1728;i+=256) wsm[i/9][i%9]=cw[i];
  for(int i=tid;i<192;i+=256) bsm[i]=cb[i];
  __syncthreads();
  const int idx=blockIdx.x*256+tid;
  const int c4=idx%48, j=(idx/48)&63, ii0=(idx/3072)&63, b=idx/196608;
  const int c0=c4*4;
  f32 acc[4]={bsm[c0],bsm[c0+1],bsm[c0+2],bsm[c0+3]};
  #pragma unroll
  for(int a=0;a<3;a++){
    int ii=ii0+a-1; if(ii<0||ii>63) continue;
    #pragma unroll
    for(int bb=0;bb<3;bb++){
      int jj=j+bb-1; if(jj<0||jj>63) continue;
      float4 v=*(const float4*)&xh_raw[((size_t)(b*4096)+(ii*64+jj))*192 + c0];
      int t=a*3+bb;
      acc[0]+=v.x*wsm[c0][t]; acc[1]+=v.y*wsm[c0+1][t];
      acc[2]+=v.z*wsm[c0+2][t]; acc[3]+=v.w*wsm[c0+3][t];
    }
  }
  float4 o; o.x=siluf(acc[0]); o.y=siluf(acc[1]); o.z=siluf(acc[2]); o.w=siluf(acc[3]);
  ((float4*)xh)[idx]=o;
}

// ---------------- Kernel W: xpw fp32 -> bf16 fragment-contiguous layout --------
// Wfrag[((nt*24+g)*16 + l)*8 + j] = W[n= nt*16+l][k= g*8+j], zero-padded cc>=38
__global__ __launch_bounds__(256) void k_wcvt(const f32* __restrict__ xpw, unsigned short* __restrict__ Wfrag){
  const int i=blockIdx.x*256+threadIdx.x;      // 3840 granule tasks
  if(i>=3840) return;
  const int g=i%24, n=i/24;
  const int nt=n>>4, l=n&15;
  const int dir=n/40, cc=n-dir*40;
  u16x8 w;
  if(cc<38){
    const f32* p=&xpw[(size_t)dir*7296 + cc*192 + g*8];
    #pragma unroll
    for(int j=0;j<8;j++) w[j]=f2bf(p[j]);
  } else {
    #pragma unroll
    for(int j=0;j<8;j++) w[j]=0;
  }
  *(u16x8*)&Wfrag[((size_t)(nt*24+g)*16+l)*8]=w;
}

// ---------------- Kernel C (MFMA): x_dbl = xh @ Wfrag^T -> dt(softplus), B, C --
// M=32768 (BM=64/block, 4 waves x 1 m-tile), N=160, K=192 (6 steps).
__global__ __launch_bounds__(256) void k_xdbl(const f32* __restrict__ xh, const unsigned short* __restrict__ Wfrag,
                                              const f32* __restrict__ dtb, f32* __restrict__ dt_sp,
                                              f32* __restrict__ Bg, f32* __restrict__ Cg){
  __shared__ unsigned short Ald[24*64*8];      // 24 KB, granule layout (g*64+r)*8
  const int m0=blockIdx.x*64;
  const int tid=threadIdx.x;
  // stage A: xh[m0..m0+63][0..191] -> bf16 granules
  for(int i=tid;i<1536;i+=256){
    int r=i&63, g=i>>6;
    const f32* p=&xh[(size_t)(m0+r)*192 + g*8];
    float4 v0=*(const float4*)p, v1=*(const float4*)(p+4);
    u16x8 w={f2bf(v0.x),f2bf(v0.y),f2bf(v0.z),f2bf(v0.w),
             f2bf(v1.x),f2bf(v1.y),f2bf(v1.z),f2bf(v1.w)};
    *(u16x8*)&Ald[(size_t)(g*64+r)*8]=w;
  }
  __syncthreads();
  const int wv=tid>>6, lane=tid&63, l15=lane&15, l4=lane>>4;
  f32x4 acc[10];
  #pragma unroll
  for(int nt=0;nt<10;nt++){ f32x4 zz={0.f,0.f,0.f,0.f}; acc[nt]=zz; }
  #pragma unroll
  for(int ks=0;ks<6;ks++){
    const int g=ks*4+l4;
    bf16x8 a=*(const bf16x8*)&Ald[(size_t)(g*64 + wv*16 + l15)*8];
    #pragma unroll
    for(int nt=0;nt<10;nt++){
      bf16x8 bfr=*(const bf16x8*)&Wfrag[((size_t)(nt*24+g)*16+l15)*8];
      acc[nt]=__builtin_amdgcn_mfma_f32_16x16x32_bf16(a,bfr,acc[nt],0,0,0);
    }
  }
  // epilogue: scatter dt/B/C
  const int rowb=m0 + wv*16 + l4*4;
  #pragma unroll
  for(int nt=0;nt<10;nt++){
    int n=nt*16+l15, dir=n/40, cc=n-dir*40;
    if(cc>=38) continue;
    #pragma unroll
    for(int r=0;r<4;r++){
      size_t pix=(size_t)(rowb+r);
      f32 v=acc[nt][r];
      if(cc<6){ f32 xv=v+dtb[dir*6+cc]; dt_sp[pix*24+dir*6+cc]=(xv>20.f)? xv : log1pf(__expf(xv)); }
      else if(cc<22){ Bg[(pix*4+dir)*16+(cc-6)]=v; }
      else          { Cg[(pix*4+dir)*16+(cc-22)]=v; }
    }
  }
}

// ---------------- Kernel D1: per (chunk, dir, b): cumsum, a_chunk, S_loc --------
__global__ __launch_bounds__(192) void k_chunk1(const f32* __restrict__ xh, const f32* __restrict__ Bg,
      const f32* __restrict__ dt_sp, const f32* __restrict__ Alogs, f32* __restrict__ S, f32* __restrict__ ach){
  __shared__ f32 xs[64][192];
  __shared__ f32 Bt[64][16];
  __shared__ f32 dtl[64][6], cuml[64][6], w3l[64][6];
  const int c=blockIdx.x, dir=blockIdx.y, b=blockIdx.z, c0=c*64, tid=threadIdx.x;
  for(int i=tid;i<3072;i+=192){int r=i/48,q=i%48; ((float4*)&xs[r][0])[q]=((const float4*)&xh[(size_t)(b*4096+pos_of(dir,c0+r))*192])[q]; }
  for(int i=tid;i<256;i+=192){int r=i>>2,q=i&3; size_t pix=(size_t)b*4096+pos_of(dir,c0+r);
      ((float4*)&Bt[r][0])[q]=((const float4*)&Bg[(pix*4+dir)*16])[q]; }
  for(int i=tid;i<384;i+=192){int r=i/6,q=i%6; size_t pix=(size_t)b*4096+pos_of(dir,c0+r);
      dtl[r][q]=dt_sp[pix*24+dir*6+q]; }
  __syncthreads();
  if(tid<6){
    f32 A=-__expf(Alogs[dir*6+tid]);
    f32 run=0.f;
    for(int t=0;t<64;t++){ run+=dtl[t][tid]*A; cuml[t][tid]=run; }
    ach[((size_t)(b*64+c))*24+dir*6+tid]=__expf(run);
  }
  __syncthreads();
  for(int i=tid;i<384;i+=192){int t=i&63,r=i>>6; w3l[t][r]=__expf(cuml[63][r]-cuml[t][r])*dtl[t][r]; }
  __syncthreads();
  const int r=tid>>5, d=tid&31;
  f32 acc[16]={};
  for(int s=0;s<64;s++){
    f32 m=xs[s][r*32+d]*w3l[s][r];
    #pragma unroll
    for(int n4=0;n4<4;n4++){
      float4 b4=((float4*)&Bt[s][0])[n4];
      acc[n4*4+0]+=m*b4.x; acc[n4*4+1]+=m*b4.y; acc[n4*4+2]+=m*b4.z; acc[n4*4+3]+=m*b4.w;
    }
  }
  f32* o=&S[(((size_t)(b*64+c))*24+dir*6+r)*512 + d*16];
  #pragma unroll
  for(int n4=0;n4<4;n4++){ float4 v={acc[n4*4+0],acc[n4*4+1],acc[n4*4+2],acc[n4*4+3]}; ((float4*)o)[n4]=v; }
}

// ---------------- Kernel D2: serial inter-chunk scan (in-place S -> prev) ------
__global__ __launch_bounds__(256) void k_scan(f32* __restrict__ S, const f32* __restrict__ ach){
  const int g=blockIdx.x*256+threadIdx.x;        // 98304 = 8*24*32*16
  const int b=g/12288, rem=g%12288, h=rem/512;
  size_t base=(size_t)b*786432 + rem;
  const f32* ap=&ach[(size_t)b*1536 + h];
  f32 st=0.f;
  for(int c=0;c<64;c++){
    f32 a=ap[c*24];
    f32 s=S[base+(size_t)c*12288];
    S[base+(size_t)c*12288]=st;
    st=a*st+s;
  }
}

// ---------------- Kernel D3 (MFMA): y = [CBtri|C] @ [x.w1 ; prevT], row-scaled --
#define LDK 104
__global__ __launch_bounds__(384) void k_chunk2(const f32* __restrict__ xh, const f32* __restrict__ Bg,
      const f32* __restrict__ Cg, const f32* __restrict__ dt_sp, const f32* __restrict__ Sprev,
      const f32* __restrict__ Alogs, const f32* __restrict__ Dsw,
      f32* __restrict__ ym0, f32* __restrict__ ym1, const int dirbase){
  __shared__ unsigned short Alds[64*LDK];
  __shared__ unsigned short Blds[192*LDK];
  __shared__ f32 Bt[64][16];
  __shared__ f32 CtP[64][21];
  __shared__ f32 dtl[64][6], cuml[64][6], erowl[64][6];
  const int c=blockIdx.x, b=blockIdx.y, dir=dirbase+blockIdx.z, c0=c*64, tid=threadIdx.x;
  f32* __restrict__ ym = (dir&1)? ym1 : ym0;
  { int r=tid/6, q=tid-r*6; size_t pix=(size_t)b*4096+pos_of(dir,c0+r);
    dtl[r][q]=dt_sp[pix*24+dir*6+q]; }
  for(int i=tid;i<256;i+=384){
    int r=i>>2,q=i&3; size_t pix=(size_t)b*4096+pos_of(dir,c0+r);
    ((float4*)&Bt[r][0])[q]=((const float4*)&Bg[(pix*4+dir)*16])[q];
    float4 cv=((const float4*)&Cg[(pix*4+dir)*16])[q];
    CtP[r][q*4+0]=cv.x; CtP[r][q*4+1]=cv.y; CtP[r][q*4+2]=cv.z; CtP[r][q*4+3]=cv.w;
  }
  __syncthreads();
  if(tid<6){
    f32 A=-__expf(Alogs[dir*6+tid]);
    f32 run=0.f;
    for(int t=0;t<64;t++){ run+=dtl[t][tid]*A; cuml[t][tid]=run; }
  }
  __syncthreads();
  { int t=tid&63, r=tid>>6; erowl[t][r]=__expf(cuml[t][r]); }
  if(tid<256){ int t=tid>>2, g=tid&3; u16x4 zz={0,0,0,0}; *(u16x4*)&Alds[t*LDK+80+g*4]=zz; }
  for(int i=tid;i<768;i+=384){ int ch=i>>2, g=i&3; u16x4 zz={0,0,0,0}; *(u16x4*)&Blds[ch*LDK+80+g*4]=zz; }
  {
    const size_t pbase=(((size_t)(b*64+c))*24 + dir*6)*512;
    for(int i=tid;i<768;i+=384){
      int ch=i>>2, ng=i&3, head=ch>>5, d=ch&31;
      float4 pv=*(const float4*)&Sprev[pbase + (size_t)head*512 + d*16 + ng*4];
      u16x4 w={f2bf(pv.x),f2bf(pv.y),f2bf(pv.z),f2bf(pv.w)};
      *(u16x4*)&Blds[ch*LDK+64+ng*4]=w;
    }
  }
  for(int i=tid;i<4096;i+=384){
    int t=i&63, s=i>>6;
    f32 v=0.f;
    if(s<=t){
      #pragma unroll
      for(int n=0;n<16;n++) v+=CtP[t][n]*Bt[s][n];
    }
    Alds[t*LDK+s]=f2bf(v);
  }
  for(int i=tid;i<1024;i+=384){ int t=i&63, n=i>>6; Alds[t*LDK+64+n]=f2bf(CtP[t][n]); }
  for(int u=tid;u<768;u+=384){
    int sg=u/48, q=u-sg*48, head=q>>3;
    f32 v[4][4];
    #pragma unroll
    for(int j=0;j<4;j++){
      int s=sg*4+j;
      float4 xv=((const float4*)&xh[(size_t)(b*4096+pos_of(dir,c0+s))*192])[q];
      f32 w1=__expf(-cuml[s][head])*dtl[s][head];
      v[j][0]=xv.x*w1; v[j][1]=xv.y*w1; v[j][2]=xv.z*w1; v[j][3]=xv.w*w1;
    }
    #pragma unroll
    for(int cc=0;cc<4;cc++){
      int ch=4*q+cc;
      u16x4 w={f2bf(v[0][cc]),f2bf(v[1][cc]),f2bf(v[2][cc]),f2bf(v[3][cc])};
      *(u16x4*)&Blds[ch*LDK+sg*4]=w;
    }
  }
  __syncthreads();
  const int wv=tid>>6, lane=tid&63, l15=lane&15, l4=lane>>4;
  f32x4 acc[4][2];
  #pragma unroll
  for(int mt=0;mt<4;mt++){ f32x4 zz={0.f,0.f,0.f,0.f}; acc[mt][0]=zz; acc[mt][1]=zz; }
  #pragma unroll
  for(int ks=0;ks<3;ks++){
    const int kg=ks*4+l4;
    bf16x8 af[4], bfr[2];
    #pragma unroll
    for(int mt=0;mt<4;mt++) af[mt]=*(const bf16x8*)&Alds[(mt*16+l15)*LDK + kg*8];
    #pragma unroll
    for(int nt=0;nt<2;nt++) bfr[nt]=*(const bf16x8*)&Blds[(wv*32+nt*16+l15)*LDK + kg*8];
    #pragma unroll
    for(int mt=0;mt<4;mt++){
      acc[mt][0]=__builtin_amdgcn_mfma_f32_16x16x32_bf16(af[mt],bfr[0],acc[mt][0],0,0,0);
      acc[mt][1]=__builtin_amdgcn_mfma_f32_16x16x32_bf16(af[mt],bfr[1],acc[mt][1],0,0,0);
    }
  }
  const f32 Dv0=Dsw[(dir*6+wv)*32 + l15];
  const f32 Dv1=Dsw[(dir*6+wv)*32 + 16 + l15];
  const int ch0=wv*32+l15, ch1=ch0+16;
  #pragma unroll
  for(int mt=0;mt<4;mt++){
    #pragma unroll
    for(int r=0;r<4;r++){
      int t=mt*16+l4*4+r;
      f32 er=erowl[t][wv];
      f32 xr=er/dtl[t][wv];
      size_t orow=((size_t)(b*4096+pos_of(dir,c0+t)))*192;
      f32 x0=bfr2f(Blds[ch0*LDK+t])*xr;
      f32 x1=bfr2f(Blds[ch1*LDK+t])*xr;
      f32 v0=acc[mt][0][r]*er + Dv0*x0;
      f32 v1=acc[mt][1][r]*er + Dv1*x1;
      if(dirbase==0){ ym[orow+ch0]=v0; ym[orow+ch1]=v1; }
      else          { ym[orow+ch0]+=v0; ym[orow+ch1]+=v1; }
    }
  }
}

// ---------------- Kernel E: layernorm(192) of (ym0+ym1) then * z ----------------
__global__ __launch_bounds__(256) void k_ln(const f32* __restrict__ ym0, const f32* __restrict__ ym1,
                                            f32* __restrict__ z,
                                            const f32* __restrict__ lw, const f32* __restrict__ lb){
  const int row=blockIdx.x*4+(threadIdx.x>>6), lane=threadIdx.x&63;
  const f32* yr0=&ym0[(size_t)row*192];
  const f32* yr1=&ym1[(size_t)row*192];
  f32 v0=yr0[lane]+yr1[lane], v1=yr0[lane+64]+yr1[lane+64], v2=yr0[lane+128]+yr1[lane+128];
  f32 s=v0+v1+v2;
  #pragma unroll
  for(int off=32;off>0;off>>=1) s+=__shfl_xor(s,off,64);
  const f32 mu=s*(1.f/192.f);
  f32 d0=v0-mu,d1=v1-mu,d2=v2-mu;
  f32 q=d0*d0+d1*d1+d2*d2;
  #pragma unroll
  for(int off=32;off>0;off>>=1) q+=__shfl_xor(q,off,64);
  const f32 rs=rsqrtf(q*(1.f/192.f)+1e-5f);
  f32* zr=&z[(size_t)row*192];
  zr[lane]    =(d0*rs*lw[lane]    +lb[lane])    *zr[lane];
  zr[lane+64] =(d1*rs*lw[lane+64] +lb[lane+64]) *zr[lane+64];
  zr[lane+128]=(d2*rs*lw[lane+128]+lb[lane+128])*zr[lane+128];
}

// ---------------- Kernel F: out = u @ out_proj_w.T (fp32 out) ------------------
__global__ __launch_bounds__(256) void k_outproj(const f32* __restrict__ u, const f32* __restrict__ w,
                                                 f32* __restrict__ out){
  __shared__ f32 As[32][68];
  __shared__ f32 Bs[32][68];
  const int m0=blockIdx.x*64, n0=blockIdx.y*64;
  const int tid=threadIdx.x, tx=tid&15, ty=tid>>4;
  f32 acc[4][4]={};
  for(int k0=0;k0<192;k0+=32){
    for(int i=tid;i<2048;i+=256){int r=i>>5,kk=i&31; As[kk][r]=u[(size_t)(m0+r)*192+k0+kk]; }
    for(int i=tid;i<2048;i+=256){int r=i>>5,kk=i&31; int n=n0+r; Bs[kk][r]=(n<96)? w[(size_t)n*192+k0+kk] : 0.f; }
    __syncthreads();
    #pragma unroll
    for(int kk=0;kk<32;kk++){
      float4 a4=*(float4*)&As[kk][ty*4];
      float4 b4=*(float4*)&Bs[kk][tx*4];
      f32 a[4]={a4.x,a4.y,a4.z,a4.w}, bb[4]={b4.x,b4.y,b4.z,b4.w};
      #pragma unroll
      for(int i=0;i<4;i++)
        #pragma unroll
        for(int j=0;j<4;j++) acc[i][j]+=a[i]*bb[j];
    }
    __syncthreads();
  }
  #pragma unroll
  for(int i=0;i<4;i++){
    int row=m0+ty*4+i;
    #pragma unroll
    for(int j=0;j<4;j++){
      int col=n0+tx*4+j;
      if(col<96) out[(size_t)row*96+col]=acc[i][j];
    }
  }
}

extern "C" void kernel_launch(void* const* d_in, const int* in_sizes, int n_in,
                              void* d_out, int out_size, void* d_ws, size_t ws_size,
                              hipStream_t stream){
  const f32* x  =(const f32*)d_in[0];
  const f32* ipw=(const f32*)d_in[1];
  const f32* cw =(const f32*)d_in[2];
  const f32* cb =(const f32*)d_in[3];
  const f32* xpw=(const f32*)d_in[4];
  const f32* alg=(const f32*)d_in[5];
  const f32* dsw=(const f32*)d_in[6];
  const f32* dtb=(const f32*)d_in[7];
  const f32* lw =(const f32*)d_in[8];
  const f32* lb =(const f32*)d_in[9];
  const f32* opw=(const f32*)d_in[10];
  f32* out=(f32*)d_out;
  f32* ws=(f32*)d_ws;

  f32* xh_raw=ws;               // 6291456 floats (reused as ym0)
  f32* z     =ws+ 6291456;      // 6291456
  f32* xh    =ws+12582912;      // 6291456
  f32* dt_sp =ws+18874368;      //  786432
  f32* Bg    =ws+19660800;      // 2097152
  f32* Cg    =ws+21757952;      // 2097152
  f32* S     =ws+23855104;      // 6291456
  f32* ach   =ws+30146560;      //   12288
  f32* ym1   =ws+30158848;      // 6291456
  unsigned short* Wfrag=(unsigned short*)(ws+36450304);  // 30720 bf16 = 15360 floats
  f32* ym0=xh_raw;

  k_inproj<<<dim3(512,6),256,0,stream>>>(x,ipw,xh_raw,z);
  k_wcvt<<<15,256,0,stream>>>(xpw,Wfrag);
  k_conv<<<6144,256,0,stream>>>(xh_raw,cw,cb,xh);
  k_xdbl<<<dim3(512),256,0,stream>>>(xh,Wfrag,dtb,dt_sp,Bg,Cg);
  k_chunk1<<<dim3(64,4,8),192,0,stream>>>(xh,Bg,dt_sp,alg,S,ach);
  k_scan<<<384,256,0,stream>>>(S,ach);
  k_chunk2<<<dim3(64,8,2),384,0,stream>>>(xh,Bg,Cg,dt_sp,S,alg,dsw,ym0,ym1,0);
  k_chunk2<<<dim3(64,8,2),384,0,stream>>>(xh,Bg,Cg,dt_sp,S,alg,dsw,ym0,ym1,2);
  k_ln<<<8192,256,0,stream>>>(ym0,ym1,z,lw,lb);
  k_outproj<<<dim3(512,2),256,0,stream>>>(z,opw,out);
}

// Round 6
// 277.335 us; speedup vs baseline: 2.0564x; 1.1836x over previous
//
#include <hip/hip_runtime.h>
#include <hip/hip_bf16.h>

using bf16 = __hip_bfloat16;
typedef float f32;
typedef __attribute__((ext_vector_type(8))) short bf16x8;
typedef __attribute__((ext_vector_type(4))) float f32x4;
typedef __attribute__((ext_vector_type(4))) unsigned short u16x4;
typedef __attribute__((ext_vector_type(8))) unsigned short u16x8;

static __device__ __forceinline__ f32 siluf(f32 v){ return v / (1.f + __expf(-v)); }
static __device__ __forceinline__ unsigned short f2bf(f32 v){
  __hip_bfloat16 h=__float2bfloat16(v); return *(unsigned short*)&h;
}
static __device__ __forceinline__ f32 bfr2f(unsigned short u){
  unsigned int x=((unsigned int)u)<<16; return __uint_as_float(x);
}

// spatial position of sequence index p for scan direction dir (H=W=64, L=4096)
static __device__ __forceinline__ int pos_of(int dir, int p){
  if(dir==0) return p;
  if(dir==1) return ((p&63)<<6) | (p>>6);
  if(dir==2) return 4095-p;
  int q = 4095-p; return ((q&63)<<6) | (q>>6);
}

// inclusive wave-64 scan
static __device__ __forceinline__ f32 wave_iscan(f32 v, int lane){
  #pragma unroll
  for(int off=1; off<64; off<<=1){
    f32 u=__shfl_up(v,off,64);
    if(lane>=off) v+=u;
  }
  return v;
}

// ---------------- Kernel A: xz = x @ in_proj_w.T ; split -> xh_raw, z=silu ----
__global__ __launch_bounds__(256) void k_inproj(const f32* __restrict__ x, const f32* __restrict__ w,
                                                f32* __restrict__ xh_raw, f32* __restrict__ z){
  __shared__ f32 As[32][68];
  __shared__ f32 Bs[32][68];
  const int m0=blockIdx.x*64, n0=blockIdx.y*64;
  const int tid=threadIdx.x, tx=tid&15, ty=tid>>4;
  f32 acc[4][4]={};
  for(int k0=0;k0<96;k0+=32){
    for(int i=tid;i<2048;i+=256){int r=i>>5,kk=i&31; As[kk][r]=x[(size_t)(m0+r)*96+k0+kk]; }
    for(int i=tid;i<2048;i+=256){int r=i>>5,kk=i&31; Bs[kk][r]=w[(size_t)(n0+r)*96+k0+kk]; }
    __syncthreads();
    #pragma unroll
    for(int kk=0;kk<32;kk++){
      float4 a4=*(float4*)&As[kk][ty*4];
      float4 b4=*(float4*)&Bs[kk][tx*4];
      f32 a[4]={a4.x,a4.y,a4.z,a4.w}, b[4]={b4.x,b4.y,b4.z,b4.w};
      #pragma unroll
      for(int i=0;i<4;i++)
        #pragma unroll
        for(int j=0;j<4;j++) acc[i][j]+=a[i]*b[j];
    }
    __syncthreads();
  }
  #pragma unroll
  for(int i=0;i<4;i++){
    int row=m0+ty*4+i;
    #pragma unroll
    for(int j=0;j<4;j++){
      int col=n0+tx*4+j; f32 v=acc[i][j];
      if(col<192) xh_raw[(size_t)row*192+col]=v;
      else        z[(size_t)row*192+(col-192)]=siluf(v);
    }
  }
}

// ---------------- Kernel B: depthwise 3x3 conv + bias + silu --------------------
__global__ __launch_bounds__(256) void k_conv(const f32* __restrict__ xh_raw, const f32* __restrict__ cw,
                                              const f32* __restrict__ cb, f32* __restrict__ xh){
  __shared__ f32 wsm[192][9];
  __shared__ f32 bsm[192];
  const int tid=threadIdx.x;
  for(int i=tid;i<1728;i+=256) wsm[i/9][i%9]=cw[i];
  for(int i=tid;i<192;i+=256) bsm[i]=cb[i];
  __syncthreads();
  const int idx=blockIdx.x*256+tid;
  const int c4=idx%48, j=(idx/48)&63, ii0=(idx/3072)&63, b=idx/196608;
  const int c0=c4*4;
  f32 acc[4]={bsm[c0],bsm[c0+1],bsm[c0+2],bsm[c0+3]};
  #pragma unroll
  for(int a=0;a<3;a++){
    int ii=ii0+a-1; if(ii<0||ii>63) continue;
    #pragma unroll
    for(int bb=0;bb<3;bb++){
      int jj=j+bb-1; if(jj<0||jj>63) continue;
      float4 v=*(const float4*)&xh_raw[((size_t)(b*4096)+(ii*64+jj))*192 + c0];
      int t=a*3+bb;
      acc[0]+=v.x*wsm[c0][t]; acc[1]+=v.y*wsm[c0+1][t];
      acc[2]+=v.z*wsm[c0+2][t]; acc[3]+=v.w*wsm[c0+3][t];
    }
  }
  float4 o; o.x=siluf(acc[0]); o.y=siluf(acc[1]); o.z=siluf(acc[2]); o.w=siluf(acc[3]);
  ((float4*)xh)[idx]=o;
}

// ---------------- Kernel W: xpw fp32 -> bf16 fragment-contiguous layout --------
__global__ __launch_bounds__(256) void k_wcvt(const f32* __restrict__ xpw, unsigned short* __restrict__ Wfrag){
  const int i=blockIdx.x*256+threadIdx.x;      // 3840 granule tasks
  if(i>=3840) return;
  const int g=i%24, n=i/24;
  const int nt=n>>4, l=n&15;
  const int dir=n/40, cc=n-dir*40;
  u16x8 w;
  if(cc<38){
    const f32* p=&xpw[(size_t)dir*7296 + cc*192 + g*8];
    #pragma unroll
    for(int j=0;j<8;j++) w[j]=f2bf(p[j]);
  } else {
    #pragma unroll
    for(int j=0;j<8;j++) w[j]=0;
  }
  *(u16x8*)&Wfrag[((size_t)(nt*24+g)*16+l)*8]=w;
}

// ---------------- Kernel C (MFMA): x_dbl = xh @ Wfrag^T -> dt(softplus), B, C --
__global__ __launch_bounds__(256) void k_xdbl(const f32* __restrict__ xh, const unsigned short* __restrict__ Wfrag,
                                              const f32* __restrict__ dtb, f32* __restrict__ dt_sp,
                                              f32* __restrict__ Bg, f32* __restrict__ Cg){
  __shared__ unsigned short Ald[24*64*8];      // 24 KB, granule layout (g*64+r)*8
  const int m0=blockIdx.x*64;
  const int tid=threadIdx.x;
  for(int i=tid;i<1536;i+=256){
    int r=i&63, g=i>>6;
    const f32* p=&xh[(size_t)(m0+r)*192 + g*8];
    float4 v0=*(const float4*)p, v1=*(const float4*)(p+4);
    u16x8 w={f2bf(v0.x),f2bf(v0.y),f2bf(v0.z),f2bf(v0.w),
             f2bf(v1.x),f2bf(v1.y),f2bf(v1.z),f2bf(v1.w)};
    *(u16x8*)&Ald[(size_t)(g*64+r)*8]=w;
  }
  __syncthreads();
  const int wv=tid>>6, lane=tid&63, l15=lane&15, l4=lane>>4;
  f32x4 acc[10];
  #pragma unroll
  for(int nt=0;nt<10;nt++){ f32x4 zz={0.f,0.f,0.f,0.f}; acc[nt]=zz; }
  #pragma unroll
  for(int ks=0;ks<6;ks++){
    const int g=ks*4+l4;
    bf16x8 a=*(const bf16x8*)&Ald[(size_t)(g*64 + wv*16 + l15)*8];
    #pragma unroll
    for(int nt=0;nt<10;nt++){
      bf16x8 bfr=*(const bf16x8*)&Wfrag[((size_t)(nt*24+g)*16+l15)*8];
      acc[nt]=__builtin_amdgcn_mfma_f32_16x16x32_bf16(a,bfr,acc[nt],0,0,0);
    }
  }
  const int rowb=m0 + wv*16 + l4*4;
  #pragma unroll
  for(int nt=0;nt<10;nt++){
    int n=nt*16+l15, dir=n/40, cc=n-dir*40;
    if(cc>=38) continue;
    #pragma unroll
    for(int r=0;r<4;r++){
      size_t pix=(size_t)(rowb+r);
      f32 v=acc[nt][r];
      if(cc<6){ f32 xv=v+dtb[dir*6+cc]; dt_sp[pix*24+dir*6+cc]=(xv>20.f)? xv : log1pf(__expf(xv)); }
      else if(cc<22){ Bg[(pix*4+dir)*16+(cc-6)]=v; }
      else          { Cg[(pix*4+dir)*16+(cc-22)]=v; }
    }
  }
}

// ---------------- Kernel D1 (MFMA): S_loc = e63 * (B' @ Bt^T) ------------------
// grid (64,4,8), 384 thr = 6 waves (wave = head for scan; m-tiles wv, wv+6)
#define LDK1 72
__global__ __launch_bounds__(384) void k_chunk1(const f32* __restrict__ xh, const f32* __restrict__ Bg,
      const f32* __restrict__ dt_sp, const f32* __restrict__ Alogs, f32* __restrict__ S, f32* __restrict__ ach){
  __shared__ unsigned short Bp[192*LDK1];   // B'[ch][s] bf16 (27.6 KB)
  __shared__ unsigned short BtT[16*LDK1];   // Bt^T[n][s]
  __shared__ f32 dtl[64][6], w1l[64][6];
  __shared__ f32 e63[6];
  const int c=blockIdx.x, dir=blockIdx.y, b=blockIdx.z, c0=c*64, tid=threadIdx.x;
  // P1: stage dt + BtT
  { int r=tid/6, q=tid-r*6; size_t pix=(size_t)b*4096+pos_of(dir,c0+r);
    dtl[r][q]=dt_sp[pix*24+dir*6+q]; }
  if(tid<256){
    int r=tid>>2,q=tid&3; size_t pix=(size_t)b*4096+pos_of(dir,c0+r);
    float4 bv=*(const float4*)&Bg[(pix*4+dir)*16+q*4];
    BtT[(4*q+0)*LDK1+r]=f2bf(bv.x); BtT[(4*q+1)*LDK1+r]=f2bf(bv.y);
    BtT[(4*q+2)*LDK1+r]=f2bf(bv.z); BtT[(4*q+3)*LDK1+r]=f2bf(bv.w);
  }
  __syncthreads();
  // P2: parallel scan, wave wv <-> head wv
  const int wv=tid>>6, lane=tid&63;
  {
    f32 A=-__expf(Alogs[dir*6+wv]);
    f32 dv=dtl[lane][wv];
    f32 v=wave_iscan(dv*A,lane);
    w1l[lane][wv]=__expf(-v)*dv;
    if(lane==63){
      f32 e=__expf(v);
      e63[wv]=e;
      ach[((size_t)(b*64+c))*24+dir*6+wv]=e;
    }
  }
  __syncthreads();
  // P3: B' build (768 tasks)
  for(int u=tid;u<768;u+=384){
    int sg=u/48, q=u-sg*48, head=q>>3;
    f32 vv[4][4];
    #pragma unroll
    for(int j=0;j<4;j++){
      int s=sg*4+j;
      float4 xv=((const float4*)&xh[(size_t)(b*4096+pos_of(dir,c0+s))*192])[q];
      f32 w1=w1l[s][head];
      vv[j][0]=xv.x*w1; vv[j][1]=xv.y*w1; vv[j][2]=xv.z*w1; vv[j][3]=xv.w*w1;
    }
    #pragma unroll
    for(int cc=0;cc<4;cc++){
      u16x4 w={f2bf(vv[0][cc]),f2bf(vv[1][cc]),f2bf(vv[2][cc]),f2bf(vv[3][cc])};
      *(u16x4*)&Bp[(4*q+cc)*LDK1+sg*4]=w;
    }
  }
  __syncthreads();
  // P4: MFMA S_loc, M=192 N=16 K=64
  const int l15=lane&15, l4=lane>>4;
  f32x4 acc[2];
  { f32x4 zz={0.f,0.f,0.f,0.f}; acc[0]=zz; acc[1]=zz; }
  #pragma unroll
  for(int i=0;i<2;i++){
    int mt=wv+6*i;
    #pragma unroll
    for(int ks=0;ks<2;ks++){
      int kg=ks*4+l4;
      bf16x8 a=*(const bf16x8*)&Bp[(size_t)(mt*16+l15)*LDK1+kg*8];
      bf16x8 bb=*(const bf16x8*)&BtT[(size_t)l15*LDK1+kg*8];
      acc[i]=__builtin_amdgcn_mfma_f32_16x16x32_bf16(a,bb,acc[i],0,0,0);
    }
  }
  const size_t base=(((size_t)(b*64+c))*24+dir*6)*512;
  #pragma unroll
  for(int i=0;i<2;i++){
    int mt=wv+6*i;
    #pragma unroll
    for(int r=0;r<4;r++){
      int ch=mt*16+l4*4+r, head=ch>>5, d=ch&31;
      S[base+(size_t)head*512+d*16+l15]=acc[i][r]*e63[head];
    }
  }
}

// ---------------- Kernel D2: serial inter-chunk scan (in-place S -> prev) ------
__global__ __launch_bounds__(256) void k_scan(f32* __restrict__ S, const f32* __restrict__ ach){
  const int g=blockIdx.x*256+threadIdx.x;        // 98304 = 8*24*32*16
  const int b=g/12288, rem=g%12288, h=rem/512;
  size_t base=(size_t)b*786432 + rem;
  const f32* ap=&ach[(size_t)b*1536 + h];
  f32 st=0.f;
  for(int c=0;c<64;c++){
    f32 a=ap[c*24];
    f32 s=S[base+(size_t)c*12288];
    S[base+(size_t)c*12288]=st;
    st=a*st+s;
  }
}

// ---------------- Kernel D3 (MFMA): y = [CBtri|Ct|0] @ [x.w1 ; prevT ; 0] -------
// grid (64, 8, 4): z = (dir-dirbase)*2 + half; 384 thr = 6 waves; half = 96 ch.
#define LDK 104
__global__ __launch_bounds__(384) void k_chunk2(const f32* __restrict__ xh, const f32* __restrict__ Bg,
      const f32* __restrict__ Cg, const f32* __restrict__ dt_sp, const f32* __restrict__ Sprev,
      const f32* __restrict__ Alogs, const f32* __restrict__ Dsw,
      f32* __restrict__ ym0, f32* __restrict__ ym1, const int dirbase){
  __shared__ unsigned short Alds[64*LDK];   // 13.3 KB: [CBtri | Ct | 0]
  __shared__ unsigned short Blds[96*LDK];   // 20.0 KB: [x*w1 ; prevT ; 0] for 96 ch
  __shared__ unsigned short Ctf[64*32];     // 4 KB (16 real k + 16 zero)
  __shared__ unsigned short Btf[64*32];     // 4 KB
  __shared__ f32 dtl[64][6], cuml[64][6], w1l[64][6], erowl[64][6];
  const int c=blockIdx.x, b=blockIdx.y;
  const int dir=dirbase+(blockIdx.z>>1), half=blockIdx.z&1;
  const int c0=c*64, tid=threadIdx.x;
  f32* __restrict__ ym = (dir&1)? ym1 : ym0;
  // ---- P1: stage dt, Ctf/Btf (+Alds Ct cols & zeros), prevT (+Blds zeros)
  { int r=tid/6, q=tid-r*6; size_t pix=(size_t)b*4096+pos_of(dir,c0+r);
    dtl[r][q]=dt_sp[pix*24+dir*6+q]; }
  if(tid<256){
    int r=tid>>2,q=tid&3; size_t pix=(size_t)b*4096+pos_of(dir,c0+r);
    float4 bv=*(const float4*)&Bg[(pix*4+dir)*16+q*4];
    float4 cv=*(const float4*)&Cg[(pix*4+dir)*16+q*4];
    u16x4 wb={f2bf(bv.x),f2bf(bv.y),f2bf(bv.z),f2bf(bv.w)};
    u16x4 wc={f2bf(cv.x),f2bf(cv.y),f2bf(cv.z),f2bf(cv.w)};
    u16x4 zz={0,0,0,0};
    *(u16x4*)&Btf[r*32+q*4]=wb;      *(u16x4*)&Btf[r*32+16+q*4]=zz;
    *(u16x4*)&Ctf[r*32+q*4]=wc;      *(u16x4*)&Ctf[r*32+16+q*4]=zz;
    *(u16x4*)&Alds[r*LDK+64+q*4]=wc; *(u16x4*)&Alds[r*LDK+80+q*4]=zz;
  }
  {
    const size_t pbase=(((size_t)(b*64+c))*24+dir*6)*512;
    int lr=tid>>2, ng=tid&3, gch=half*96+lr, head=gch>>5, d=gch&31;
    float4 pv=*(const float4*)&Sprev[pbase+(size_t)head*512+d*16+ng*4];
    u16x4 w={f2bf(pv.x),f2bf(pv.y),f2bf(pv.z),f2bf(pv.w)};
    u16x4 zz={0,0,0,0};
    *(u16x4*)&Blds[lr*LDK+64+ng*4]=w;
    *(u16x4*)&Blds[lr*LDK+80+ng*4]=zz;
  }
  __syncthreads();
  // ---- P2: parallel scan (wave = head)
  const int wv=tid>>6, lane=tid&63;
  {
    f32 A=-__expf(Alogs[dir*6+wv]);
    f32 dv=dtl[lane][wv];
    f32 v=wave_iscan(dv*A,lane);
    cuml[lane][wv]=v;
    w1l[lane][wv]=__expf(-v)*dv;
    erowl[lane][wv]=__expf(v);
  }
  __syncthreads();
  // ---- P3a: CB = Ct @ Bt^T via MFMA (tiles wv, wv+6, wv+12), masked write
  const int l15=lane&15, l4=lane>>4;
  #pragma unroll
  for(int tt=0;tt<3;tt++){
    int tile=wv+6*tt;
    if(tile<16){
      int mt=tile>>2, nt=tile&3;
      f32x4 a4={0.f,0.f,0.f,0.f};
      bf16x8 af=*(const bf16x8*)&Ctf[(mt*16+l15)*32+l4*8];
      bf16x8 bfr=*(const bf16x8*)&Btf[(nt*16+l15)*32+l4*8];
      a4=__builtin_amdgcn_mfma_f32_16x16x32_bf16(af,bfr,a4,0,0,0);
      #pragma unroll
      for(int r=0;r<4;r++){
        int t=mt*16+l4*4+r, s=nt*16+l15;
        Alds[t*LDK+s]=(s<=t)? f2bf(a4[r]) : (unsigned short)0;
      }
    }
  }
  // ---- P3b: B' x-part for this half (384 tasks: sg 16 x ql 24)
  {
    int sg=tid/24, ql=tid-sg*24, q=half*24+ql, head=q>>3;
    f32 vv[4][4];
    #pragma unroll
    for(int j=0;j<4;j++){
      int s=sg*4+j;
      float4 xv=((const float4*)&xh[(size_t)(b*4096+pos_of(dir,c0+s))*192])[q];
      f32 w1=w1l[s][head];
      vv[j][0]=xv.x*w1; vv[j][1]=xv.y*w1; vv[j][2]=xv.z*w1; vv[j][3]=xv.w*w1;
    }
    #pragma unroll
    for(int cc=0;cc<4;cc++){
      u16x4 w={f2bf(vv[0][cc]),f2bf(vv[1][cc]),f2bf(vv[2][cc]),f2bf(vv[3][cc])};
      *(u16x4*)&Blds[(4*ql+cc)*LDK+sg*4]=w;
    }
  }
  __syncthreads();
  // ---- P4: main MFMA 64x96x96 (per wave: 4 m-tiles x its 16-ch strip)
  f32x4 acc[4];
  #pragma unroll
  for(int mt=0;mt<4;mt++){ f32x4 zz={0.f,0.f,0.f,0.f}; acc[mt]=zz; }
  #pragma unroll
  for(int ks=0;ks<3;ks++){
    const int kg=ks*4+l4;
    bf16x8 bfr=*(const bf16x8*)&Blds[(wv*16+l15)*LDK+kg*8];
    #pragma unroll
    for(int mt=0;mt<4;mt++){
      bf16x8 af=*(const bf16x8*)&Alds[(mt*16+l15)*LDK+kg*8];
      acc[mt]=__builtin_amdgcn_mfma_f32_16x16x32_bf16(af,bfr,acc[mt],0,0,0);
    }
  }
  // ---- epilogue
  const int lr=wv*16+l15, gch=half*96+lr, head=gch>>5;
  const f32 Dv=Dsw[dir*192+gch];
  #pragma unroll
  for(int mt=0;mt<4;mt++){
    #pragma unroll
    for(int r=0;r<4;r++){
      int t=mt*16+l4*4+r;
      f32 er=erowl[t][head];
      f32 xv=bfr2f(Blds[lr*LDK+t])*er/dtl[t][head];
      f32 v=acc[mt][r]*er + Dv*xv;
      size_t o=((size_t)(b*4096+pos_of(dir,c0+t)))*192+gch;
      if(dirbase==0) ym[o]=v; else ym[o]+=v;
    }
  }
}

// ---------------- Kernel E: layernorm(192) of (ym0+ym1) then * z ----------------
__global__ __launch_bounds__(256) void k_ln(const f32* __restrict__ ym0, const f32* __restrict__ ym1,
                                            f32* __restrict__ z,
                                            const f32* __restrict__ lw, const f32* __restrict__ lb){
  const int row=blockIdx.x*4+(threadIdx.x>>6), lane=threadIdx.x&63;
  const f32* yr0=&ym0[(size_t)row*192];
  const f32* yr1=&ym1[(size_t)row*192];
  f32 v0=yr0[lane]+yr1[lane], v1=yr0[lane+64]+yr1[lane+64], v2=yr0[lane+128]+yr1[lane+128];
  f32 s=v0+v1+v2;
  #pragma unroll
  for(int off=32;off>0;off>>=1) s+=__shfl_xor(s,off,64);
  const f32 mu=s*(1.f/192.f);
  f32 d0=v0-mu,d1=v1-mu,d2=v2-mu;
  f32 q=d0*d0+d1*d1+d2*d2;
  #pragma unroll
  for(int off=32;off>0;off>>=1) q+=__shfl_xor(q,off,64);
  const f32 rs=rsqrtf(q*(1.f/192.f)+1e-5f);
  f32* zr=&z[(size_t)row*192];
  zr[lane]    =(d0*rs*lw[lane]    +lb[lane])    *zr[lane];
  zr[lane+64] =(d1*rs*lw[lane+64] +lb[lane+64]) *zr[lane+64];
  zr[lane+128]=(d2*rs*lw[lane+128]+lb[lane+128])*zr[lane+128];
}

// ---------------- Kernel F: out = u @ out_proj_w.T (fp32 out) ------------------
__global__ __launch_bounds__(256) void k_outproj(const f32* __restrict__ u, const f32* __restrict__ w,
                                                 f32* __restrict__ out){
  __shared__ f32 As[32][68];
  __shared__ f32 Bs[32][68];
  const int m0=blockIdx.x*64, n0=blockIdx.y*64;
  const int tid=threadIdx.x, tx=tid&15, ty=tid>>4;
  f32 acc[4][4]={};
  for(int k0=0;k0<192;k0+=32){
    for(int i=tid;i<2048;i+=256){int r=i>>5,kk=i&31; As[kk][r]=u[(size_t)(m0+r)*192+k0+kk]; }
    for(int i=tid;i<2048;i+=256){int r=i>>5,kk=i&31; int n=n0+r; Bs[kk][r]=(n<96)? w[(size_t)n*192+k0+kk] : 0.f; }
    __syncthreads();
    #pragma unroll
    for(int kk=0;kk<32;kk++){
      float4 a4=*(float4*)&As[kk][ty*4];
      float4 b4=*(float4*)&Bs[kk][tx*4];
      f32 a[4]={a4.x,a4.y,a4.z,a4.w}, bb[4]={b4.x,b4.y,b4.z,b4.w};
      #pragma unroll
      for(int i=0;i<4;i++)
        #pragma unroll
        for(int j=0;j<4;j++) acc[i][j]+=a[i]*bb[j];
    }
    __syncthreads();
  }
  #pragma unroll
  for(int i=0;i<4;i++){
    int row=m0+ty*4+i;
    #pragma unroll
    for(int j=0;j<4;j++){
      int col=n0+tx*4+j;
      if(col<96) out[(size_t)row*96+col]=acc[i][j];
    }
  }
}

extern "C" void kernel_launch(void* const* d_in, const int* in_sizes, int n_in,
                              void* d_out, int out_size, void* d_ws, size_t ws_size,
                              hipStream_t stream){
  const f32* x  =(const f32*)d_in[0];
  const f32* ipw=(const f32*)d_in[1];
  const f32* cw =(const f32*)d_in[2];
  const f32* cb =(const f32*)d_in[3];
  const f32* xpw=(const f32*)d_in[4];
  const f32* alg=(const f32*)d_in[5];
  const f32* dsw=(const f32*)d_in[6];
  const f32* dtb=(const f32*)d_in[7];
  const f32* lw =(const f32*)d_in[8];
  const f32* lb =(const f32*)d_in[9];
  const f32* opw=(const f32*)d_in[10];
  f32* out=(f32*)d_out;
  f32* ws=(f32*)d_ws;

  f32* xh_raw=ws;               // 6291456 floats (reused as ym0)
  f32* z     =ws+ 6291456;      // 6291456
  f32* xh    =ws+12582912;      // 6291456
  f32* dt_sp =ws+18874368;      //  786432
  f32* Bg    =ws+19660800;      // 2097152
  f32* Cg    =ws+21757952;      // 2097152
  f32* S     =ws+23855104;      // 6291456
  f32* ach   =ws+30146560;      //   12288
  f32* ym1   =ws+30158848;      // 6291456
  unsigned short* Wfrag=(unsigned short*)(ws+36450304);  // 30720 bf16
  f32* ym0=xh_raw;

  k_inproj<<<dim3(512,6),256,0,stream>>>(x,ipw,xh_raw,z);
  k_wcvt<<<15,256,0,stream>>>(xpw,Wfrag);
  k_conv<<<6144,256,0,stream>>>(xh_raw,cw,cb,xh);
  k_xdbl<<<dim3(512),256,0,stream>>>(xh,Wfrag,dtb,dt_sp,Bg,Cg);
  k_chunk1<<<dim3(64,4,8),384,0,stream>>>(xh,Bg,dt_sp,alg,S,ach);
  k_scan<<<384,256,0,stream>>>(S,ach);
  k_chunk2<<<dim3(64,8,4),384,0,stream>>>(xh,Bg,Cg,dt_sp,S,alg,dsw,ym0,ym1,0);
  k_chunk2<<<dim3(64,8,4),384,0,stream>>>(xh,Bg,Cg,dt_sp,S,alg,dsw,ym0,ym1,2);
  k_ln<<<8192,256,0,stream>>>(ym0,ym1,z,lw,lb);
  k_outproj<<<dim3(512,2),256,0,stream>>>(z,opw,out);
}

// Round 8
// 227.568 us; speedup vs baseline: 2.5062x; 1.2187x over previous
//
#include <hip/hip_runtime.h>
#include <hip/hip_bf16.h>

using bf16 = __hip_bfloat16;
typedef float f32;
typedef __attribute__((ext_vector_type(8))) short bf16x8;
typedef __attribute__((ext_vector_type(4))) float f32x4;
typedef __attribute__((ext_vector_type(4))) unsigned short u16x4;
typedef __attribute__((ext_vector_type(8))) unsigned short u16x8;

static __device__ __forceinline__ f32 siluf(f32 v){ return v / (1.f + __expf(-v)); }
static __device__ __forceinline__ unsigned short f2bf(f32 v){
  __hip_bfloat16 h=__float2bfloat16(v); return *(unsigned short*)&h;
}
static __device__ __forceinline__ f32 bfr2f(unsigned short u){
  unsigned int x=((unsigned int)u)<<16; return __uint_as_float(x);
}

// spatial position of sequence index p for scan direction dir (H=W=64, L=4096)
static __device__ __forceinline__ int pos_of(int dir, int p){
  if(dir==0) return p;
  if(dir==1) return ((p&63)<<6) | (p>>6);
  if(dir==2) return 4095-p;
  int q = 4095-p; return ((q&63)<<6) | (q>>6);
}

// inclusive wave-64 scan
static __device__ __forceinline__ f32 wave_iscan(f32 v, int lane){
  #pragma unroll
  for(int off=1; off<64; off<<=1){
    f32 u=__shfl_up(v,off,64);
    if(lane>=off) v+=u;
  }
  return v;
}

// ---------------- Kernel W: all three weight matrices -> bf16 fragment layout --
// xpw:   10 nt x 24 g  (N=160 pad, K=192)  -> Wx[((nt*24+g)*16+l)*8]
// ipw:   24 nt x 12 g  (N=384,     K=96)   -> Wi[((nt*12+g)*16+l)*8]
// opw:    6 nt x 24 g  (N=96,      K=192)  -> Wo[((nt*24+g)*16+l)*8]
__global__ __launch_bounds__(256) void k_wcvt_all(const f32* __restrict__ xpw, const f32* __restrict__ ipw,
                                                  const f32* __restrict__ opw, unsigned short* __restrict__ Wx,
                                                  unsigned short* __restrict__ Wi, unsigned short* __restrict__ Wo){
  const int t=blockIdx.x*256+threadIdx.x;
  if(t<3840){
    const int g=t%24, n=t/24, nt=n>>4, l=n&15;
    const int dir=n/40, cc=n-dir*40;
    u16x8 w={0,0,0,0,0,0,0,0};
    if(cc<38){
      const f32* p=&xpw[(size_t)dir*7296+cc*192+g*8];
      #pragma unroll
      for(int j=0;j<8;j++) w[j]=f2bf(p[j]);
    }
    *(u16x8*)&Wx[((size_t)(nt*24+g)*16+l)*8]=w;
  } else if(t<8448){
    const int i=t-3840, g=i%12, n=i/12, nt=n>>4, l=n&15;
    const f32* p=&ipw[(size_t)n*96+g*8];
    u16x8 w;
    #pragma unroll
    for(int j=0;j<8;j++) w[j]=f2bf(p[j]);
    *(u16x8*)&Wi[((size_t)(nt*12+g)*16+l)*8]=w;
  } else if(t<10752){
    const int i=t-8448, g=i%24, n=i/24, nt=n>>4, l=n&15;
    const f32* p=&opw[(size_t)n*192+g*8];
    u16x8 w;
    #pragma unroll
    for(int j=0;j<8;j++) w[j]=f2bf(p[j]);
    *(u16x8*)&Wo[((size_t)(nt*24+g)*16+l)*8]=w;
  }
}

// ---------------- Kernel A (MFMA): xz = x @ in_proj_w.T ; split, silu ----------
// M=32768 (BM=64), N=384 (24 nt), K=96 (3 steps).
__global__ __launch_bounds__(256) void k_inproj(const f32* __restrict__ x, const unsigned short* __restrict__ Wi,
                                                f32* __restrict__ xh_raw, f32* __restrict__ z){
  __shared__ unsigned short Ald[12*64*8];      // 12 KB
  const int m0=blockIdx.x*64, tid=threadIdx.x;
  for(int i=tid;i<768;i+=256){
    int r=i&63, g=i>>6;
    const f32* p=&x[(size_t)(m0+r)*96+g*8];
    float4 v0=*(const float4*)p, v1=*(const float4*)(p+4);
    u16x8 w={f2bf(v0.x),f2bf(v0.y),f2bf(v0.z),f2bf(v0.w),
             f2bf(v1.x),f2bf(v1.y),f2bf(v1.z),f2bf(v1.w)};
    *(u16x8*)&Ald[(size_t)(g*64+r)*8]=w;
  }
  __syncthreads();
  const int wv=tid>>6, lane=tid&63, l15=lane&15, l4=lane>>4;
  f32x4 acc[24];
  #pragma unroll
  for(int nt=0;nt<24;nt++){ f32x4 zz={0.f,0.f,0.f,0.f}; acc[nt]=zz; }
  #pragma unroll
  for(int ks=0;ks<3;ks++){
    const int g=ks*4+l4;
    bf16x8 a=*(const bf16x8*)&Ald[(size_t)(g*64+wv*16+l15)*8];
    #pragma unroll
    for(int nt=0;nt<24;nt++){
      bf16x8 bfr=*(const bf16x8*)&Wi[((size_t)(nt*12+g)*16+l15)*8];
      acc[nt]=__builtin_amdgcn_mfma_f32_16x16x32_bf16(a,bfr,acc[nt],0,0,0);
    }
  }
  const int rowb=m0+wv*16+l4*4;
  #pragma unroll
  for(int nt=0;nt<24;nt++){
    int col=nt*16+l15;
    #pragma unroll
    for(int r=0;r<4;r++){
      int row=rowb+r; f32 v=acc[nt][r];
      if(col<192) xh_raw[(size_t)row*192+col]=v;
      else        z[(size_t)row*192+(col-192)]=siluf(v);
    }
  }
}

// ---------------- Kernel B: depthwise 3x3 conv + bias + silu --------------------
__global__ __launch_bounds__(256) void k_conv(const f32* __restrict__ xh_raw, const f32* __restrict__ cw,
                                              const f32* __restrict__ cb, f32* __restrict__ xh){
  __shared__ f32 wsm[192][9];
  __shared__ f32 bsm[192];
  const int tid=threadIdx.x;
  for(int i=tid;i<1728;i+=256) wsm[i/9][i%9]=cw[i];
  for(int i=tid;i<192;i+=256) bsm[i]=cb[i];
  __syncthreads();
  const int idx=blockIdx.x*256+tid;
  const int c4=idx%48, j=(idx/48)&63, ii0=(idx/3072)&63, b=idx/196608;
  const int c0=c4*4;
  f32 acc[4]={bsm[c0],bsm[c0+1],bsm[c0+2],bsm[c0+3]};
  #pragma unroll
  for(int a=0;a<3;a++){
    int ii=ii0+a-1; if(ii<0||ii>63) continue;
    #pragma unroll
    for(int bb=0;bb<3;bb++){
      int jj=j+bb-1; if(jj<0||jj>63) continue;
      float4 v=*(const float4*)&xh_raw[((size_t)(b*4096)+(ii*64+jj))*192 + c0];
      int t=a*3+bb;
      acc[0]+=v.x*wsm[c0][t]; acc[1]+=v.y*wsm[c0+1][t];
      acc[2]+=v.z*wsm[c0+2][t]; acc[3]+=v.w*wsm[c0+3][t];
    }
  }
  float4 o; o.x=siluf(acc[0]); o.y=siluf(acc[1]); o.z=siluf(acc[2]); o.w=siluf(acc[3]);
  ((float4*)xh)[idx]=o;
}

// ---------------- Kernel C (MFMA): x_dbl = xh @ Wx^T -> dt(softplus), B, C -----
__global__ __launch_bounds__(256) void k_xdbl(const f32* __restrict__ xh, const unsigned short* __restrict__ Wfrag,
                                              const f32* __restrict__ dtb, f32* __restrict__ dt_sp,
                                              f32* __restrict__ Bg, f32* __restrict__ Cg){
  __shared__ unsigned short Ald[24*64*8];      // 24 KB, granule layout (g*64+r)*8
  const int m0=blockIdx.x*64;
  const int tid=threadIdx.x;
  for(int i=tid;i<1536;i+=256){
    int r=i&63, g=i>>6;
    const f32* p=&xh[(size_t)(m0+r)*192 + g*8];
    float4 v0=*(const float4*)p, v1=*(const float4*)(p+4);
    u16x8 w={f2bf(v0.x),f2bf(v0.y),f2bf(v0.z),f2bf(v0.w),
             f2bf(v1.x),f2bf(v1.y),f2bf(v1.z),f2bf(v1.w)};
    *(u16x8*)&Ald[(size_t)(g*64+r)*8]=w;
  }
  __syncthreads();
  const int wv=tid>>6, lane=tid&63, l15=lane&15, l4=lane>>4;
  f32x4 acc[10];
  #pragma unroll
  for(int nt=0;nt<10;nt++){ f32x4 zz={0.f,0.f,0.f,0.f}; acc[nt]=zz; }
  #pragma unroll
  for(int ks=0;ks<6;ks++){
    const int g=ks*4+l4;
    bf16x8 a=*(const bf16x8*)&Ald[(size_t)(g*64 + wv*16 + l15)*8];
    #pragma unroll
    for(int nt=0;nt<10;nt++){
      bf16x8 bfr=*(const bf16x8*)&Wfrag[((size_t)(nt*24+g)*16+l15)*8];
      acc[nt]=__builtin_amdgcn_mfma_f32_16x16x32_bf16(a,bfr,acc[nt],0,0,0);
    }
  }
  const int rowb=m0 + wv*16 + l4*4;
  #pragma unroll
  for(int nt=0;nt<10;nt++){
    int n=nt*16+l15, dir=n/40, cc=n-dir*40;
    if(cc>=38) continue;
    #pragma unroll
    for(int r=0;r<4;r++){
      size_t pix=(size_t)(rowb+r);
      f32 v=acc[nt][r];
      if(cc<6){ f32 xv=v+dtb[dir*6+cc]; dt_sp[pix*24+dir*6+cc]=(xv>20.f)? xv : log1pf(__expf(xv)); }
      else if(cc<22){ Bg[(pix*4+dir)*16+(cc-6)]=v; }
      else          { Cg[(pix*4+dir)*16+(cc-22)]=v; }
    }
  }
}

// ---------------- Kernel D1 (MFMA): S_loc = e63 * (B' @ Bt^T) ------------------
#define LDK1 72
__global__ __launch_bounds__(384) void k_chunk1(const f32* __restrict__ xh, const f32* __restrict__ Bg,
      const f32* __restrict__ dt_sp, const f32* __restrict__ Alogs, f32* __restrict__ S, f32* __restrict__ ach){
  __shared__ unsigned short Bp[192*LDK1];   // B'[ch][s] bf16 (27.6 KB)
  __shared__ unsigned short BtT[16*LDK1];   // Bt^T[n][s]
  __shared__ f32 dtl[64][6], w1l[64][6];
  __shared__ f32 e63[6];
  const int c=blockIdx.x, dir=blockIdx.y, b=blockIdx.z, c0=c*64, tid=threadIdx.x;
  { int r=tid/6, q=tid-r*6; size_t pix=(size_t)b*4096+pos_of(dir,c0+r);
    dtl[r][q]=dt_sp[pix*24+dir*6+q]; }
  if(tid<256){
    int r=tid>>2,q=tid&3; size_t pix=(size_t)b*4096+pos_of(dir,c0+r);
    float4 bv=*(const float4*)&Bg[(pix*4+dir)*16+q*4];
    BtT[(4*q+0)*LDK1+r]=f2bf(bv.x); BtT[(4*q+1)*LDK1+r]=f2bf(bv.y);
    BtT[(4*q+2)*LDK1+r]=f2bf(bv.z); BtT[(4*q+3)*LDK1+r]=f2bf(bv.w);
  }
  __syncthreads();
  const int wv=tid>>6, lane=tid&63;
  {
    f32 A=-__expf(Alogs[dir*6+wv]);
    f32 dv=dtl[lane][wv];
    f32 v=wave_iscan(dv*A,lane);
    w1l[lane][wv]=__expf(-v)*dv;
    if(lane==63){
      f32 e=__expf(v);
      e63[wv]=e;
      ach[((size_t)(b*64+c))*24+dir*6+wv]=e;
    }
  }
  __syncthreads();
  for(int u=tid;u<768;u+=384){
    int sg=u/48, q=u-sg*48, head=q>>3;
    f32 vv[4][4];
    #pragma unroll
    for(int j=0;j<4;j++){
      int s=sg*4+j;
      float4 xv=((const float4*)&xh[(size_t)(b*4096+pos_of(dir,c0+s))*192])[q];
      f32 w1=w1l[s][head];
      vv[j][0]=xv.x*w1; vv[j][1]=xv.y*w1; vv[j][2]=xv.z*w1; vv[j][3]=xv.w*w1;
    }
    #pragma unroll
    for(int cc=0;cc<4;cc++){
      u16x4 w={f2bf(vv[0][cc]),f2bf(vv[1][cc]),f2bf(vv[2][cc]),f2bf(vv[3][cc])};
      *(u16x4*)&Bp[(4*q+cc)*LDK1+sg*4]=w;
    }
  }
  __syncthreads();
  const int l15=lane&15, l4=lane>>4;
  f32x4 acc[2];
  { f32x4 zz={0.f,0.f,0.f,0.f}; acc[0]=zz; acc[1]=zz; }
  #pragma unroll
  for(int i=0;i<2;i++){
    int mt=wv+6*i;
    #pragma unroll
    for(int ks=0;ks<2;ks++){
      int kg=ks*4+l4;
      bf16x8 a=*(const bf16x8*)&Bp[(size_t)(mt*16+l15)*LDK1+kg*8];
      bf16x8 bb=*(const bf16x8*)&BtT[(size_t)l15*LDK1+kg*8];
      acc[i]=__builtin_amdgcn_mfma_f32_16x16x32_bf16(a,bb,acc[i],0,0,0);
    }
  }
  const size_t base=(((size_t)(b*64+c))*24+dir*6)*512;
  #pragma unroll
  for(int i=0;i<2;i++){
    int mt=wv+6*i;
    #pragma unroll
    for(int r=0;r<4;r++){
      int ch=mt*16+l4*4+r, head=ch>>5, d=ch&31;
      S[base+(size_t)head*512+d*16+l15]=acc[i][r]*e63[head];
    }
  }
}

// ---------------- Kernel D2: serial inter-chunk scan (in-place S -> prev) ------
__global__ __launch_bounds__(256) void k_scan(f32* __restrict__ S, const f32* __restrict__ ach){
  const int g=blockIdx.x*256+threadIdx.x;        // 98304 = 8*24*32*16
  const int b=g/12288, rem=g%12288, h=rem/512;
  size_t base=(size_t)b*786432 + rem;
  const f32* ap=&ach[(size_t)b*1536 + h];
  f32 st=0.f;
  for(int c=0;c<64;c++){
    f32 a=ap[c*24];
    f32 s=S[base+(size_t)c*12288];
    S[base+(size_t)c*12288]=st;
    st=a*st+s;
  }
}

// ---------------- Kernel D3 (MFMA): y = [CBtri|Ct|0] @ [x.w1 ; prevT ; 0] -------
#define LDK 104
__global__ __launch_bounds__(384) void k_chunk2(const f32* __restrict__ xh, const f32* __restrict__ Bg,
      const f32* __restrict__ Cg, const f32* __restrict__ dt_sp, const f32* __restrict__ Sprev,
      const f32* __restrict__ Alogs, const f32* __restrict__ Dsw,
      f32* __restrict__ ym0, f32* __restrict__ ym1, const int dirbase){
  __shared__ unsigned short Alds[64*LDK];   // 13.3 KB: [CBtri | Ct | 0]
  __shared__ unsigned short Blds[96*LDK];   // 20.0 KB: [x*w1 ; prevT ; 0] for 96 ch
  __shared__ unsigned short Ctf[64*32];     // 4 KB
  __shared__ unsigned short Btf[64*32];     // 4 KB
  __shared__ f32 dtl[64][6], cuml[64][6], w1l[64][6], erowl[64][6];
  const int c=blockIdx.x, b=blockIdx.y;
  const int dir=dirbase+(blockIdx.z>>1), half=blockIdx.z&1;
  const int c0=c*64, tid=threadIdx.x;
  f32* __restrict__ ym = (dir&1)? ym1 : ym0;
  { int r=tid/6, q=tid-r*6; size_t pix=(size_t)b*4096+pos_of(dir,c0+r);
    dtl[r][q]=dt_sp[pix*24+dir*6+q]; }
  if(tid<256){
    int r=tid>>2,q=tid&3; size_t pix=(size_t)b*4096+pos_of(dir,c0+r);
    float4 bv=*(const float4*)&Bg[(pix*4+dir)*16+q*4];
    float4 cv=*(const float4*)&Cg[(pix*4+dir)*16+q*4];
    u16x4 wb={f2bf(bv.x),f2bf(bv.y),f2bf(bv.z),f2bf(bv.w)};
    u16x4 wc={f2bf(cv.x),f2bf(cv.y),f2bf(cv.z),f2bf(cv.w)};
    u16x4 zz={0,0,0,0};
    *(u16x4*)&Btf[r*32+q*4]=wb;      *(u16x4*)&Btf[r*32+16+q*4]=zz;
    *(u16x4*)&Ctf[r*32+q*4]=wc;      *(u16x4*)&Ctf[r*32+16+q*4]=zz;
    *(u16x4*)&Alds[r*LDK+64+q*4]=wc; *(u16x4*)&Alds[r*LDK+80+q*4]=zz;
  }
  {
    const size_t pbase=(((size_t)(b*64+c))*24+dir*6)*512;
    int lr=tid>>2, ng=tid&3, gch=half*96+lr, head=gch>>5, d=gch&31;
    float4 pv=*(const float4*)&Sprev[pbase+(size_t)head*512+d*16+ng*4];
    u16x4 w={f2bf(pv.x),f2bf(pv.y),f2bf(pv.z),f2bf(pv.w)};
    u16x4 zz={0,0,0,0};
    *(u16x4*)&Blds[lr*LDK+64+ng*4]=w;
    *(u16x4*)&Blds[lr*LDK+80+ng*4]=zz;
  }
  __syncthreads();
  const int wv=tid>>6, lane=tid&63;
  {
    f32 A=-__expf(Alogs[dir*6+wv]);
    f32 dv=dtl[lane][wv];
    f32 v=wave_iscan(dv*A,lane);
    cuml[lane][wv]=v;
    w1l[lane][wv]=__expf(-v)*dv;
    erowl[lane][wv]=__expf(v);
  }
  __syncthreads();
  const int l15=lane&15, l4=lane>>4;
  #pragma unroll
  for(int tt=0;tt<3;tt++){
    int tile=wv+6*tt;
    if(tile<16){
      int mt=tile>>2, nt=tile&3;
      f32x4 a4={0.f,0.f,0.f,0.f};
      bf16x8 af=*(const bf16x8*)&Ctf[(mt*16+l15)*32+l4*8];
      bf16x8 bfr=*(const bf16x8*)&Btf[(nt*16+l15)*32+l4*8];
      a4=__builtin_amdgcn_mfma_f32_16x16x32_bf16(af,bfr,a4,0,0,0);
      #pragma unroll
      for(int r=0;r<4;r++){
        int t=mt*16+l4*4+r, s=nt*16+l15;
        Alds[t*LDK+s]=(s<=t)? f2bf(a4[r]) : (unsigned short)0;
      }
    }
  }
  {
    int sg=tid/24, ql=tid-sg*24, q=half*24+ql, head=q>>3;
    f32 vv[4][4];
    #pragma unroll
    for(int j=0;j<4;j++){
      int s=sg*4+j;
      float4 xv=((const float4*)&xh[(size_t)(b*4096+pos_of(dir,c0+s))*192])[q];
      f32 w1=w1l[s][head];
      vv[j][0]=xv.x*w1; vv[j][1]=xv.y*w1; vv[j][2]=xv.z*w1; vv[j][3]=xv.w*w1;
    }
    #pragma unroll
    for(int cc=0;cc<4;cc++){
      u16x4 w={f2bf(vv[0][cc]),f2bf(vv[1][cc]),f2bf(vv[2][cc]),f2bf(vv[3][cc])};
      *(u16x4*)&Blds[(4*ql+cc)*LDK+sg*4]=w;
    }
  }
  __syncthreads();
  f32x4 acc[4];
  #pragma unroll
  for(int mt=0;mt<4;mt++){ f32x4 zz={0.f,0.f,0.f,0.f}; acc[mt]=zz; }
  #pragma unroll
  for(int ks=0;ks<3;ks++){
    const int kg=ks*4+l4;
    bf16x8 bfr=*(const bf16x8*)&Blds[(wv*16+l15)*LDK+kg*8];
    #pragma unroll
    for(int mt=0;mt<4;mt++){
      bf16x8 af=*(const bf16x8*)&Alds[(mt*16+l15)*LDK+kg*8];
      acc[mt]=__builtin_amdgcn_mfma_f32_16x16x32_bf16(af,bfr,acc[mt],0,0,0);
    }
  }
  const int lr=wv*16+l15, gch=half*96+lr, head=gch>>5;
  const f32 Dv=Dsw[dir*192+gch];
  #pragma unroll
  for(int mt=0;mt<4;mt++){
    #pragma unroll
    for(int r=0;r<4;r++){
      int t=mt*16+l4*4+r;
      f32 er=erowl[t][head];
      f32 xv=bfr2f(Blds[lr*LDK+t])*er/dtl[t][head];
      f32 v=acc[mt][r]*er + Dv*xv;
      size_t o=((size_t)(b*4096+pos_of(dir,c0+t)))*192+gch;
      if(dirbase==0) ym[o]=v; else ym[o]+=v;
    }
  }
}

// ---------------- Kernel E: layernorm(192) of (ym0+ym1) then * z ----------------
__global__ __launch_bounds__(256) void k_ln(const f32* __restrict__ ym0, const f32* __restrict__ ym1,
                                            f32* __restrict__ z,
                                            const f32* __restrict__ lw, const f32* __restrict__ lb){
  const int row=blockIdx.x*4+(threadIdx.x>>6), lane=threadIdx.x&63;
  const f32* yr0=&ym0[(size_t)row*192];
  const f32* yr1=&ym1[(size_t)row*192];
  f32 v0=yr0[lane]+yr1[lane], v1=yr0[lane+64]+yr1[lane+64], v2=yr0[lane+128]+yr1[lane+128];
  f32 s=v0+v1+v2;
  #pragma unroll
  for(int off=32;off>0;off>>=1) s+=__shfl_xor(s,off,64);
  const f32 mu=s*(1.f/192.f);
  f32 d0=v0-mu,d1=v1-mu,d2=v2-mu;
  f32 q=d0*d0+d1*d1+d2*d2;
  #pragma unroll
  for(int off=32;off>0;off>>=1) q+=__shfl_xor(q,off,64);
  const f32 rs=rsqrtf(q*(1.f/192.f)+1e-5f);
  f32* zr=&z[(size_t)row*192];
  zr[lane]    =(d0*rs*lw[lane]    +lb[lane])    *zr[lane];
  zr[lane+64] =(d1*rs*lw[lane+64] +lb[lane+64]) *zr[lane+64];
  zr[lane+128]=(d2*rs*lw[lane+128]+lb[lane+128])*zr[lane+128];
}

// ---------------- Kernel F (MFMA): out = u @ out_proj_w.T ----------------------
// M=32768 (BM=64), N=96 (6 nt), K=192 (6 steps).
__global__ __launch_bounds__(256) void k_outproj(const f32* __restrict__ u, const unsigned short* __restrict__ Wo,
                                                 f32* __restrict__ out){
  __shared__ unsigned short Ald[24*64*8];      // 24 KB
  const int m0=blockIdx.x*64, tid=threadIdx.x;
  for(int i=tid;i<1536;i+=256){
    int r=i&63, g=i>>6;
    const f32* p=&u[(size_t)(m0+r)*192+g*8];
    float4 v0=*(const float4*)p, v1=*(const float4*)(p+4);
    u16x8 w={f2bf(v0.x),f2bf(v0.y),f2bf(v0.z),f2bf(v0.w),
             f2bf(v1.x),f2bf(v1.y),f2bf(v1.z),f2bf(v1.w)};
    *(u16x8*)&Ald[(size_t)(g*64+r)*8]=w;
  }
  __syncthreads();
  const int wv=tid>>6, lane=tid&63, l15=lane&15, l4=lane>>4;
  f32x4 acc[6];
  #pragma unroll
  for(int nt=0;nt<6;nt++){ f32x4 zz={0.f,0.f,0.f,0.f}; acc[nt]=zz; }
  #pragma unroll
  for(int ks=0;ks<6;ks++){
    const int g=ks*4+l4;
    bf16x8 a=*(const bf16x8*)&Ald[(size_t)(g*64+wv*16+l15)*8];
    #pragma unroll
    for(int nt=0;nt<6;nt++){
      bf16x8 bfr=*(const bf16x8*)&Wo[((size_t)(nt*24+g)*16+l15)*8];
      acc[nt]=__builtin_amdgcn_mfma_f32_16x16x32_bf16(a,bfr,acc[nt],0,0,0);
    }
  }
  const int rowb=m0+wv*16+l4*4;
  #pragma unroll
  for(int nt=0;nt<6;nt++){
    int col=nt*16+l15;
    #pragma unroll
    for(int r=0;r<4;r++){
      out[(size_t)(rowb+r)*96+col]=acc[nt][r];
    }
  }
}

extern "C" void kernel_launch(void* const* d_in, const int* in_sizes, int n_in,
                              void* d_out, int out_size, void* d_ws, size_t ws_size,
                              hipStream_t stream){
  const f32* x  =(const f32*)d_in[0];
  const f32* ipw=(const f32*)d_in[1];
  const f32* cw =(const f32*)d_in[2];
  const f32* cb =(const f32*)d_in[3];
  const f32* xpw=(const f32*)d_in[4];
  const f32* alg=(const f32*)d_in[5];
  const f32* dsw=(const f32*)d_in[6];
  const f32* dtb=(const f32*)d_in[7];
  const f32* lw =(const f32*)d_in[8];
  const f32* lb =(const f32*)d_in[9];
  const f32* opw=(const f32*)d_in[10];
  f32* out=(f32*)d_out;
  f32* ws=(f32*)d_ws;

  f32* xh_raw=ws;               // 6291456 floats (reused as ym0)
  f32* z     =ws+ 6291456;      // 6291456
  f32* xh    =ws+12582912;      // 6291456
  f32* dt_sp =ws+18874368;      //  786432
  f32* Bg    =ws+19660800;      // 2097152
  f32* Cg    =ws+21757952;      // 2097152
  f32* S     =ws+23855104;      // 6291456
  f32* ach   =ws+30146560;      //   12288
  f32* ym1   =ws+30158848;      // 6291456
  unsigned short* Wx=(unsigned short*)(ws+36450304);   // 30720 u16 = 15360 f32
  unsigned short* Wi=(unsigned short*)(ws+36465664);   // 36864 u16 = 18432 f32
  unsigned short* Wo=(unsigned short*)(ws+36484096);   // 18432 u16 =  9216 f32
  f32* ym0=xh_raw;

  k_wcvt_all<<<42,256,0,stream>>>(xpw,ipw,opw,Wx,Wi,Wo);
  k_inproj<<<512,256,0,stream>>>(x,Wi,xh_raw,z);
  k_conv<<<6144,256,0,stream>>>(xh_raw,cw,cb,xh);
  k_xdbl<<<dim3(512),256,0,stream>>>(xh,Wx,dtb,dt_sp,Bg,Cg);
  k_chunk1<<<dim3(64,4,8),384,0,stream>>>(xh,Bg,dt_sp,alg,S,ach);
  k_scan<<<384,256,0,stream>>>(S,ach);
  k_chunk2<<<dim3(64,8,4),384,0,stream>>>(xh,Bg,Cg,dt_sp,S,alg,dsw,ym0,ym1,0);
  k_chunk2<<<dim3(64,8,4),384,0,stream>>>(xh,Bg,Cg,dt_sp,S,alg,dsw,ym0,ym1,2);
  k_ln<<<8192,256,0,stream>>>(ym0,ym1,z,lw,lb);
  k_outproj<<<512,256,0,stream>>>(z,Wo,out);
}

// Round 9
// 199.477 us; speedup vs baseline: 2.8591x; 1.1408x over previous
//
#include <hip/hip_runtime.h>
#include <hip/hip_bf16.h>

using bf16 = __hip_bfloat16;
typedef float f32;
typedef __attribute__((ext_vector_type(8))) short bf16x8;
typedef __attribute__((ext_vector_type(4))) float f32x4;
typedef __attribute__((ext_vector_type(4))) unsigned short u16x4;
typedef __attribute__((ext_vector_type(8))) unsigned short u16x8;

static __device__ __forceinline__ f32 siluf(f32 v){ return v / (1.f + __expf(-v)); }
static __device__ __forceinline__ unsigned short f2bf(f32 v){
  __hip_bfloat16 h=__float2bfloat16(v); return *(unsigned short*)&h;
}
static __device__ __forceinline__ f32 bfr2f(unsigned short u){
  unsigned int x=((unsigned int)u)<<16; return __uint_as_float(x);
}

// spatial position of sequence index p for scan direction dir (H=W=64, L=4096)
static __device__ __forceinline__ int pos_of(int dir, int p){
  if(dir==0) return p;
  if(dir==1) return ((p&63)<<6) | (p>>6);
  if(dir==2) return 4095-p;
  int q = 4095-p; return ((q&63)<<6) | (q>>6);
}

// inclusive wave-64 prefix scan
static __device__ __forceinline__ f32 wave_iscan(f32 v, int lane){
  #pragma unroll
  for(int off=1; off<64; off<<=1){
    f32 u=__shfl_up(v,off,64);
    if(lane>=off) v+=u;
  }
  return v;
}
// inclusive wave-64 suffix scan (v[lane] = sum_{j>=lane})
static __device__ __forceinline__ f32 wave_sscan(f32 v, int lane){
  #pragma unroll
  for(int off=1; off<64; off<<=1){
    f32 u=__shfl_down(v,off,64);
    if(lane<64-off) v+=u;
  }
  return v;
}

// ---------------- Kernel W: all three weight matrices -> bf16 fragment layout --
__global__ __launch_bounds__(256) void k_wcvt_all(const f32* __restrict__ xpw, const f32* __restrict__ ipw,
                                                  const f32* __restrict__ opw, unsigned short* __restrict__ Wx,
                                                  unsigned short* __restrict__ Wi, unsigned short* __restrict__ Wo){
  const int t=blockIdx.x*256+threadIdx.x;
  if(t<3840){
    const int g=t%24, n=t/24, nt=n>>4, l=n&15;
    const int dir=n/40, cc=n-dir*40;
    u16x8 w={0,0,0,0,0,0,0,0};
    if(cc<38){
      const f32* p=&xpw[(size_t)dir*7296+cc*192+g*8];
      #pragma unroll
      for(int j=0;j<8;j++) w[j]=f2bf(p[j]);
    }
    *(u16x8*)&Wx[((size_t)(nt*24+g)*16+l)*8]=w;
  } else if(t<8448){
    const int i=t-3840, g=i%12, n=i/12, nt=n>>4, l=n&15;
    const f32* p=&ipw[(size_t)n*96+g*8];
    u16x8 w;
    #pragma unroll
    for(int j=0;j<8;j++) w[j]=f2bf(p[j]);
    *(u16x8*)&Wi[((size_t)(nt*12+g)*16+l)*8]=w;
  } else if(t<10752){
    const int i=t-8448, g=i%24, n=i/24, nt=n>>4, l=n&15;
    const f32* p=&opw[(size_t)n*192+g*8];
    u16x8 w;
    #pragma unroll
    for(int j=0;j<8;j++) w[j]=f2bf(p[j]);
    *(u16x8*)&Wo[((size_t)(nt*24+g)*16+l)*8]=w;
  }
}

// ---------------- Kernel A (MFMA): xz = x @ in_proj_w.T ; split, silu ----------
__global__ __launch_bounds__(256) void k_inproj(const f32* __restrict__ x, const unsigned short* __restrict__ Wi,
                                                f32* __restrict__ xh_raw, f32* __restrict__ z){
  __shared__ unsigned short Ald[12*64*8];      // 12 KB
  const int m0=blockIdx.x*64, tid=threadIdx.x;
  for(int i=tid;i<768;i+=256){
    int r=i&63, g=i>>6;
    const f32* p=&x[(size_t)(m0+r)*96+g*8];
    float4 v0=*(const float4*)p, v1=*(const float4*)(p+4);
    u16x8 w={f2bf(v0.x),f2bf(v0.y),f2bf(v0.z),f2bf(v0.w),
             f2bf(v1.x),f2bf(v1.y),f2bf(v1.z),f2bf(v1.w)};
    *(u16x8*)&Ald[(size_t)(g*64+r)*8]=w;
  }
  __syncthreads();
  const int wv=tid>>6, lane=tid&63, l15=lane&15, l4=lane>>4;
  f32x4 acc[24];
  #pragma unroll
  for(int nt=0;nt<24;nt++){ f32x4 zz={0.f,0.f,0.f,0.f}; acc[nt]=zz; }
  #pragma unroll
  for(int ks=0;ks<3;ks++){
    const int g=ks*4+l4;
    bf16x8 a=*(const bf16x8*)&Ald[(size_t)(g*64+wv*16+l15)*8];
    #pragma unroll
    for(int nt=0;nt<24;nt++){
      bf16x8 bfr=*(const bf16x8*)&Wi[((size_t)(nt*12+g)*16+l15)*8];
      acc[nt]=__builtin_amdgcn_mfma_f32_16x16x32_bf16(a,bfr,acc[nt],0,0,0);
    }
  }
  const int rowb=m0+wv*16+l4*4;
  #pragma unroll
  for(int nt=0;nt<24;nt++){
    int col=nt*16+l15;
    #pragma unroll
    for(int r=0;r<4;r++){
      int row=rowb+r; f32 v=acc[nt][r];
      if(col<192) xh_raw[(size_t)row*192+col]=v;
      else        z[(size_t)row*192+(col-192)]=siluf(v);
    }
  }
}

// ---------------- Kernel B: depthwise 3x3 conv + bias + silu --------------------
__global__ __launch_bounds__(256) void k_conv(const f32* __restrict__ xh_raw, const f32* __restrict__ cw,
                                              const f32* __restrict__ cb, f32* __restrict__ xh){
  __shared__ f32 wsm[192][9];
  __shared__ f32 bsm[192];
  const int tid=threadIdx.x;
  for(int i=tid;i<1728;i+=256) wsm[i/9][i%9]=cw[i];
  for(int i=tid;i<192;i+=256) bsm[i]=cb[i];
  __syncthreads();
  const int idx=blockIdx.x*256+tid;
  const int c4=idx%48, j=(idx/48)&63, ii0=(idx/3072)&63, b=idx/196608;
  const int c0=c4*4;
  f32 acc[4]={bsm[c0],bsm[c0+1],bsm[c0+2],bsm[c0+3]};
  #pragma unroll
  for(int a=0;a<3;a++){
    int ii=ii0+a-1; if(ii<0||ii>63) continue;
    #pragma unroll
    for(int bb=0;bb<3;bb++){
      int jj=j+bb-1; if(jj<0||jj>63) continue;
      float4 v=*(const float4*)&xh_raw[((size_t)(b*4096)+(ii*64+jj))*192 + c0];
      int t=a*3+bb;
      acc[0]+=v.x*wsm[c0][t]; acc[1]+=v.y*wsm[c0+1][t];
      acc[2]+=v.z*wsm[c0+2][t]; acc[3]+=v.w*wsm[c0+3][t];
    }
  }
  float4 o; o.x=siluf(acc[0]); o.y=siluf(acc[1]); o.z=siluf(acc[2]); o.w=siluf(acc[3]);
  ((float4*)xh)[idx]=o;
}

// ---------------- Kernel C (MFMA): x_dbl = xh @ Wx^T -> dt(softplus), B, C -----
__global__ __launch_bounds__(256) void k_xdbl(const f32* __restrict__ xh, const unsigned short* __restrict__ Wfrag,
                                              const f32* __restrict__ dtb, f32* __restrict__ dt_sp,
                                              f32* __restrict__ Bg, f32* __restrict__ Cg){
  __shared__ unsigned short Ald[24*64*8];      // 24 KB
  const int m0=blockIdx.x*64;
  const int tid=threadIdx.x;
  for(int i=tid;i<1536;i+=256){
    int r=i&63, g=i>>6;
    const f32* p=&xh[(size_t)(m0+r)*192 + g*8];
    float4 v0=*(const float4*)p, v1=*(const float4*)(p+4);
    u16x8 w={f2bf(v0.x),f2bf(v0.y),f2bf(v0.z),f2bf(v0.w),
             f2bf(v1.x),f2bf(v1.y),f2bf(v1.z),f2bf(v1.w)};
    *(u16x8*)&Ald[(size_t)(g*64+r)*8]=w;
  }
  __syncthreads();
  const int wv=tid>>6, lane=tid&63, l15=lane&15, l4=lane>>4;
  f32x4 acc[10];
  #pragma unroll
  for(int nt=0;nt<10;nt++){ f32x4 zz={0.f,0.f,0.f,0.f}; acc[nt]=zz; }
  #pragma unroll
  for(int ks=0;ks<6;ks++){
    const int g=ks*4+l4;
    bf16x8 a=*(const bf16x8*)&Ald[(size_t)(g*64 + wv*16 + l15)*8];
    #pragma unroll
    for(int nt=0;nt<10;nt++){
      bf16x8 bfr=*(const bf16x8*)&Wfrag[((size_t)(nt*24+g)*16+l15)*8];
      acc[nt]=__builtin_amdgcn_mfma_f32_16x16x32_bf16(a,bfr,acc[nt],0,0,0);
    }
  }
  const int rowb=m0 + wv*16 + l4*4;
  #pragma unroll
  for(int nt=0;nt<10;nt++){
    int n=nt*16+l15, dir=n/40, cc=n-dir*40;
    if(cc>=38) continue;
    #pragma unroll
    for(int r=0;r<4;r++){
      size_t pix=(size_t)(rowb+r);
      f32 v=acc[nt][r];
      if(cc<6){ f32 xv=v+dtb[dir*6+cc]; dt_sp[pix*24+dir*6+cc]=(xv>20.f)? xv : log1pf(__expf(xv)); }
      else if(cc<22){ Bg[(pix*4+dir)*16+(cc-6)]=v; }
      else          { Cg[(pix*4+dir)*16+(cc-22)]=v; }
    }
  }
}

// ---------------- Kernel D1 (MFMA): S_loc = e63 * (B' @ Bt^T) ------------------
#define LDK1 72
__global__ __launch_bounds__(384) void k_chunk1(const f32* __restrict__ xh, const f32* __restrict__ Bg,
      const f32* __restrict__ dt_sp, const f32* __restrict__ Alogs, f32* __restrict__ S, f32* __restrict__ ach){
  __shared__ unsigned short Bp[192*LDK1];
  __shared__ unsigned short BtT[16*LDK1];
  __shared__ f32 dtl[64][6], w1l[64][6];
  __shared__ f32 e63[6];
  const int c=blockIdx.x, dir=blockIdx.y, b=blockIdx.z, c0=c*64, tid=threadIdx.x;
  { int r=tid/6, q=tid-r*6; size_t pix=(size_t)b*4096+pos_of(dir,c0+r);
    dtl[r][q]=dt_sp[pix*24+dir*6+q]; }
  if(tid<256){
    int r=tid>>2,q=tid&3; size_t pix=(size_t)b*4096+pos_of(dir,c0+r);
    float4 bv=*(const float4*)&Bg[(pix*4+dir)*16+q*4];
    BtT[(4*q+0)*LDK1+r]=f2bf(bv.x); BtT[(4*q+1)*LDK1+r]=f2bf(bv.y);
    BtT[(4*q+2)*LDK1+r]=f2bf(bv.z); BtT[(4*q+3)*LDK1+r]=f2bf(bv.w);
  }
  __syncthreads();
  const int wv=tid>>6, lane=tid&63;
  {
    f32 A=-__expf(Alogs[dir*6+wv]);
    f32 dv=dtl[lane][wv];
    f32 v=wave_iscan(dv*A,lane);
    w1l[lane][wv]=__expf(-v)*dv;
    if(lane==63){
      f32 e=__expf(v);
      e63[wv]=e;
      ach[((size_t)(b*64+c))*24+dir*6+wv]=e;
    }
  }
  __syncthreads();
  for(int u=tid;u<768;u+=384){
    int sg=u/48, q=u-sg*48, head=q>>3;
    f32 vv[4][4];
    #pragma unroll
    for(int j=0;j<4;j++){
      int s=sg*4+j;
      float4 xv=((const float4*)&xh[(size_t)(b*4096+pos_of(dir,c0+s))*192])[q];
      f32 w1=w1l[s][head];
      vv[j][0]=xv.x*w1; vv[j][1]=xv.y*w1; vv[j][2]=xv.z*w1; vv[j][3]=xv.w*w1;
    }
    #pragma unroll
    for(int cc=0;cc<4;cc++){
      u16x4 w={f2bf(vv[0][cc]),f2bf(vv[1][cc]),f2bf(vv[2][cc]),f2bf(vv[3][cc])};
      *(u16x4*)&Bp[(4*q+cc)*LDK1+sg*4]=w;
    }
  }
  __syncthreads();
  const int l15=lane&15, l4=lane>>4;
  f32x4 acc[2];
  { f32x4 zz={0.f,0.f,0.f,0.f}; acc[0]=zz; acc[1]=zz; }
  #pragma unroll
  for(int i=0;i<2;i++){
    int mt=wv+6*i;
    #pragma unroll
    for(int ks=0;ks<2;ks++){
      int kg=ks*4+l4;
      bf16x8 a=*(const bf16x8*)&Bp[(size_t)(mt*16+l15)*LDK1+kg*8];
      bf16x8 bb=*(const bf16x8*)&BtT[(size_t)l15*LDK1+kg*8];
      acc[i]=__builtin_amdgcn_mfma_f32_16x16x32_bf16(a,bb,acc[i],0,0,0);
    }
  }
  const size_t base=(((size_t)(b*64+c))*24+dir*6)*512;
  #pragma unroll
  for(int i=0;i<2;i++){
    int mt=wv+6*i;
    #pragma unroll
    for(int r=0;r<4;r++){
      int ch=mt*16+l4*4+r, head=ch>>5, d=ch&31;
      S[base+(size_t)head*512+d*16+l15]=acc[i][r]*e63[head];
    }
  }
}

// ---------------- Kernel D2: serial inter-chunk scan (in-place S -> prev) ------
__global__ __launch_bounds__(256) void k_scan(f32* __restrict__ S, const f32* __restrict__ ach){
  const int g=blockIdx.x*256+threadIdx.x;
  const int b=g/12288, rem=g%12288, h=rem/512;
  size_t base=(size_t)b*786432 + rem;
  const f32* ap=&ach[(size_t)b*1536 + h];
  f32 st=0.f;
  for(int c=0;c<64;c++){
    f32 a=ap[c*24];
    f32 s=S[base+(size_t)c*12288];
    S[base+(size_t)c*12288]=st;
    st=a*st+s;
  }
}

// ---------------- Kernel D3 (MFMA, merged dirs): both paired dirs per block -----
// grid (64 c, 8 b, 4 = pair*2+half), 384 thr = 6 waves.
// pair 0 = dirs {0,2} (row tiles) -> ym0 ; pair 1 = dirs {1,3} (col tiles) -> ym1.
// dir pair+2 handled in pixel order via suffix scan + upper-triangle mask.
#define LDK 104
#define XLP 100
__global__ __launch_bounds__(384) void k_chunk2(const f32* __restrict__ xh, const f32* __restrict__ Bg,
      const f32* __restrict__ Cg, const f32* __restrict__ dt_sp, const f32* __restrict__ Sprev,
      const f32* __restrict__ Alogs, const f32* __restrict__ Dsw,
      f32* __restrict__ ym0, f32* __restrict__ ym1){
  __shared__ unsigned short Xl[64*XLP];     // 12.5 KB: x bf16, this half's 96 ch
  __shared__ unsigned short Alds[64*LDK];   // 13.3 KB: [CBtri | Ct | 0]
  __shared__ unsigned short Blds[96*LDK];   // 20.0 KB: [x*w1 ; prevT ; 0]
  __shared__ unsigned short Btf[64*32];     // 4 KB (16 real k + 16 zero)
  __shared__ f32 dtl[64][6], w1l[64][6], erowl[64][6];
  const int c=blockIdx.x, b=blockIdx.y, pair=blockIdx.z>>1, half=blockIdx.z&1;
  const int c0=c*64, tid=threadIdx.x;
  f32* __restrict__ ym = pair? ym1 : ym0;
  const int wv=tid>>6, lane=tid&63, l15=lane&15, l4=lane>>4;
  // stage Xl once (shared by both dirs)
  for(int i=tid;i<1536;i+=384){
    int t=i/24, g=i%24;
    size_t pix=(size_t)b*4096 + (pair==0 ? (c0+t) : (t*64+c));
    float4 v=*(const float4*)&xh[pix*192 + half*96 + g*4];
    u16x4 w={f2bf(v.x),f2bf(v.y),f2bf(v.z),f2bf(v.w)};
    *(u16x4*)&Xl[t*XLP+g*4]=w;
  }
  f32 vsum[4][4];
  #pragma unroll
  for(int mt=0;mt<4;mt++){
    #pragma unroll
    for(int r=0;r<4;r++) vsum[mt][r]=0.f;
  }
  const int lch=wv*16+l15, gch=half*96+lch, ohead=gch>>5;
  #pragma unroll
  for(int d=0;d<2;d++){
    const int dir=pair+d*2;
    const int cd=d? (63-c) : c;
    __syncthreads();   // d=0: Xl ready; d=1: previous MFMA reads done
    // stage dt (pixel order)
    { int r=tid/6, q=tid-r*6;
      size_t pix=(size_t)b*4096 + (pair==0 ? (c0+r) : (r*64+c));
      dtl[r][q]=dt_sp[pix*24+dir*6+q]; }
    // stage B->Btf, C->Alds cols 64..95 (pixel order)
    if(tid<256){
      int r=tid>>2,q=tid&3;
      size_t pix=(size_t)b*4096 + (pair==0 ? (c0+r) : (r*64+c));
      float4 bv=*(const float4*)&Bg[(pix*4+dir)*16+q*4];
      float4 cv=*(const float4*)&Cg[(pix*4+dir)*16+q*4];
      u16x4 wb={f2bf(bv.x),f2bf(bv.y),f2bf(bv.z),f2bf(bv.w)};
      u16x4 wc={f2bf(cv.x),f2bf(cv.y),f2bf(cv.z),f2bf(cv.w)};
      u16x4 zz={0,0,0,0};
      *(u16x4*)&Btf[r*32+q*4]=wb;      *(u16x4*)&Btf[r*32+16+q*4]=zz;
      *(u16x4*)&Alds[r*LDK+64+q*4]=wc; *(u16x4*)&Alds[r*LDK+80+q*4]=zz;
    }
    // stage prevT (chunk cd of this dir)
    {
      const size_t pbase=(((size_t)(b*64+cd))*24+dir*6)*512;
      int lr=tid>>2, ng=tid&3, g2=half*96+lr, hh=g2>>5, dd=g2&31;
      float4 pv=*(const float4*)&Sprev[pbase+(size_t)hh*512+dd*16+ng*4];
      u16x4 w={f2bf(pv.x),f2bf(pv.y),f2bf(pv.z),f2bf(pv.w)};
      u16x4 zz={0,0,0,0};
      *(u16x4*)&Blds[lr*LDK+64+ng*4]=w;
      *(u16x4*)&Blds[lr*LDK+80+ng*4]=zz;
    }
    __syncthreads();
    // per-head scan: prefix for dir A (seq order = pixel order), suffix for dir B
    {
      f32 Aa=-__expf(Alogs[dir*6+wv]);
      f32 dv=dtl[lane][wv];
      f32 sc = d? wave_sscan(dv*Aa,lane) : wave_iscan(dv*Aa,lane);
      w1l[lane][wv]=__expf(-sc)*dv;
      erowl[lane][wv]=__expf(sc);
    }
    __syncthreads();
    // CB = Ct@Bt^T via MFMA (A-frag read from Alds cols 64..95), masked write
    #pragma unroll
    for(int tt=0;tt<3;tt++){
      int tile=wv+6*tt;
      if(tile<16){
        int mt=tile>>2, nt=tile&3;
        f32x4 a4={0.f,0.f,0.f,0.f};
        bf16x8 af=*(const bf16x8*)&Alds[(mt*16+l15)*LDK+64+l4*8];
        bf16x8 bfr=*(const bf16x8*)&Btf[(nt*16+l15)*32+l4*8];
        a4=__builtin_amdgcn_mfma_f32_16x16x32_bf16(af,bfr,a4,0,0,0);
        #pragma unroll
        for(int r=0;r<4;r++){
          int t=mt*16+l4*4+r, s=nt*16+l15;
          bool keep = d? (s>=t) : (s<=t);
          Alds[t*LDK+s]= keep? f2bf(a4[r]) : (unsigned short)0;
        }
      }
    }
    // B' = Xl * w1 (transposed write)
    {
      int sg=tid/24, ql=tid-sg*24;
      int head=(half*96+ql*4)>>5;
      f32 vv[4][4];
      #pragma unroll
      for(int j=0;j<4;j++){
        int s=sg*4+j;
        u16x4 xv=*(const u16x4*)&Xl[s*XLP+ql*4];
        f32 w1=w1l[s][head];
        vv[j][0]=bfr2f(xv[0])*w1; vv[j][1]=bfr2f(xv[1])*w1;
        vv[j][2]=bfr2f(xv[2])*w1; vv[j][3]=bfr2f(xv[3])*w1;
      }
      #pragma unroll
      for(int cc=0;cc<4;cc++){
        u16x4 w={f2bf(vv[0][cc]),f2bf(vv[1][cc]),f2bf(vv[2][cc]),f2bf(vv[3][cc])};
        *(u16x4*)&Blds[(4*ql+cc)*LDK+sg*4]=w;
      }
    }
    __syncthreads();
    // main MFMA 64x96x96 + epilogue accumulate
    f32x4 acc[4];
    #pragma unroll
    for(int mt=0;mt<4;mt++){ f32x4 zz={0.f,0.f,0.f,0.f}; acc[mt]=zz; }
    #pragma unroll
    for(int ks=0;ks<3;ks++){
      const int kg=ks*4+l4;
      bf16x8 bfr=*(const bf16x8*)&Blds[(wv*16+l15)*LDK+kg*8];
      #pragma unroll
      for(int mt=0;mt<4;mt++){
        bf16x8 af=*(const bf16x8*)&Alds[(mt*16+l15)*LDK+kg*8];
        acc[mt]=__builtin_amdgcn_mfma_f32_16x16x32_bf16(af,bfr,acc[mt],0,0,0);
      }
    }
    const f32 Dv=Dsw[dir*192+gch];
    #pragma unroll
    for(int mt=0;mt<4;mt++){
      #pragma unroll
      for(int r=0;r<4;r++){
        int t=mt*16+l4*4+r;
        f32 er=erowl[t][ohead];
        f32 xv=bfr2f(Xl[t*XLP+lch]);
        vsum[mt][r]+=acc[mt][r]*er + Dv*xv;
      }
    }
  }
  // single store (no RMW)
  #pragma unroll
  for(int mt=0;mt<4;mt++){
    #pragma unroll
    for(int r=0;r<4;r++){
      int t=mt*16+l4*4+r;
      size_t pix=(size_t)b*4096 + (pair==0 ? (c0+t) : (t*64+c));
      ym[pix*192+gch]=vsum[mt][r];
    }
  }
}

// ---------------- Kernel F (MFMA, fused LN+gate): out = LN(ym0+ym1)*z @ Wo^T ---
__global__ __launch_bounds__(256) void k_outproj(const f32* __restrict__ ym0, const f32* __restrict__ ym1,
                                                 const f32* __restrict__ z,
                                                 const f32* __restrict__ lw, const f32* __restrict__ lb,
                                                 const unsigned short* __restrict__ Wo, f32* __restrict__ out){
  __shared__ unsigned short Ald[24*64*8];      // 24 KB
  __shared__ f32 lws[192], lbs[192];
  const int m0=blockIdx.x*64, tid=threadIdx.x;
  for(int i=tid;i<192;i+=256){ lws[i]=lw[i]; lbs[i]=lb[i]; }
  __syncthreads();
  const int r=tid>>2, sub=tid&3;
  const size_t base=(size_t)(m0+r)*192 + sub*48;
  f32 y[48];
  f32 s=0.f;
  #pragma unroll
  for(int j=0;j<48;j+=4){
    float4 a=*(const float4*)&ym0[base+j];
    float4 bb=*(const float4*)&ym1[base+j];
    y[j]=a.x+bb.x; y[j+1]=a.y+bb.y; y[j+2]=a.z+bb.z; y[j+3]=a.w+bb.w;
    s+=y[j]+y[j+1]+y[j+2]+y[j+3];
  }
  s+=__shfl_xor(s,1,64); s+=__shfl_xor(s,2,64);
  const f32 mu=s*(1.f/192.f);
  f32 q=0.f;
  #pragma unroll
  for(int j=0;j<48;j++){ f32 dd=y[j]-mu; q+=dd*dd; }
  q+=__shfl_xor(q,1,64); q+=__shfl_xor(q,2,64);
  const f32 rs=rsqrtf(q*(1.f/192.f)+1e-5f);
  #pragma unroll
  for(int j=0;j<48;j+=8){
    float4 z0=*(const float4*)&z[base+j];
    float4 z1=*(const float4*)&z[base+j+4];
    int col=sub*48+j;
    u16x8 w;
    w[0]=f2bf(((y[j+0]-mu)*rs*lws[col+0]+lbs[col+0])*z0.x);
    w[1]=f2bf(((y[j+1]-mu)*rs*lws[col+1]+lbs[col+1])*z0.y);
    w[2]=f2bf(((y[j+2]-mu)*rs*lws[col+2]+lbs[col+2])*z0.z);
    w[3]=f2bf(((y[j+3]-mu)*rs*lws[col+3]+lbs[col+3])*z0.w);
    w[4]=f2bf(((y[j+4]-mu)*rs*lws[col+4]+lbs[col+4])*z1.x);
    w[5]=f2bf(((y[j+5]-mu)*rs*lws[col+5]+lbs[col+5])*z1.y);
    w[6]=f2bf(((y[j+6]-mu)*rs*lws[col+6]+lbs[col+6])*z1.z);
    w[7]=f2bf(((y[j+7]-mu)*rs*lws[col+7]+lbs[col+7])*z1.w);
    int g=col>>3;
    *(u16x8*)&Ald[((size_t)g*64+r)*8]=w;
  }
  __syncthreads();
  const int wv=tid>>6, lane=tid&63, l15=lane&15, l4=lane>>4;
  f32x4 acc[6];
  #pragma unroll
  for(int nt=0;nt<6;nt++){ f32x4 zz={0.f,0.f,0.f,0.f}; acc[nt]=zz; }
  #pragma unroll
  for(int ks=0;ks<6;ks++){
    const int g=ks*4+l4;
    bf16x8 a=*(const bf16x8*)&Ald[(size_t)(g*64+wv*16+l15)*8];
    #pragma unroll
    for(int nt=0;nt<6;nt++){
      bf16x8 bfr=*(const bf16x8*)&Wo[((size_t)(nt*24+g)*16+l15)*8];
      acc[nt]=__builtin_amdgcn_mfma_f32_16x16x32_bf16(a,bfr,acc[nt],0,0,0);
    }
  }
  const int rowb=m0+wv*16+l4*4;
  #pragma unroll
  for(int nt=0;nt<6;nt++){
    int col=nt*16+l15;
    #pragma unroll
    for(int r2=0;r2<4;r2++){
      out[(size_t)(rowb+r2)*96+col]=acc[nt][r2];
    }
  }
}

extern "C" void kernel_launch(void* const* d_in, const int* in_sizes, int n_in,
                              void* d_out, int out_size, void* d_ws, size_t ws_size,
                              hipStream_t stream){
  const f32* x  =(const f32*)d_in[0];
  const f32* ipw=(const f32*)d_in[1];
  const f32* cw =(const f32*)d_in[2];
  const f32* cb =(const f32*)d_in[3];
  const f32* xpw=(const f32*)d_in[4];
  const f32* alg=(const f32*)d_in[5];
  const f32* dsw=(const f32*)d_in[6];
  const f32* dtb=(const f32*)d_in[7];
  const f32* lw =(const f32*)d_in[8];
  const f32* lb =(const f32*)d_in[9];
  const f32* opw=(const f32*)d_in[10];
  f32* out=(f32*)d_out;
  f32* ws=(f32*)d_ws;

  f32* xh_raw=ws;               // 6291456 floats (reused as ym0)
  f32* z     =ws+ 6291456;      // 6291456
  f32* xh    =ws+12582912;      // 6291456
  f32* dt_sp =ws+18874368;      //  786432
  f32* Bg    =ws+19660800;      // 2097152
  f32* Cg    =ws+21757952;      // 2097152
  f32* S     =ws+23855104;      // 6291456
  f32* ach   =ws+30146560;      //   12288
  f32* ym1   =ws+30158848;      // 6291456
  unsigned short* Wx=(unsigned short*)(ws+36450304);
  unsigned short* Wi=(unsigned short*)(ws+36465664);
  unsigned short* Wo=(unsigned short*)(ws+36484096);
  f32* ym0=xh_raw;

  k_wcvt_all<<<42,256,0,stream>>>(xpw,ipw,opw,Wx,Wi,Wo);
  k_inproj<<<512,256,0,stream>>>(x,Wi,xh_raw,z);
  k_conv<<<6144,256,0,stream>>>(xh_raw,cw,cb,xh);
  k_xdbl<<<dim3(512),256,0,stream>>>(xh,Wx,dtb,dt_sp,Bg,Cg);
  k_chunk1<<<dim3(64,4,8),384,0,stream>>>(xh,Bg,dt_sp,alg,S,ach);
  k_scan<<<384,256,0,stream>>>(S,ach);
  k_chunk2<<<dim3(64,8,4),384,0,stream>>>(xh,Bg,Cg,dt_sp,S,alg,dsw,ym0,ym1);
  k_outproj<<<512,256,0,stream>>>(ym0,ym1,z,lw,lb,Wo,out);
}

// Round 10
// 189.295 us; speedup vs baseline: 3.0129x; 1.0538x over previous
//
#include <hip/hip_runtime.h>
#include <hip/hip_bf16.h>

using bf16 = __hip_bfloat16;
typedef float f32;
typedef __attribute__((ext_vector_type(8))) short bf16x8;
typedef __attribute__((ext_vector_type(4))) float f32x4;
typedef __attribute__((ext_vector_type(4))) unsigned short u16x4;
typedef __attribute__((ext_vector_type(8))) unsigned short u16x8;

static __device__ __forceinline__ f32 siluf(f32 v){ return v / (1.f + __expf(-v)); }
static __device__ __forceinline__ unsigned short f2bf(f32 v){
  __hip_bfloat16 h=__float2bfloat16(v); return *(unsigned short*)&h;
}
static __device__ __forceinline__ f32 bfr2f(unsigned short u){
  unsigned int x=((unsigned int)u)<<16; return __uint_as_float(x);
}

// spatial position of sequence index p for scan direction dir (H=W=64, L=4096)
static __device__ __forceinline__ int pos_of(int dir, int p){
  if(dir==0) return p;
  if(dir==1) return ((p&63)<<6) | (p>>6);
  if(dir==2) return 4095-p;
  int q = 4095-p; return ((q&63)<<6) | (q>>6);
}

// inclusive wave-64 prefix scan
static __device__ __forceinline__ f32 wave_iscan(f32 v, int lane){
  #pragma unroll
  for(int off=1; off<64; off<<=1){
    f32 u=__shfl_up(v,off,64);
    if(lane>=off) v+=u;
  }
  return v;
}
// inclusive wave-64 suffix scan (v[lane] = sum_{j>=lane})
static __device__ __forceinline__ f32 wave_sscan(f32 v, int lane){
  #pragma unroll
  for(int off=1; off<64; off<<=1){
    f32 u=__shfl_down(v,off,64);
    if(lane<64-off) v+=u;
  }
  return v;
}

// ---------------- Kernel W: all three weight matrices -> bf16 fragment layout --
__global__ __launch_bounds__(256) void k_wcvt_all(const f32* __restrict__ xpw, const f32* __restrict__ ipw,
                                                  const f32* __restrict__ opw, unsigned short* __restrict__ Wx,
                                                  unsigned short* __restrict__ Wi, unsigned short* __restrict__ Wo){
  const int t=blockIdx.x*256+threadIdx.x;
  if(t<3840){
    const int g=t%24, n=t/24, nt=n>>4, l=n&15;
    const int dir=n/40, cc=n-dir*40;
    u16x8 w={0,0,0,0,0,0,0,0};
    if(cc<38){
      const f32* p=&xpw[(size_t)dir*7296+cc*192+g*8];
      #pragma unroll
      for(int j=0;j<8;j++) w[j]=f2bf(p[j]);
    }
    *(u16x8*)&Wx[((size_t)(nt*24+g)*16+l)*8]=w;
  } else if(t<8448){
    const int i=t-3840, g=i%12, n=i/12, nt=n>>4, l=n&15;
    const f32* p=&ipw[(size_t)n*96+g*8];
    u16x8 w;
    #pragma unroll
    for(int j=0;j<8;j++) w[j]=f2bf(p[j]);
    *(u16x8*)&Wi[((size_t)(nt*12+g)*16+l)*8]=w;
  } else if(t<10752){
    const int i=t-8448, g=i%24, n=i/24, nt=n>>4, l=n&15;
    const f32* p=&opw[(size_t)n*192+g*8];
    u16x8 w;
    #pragma unroll
    for(int j=0;j<8;j++) w[j]=f2bf(p[j]);
    *(u16x8*)&Wo[((size_t)(nt*24+g)*16+l)*8]=w;
  }
}

// ---------------- Kernel A (MFMA): xz = x @ in_proj_w.T ; split, silu ----------
__global__ __launch_bounds__(256) void k_inproj(const f32* __restrict__ x, const unsigned short* __restrict__ Wi,
                                                f32* __restrict__ xh_raw, f32* __restrict__ z){
  __shared__ unsigned short Ald[12*64*8];      // 12 KB
  const int m0=blockIdx.x*64, tid=threadIdx.x;
  for(int i=tid;i<768;i+=256){
    int r=i&63, g=i>>6;
    const f32* p=&x[(size_t)(m0+r)*96+g*8];
    float4 v0=*(const float4*)p, v1=*(const float4*)(p+4);
    u16x8 w={f2bf(v0.x),f2bf(v0.y),f2bf(v0.z),f2bf(v0.w),
             f2bf(v1.x),f2bf(v1.y),f2bf(v1.z),f2bf(v1.w)};
    *(u16x8*)&Ald[(size_t)(g*64+r)*8]=w;
  }
  __syncthreads();
  const int wv=tid>>6, lane=tid&63, l15=lane&15, l4=lane>>4;
  f32x4 acc[24];
  #pragma unroll
  for(int nt=0;nt<24;nt++){ f32x4 zz={0.f,0.f,0.f,0.f}; acc[nt]=zz; }
  #pragma unroll
  for(int ks=0;ks<3;ks++){
    const int g=ks*4+l4;
    bf16x8 a=*(const bf16x8*)&Ald[(size_t)(g*64+wv*16+l15)*8];
    #pragma unroll
    for(int nt=0;nt<24;nt++){
      bf16x8 bfr=*(const bf16x8*)&Wi[((size_t)(nt*12+g)*16+l15)*8];
      acc[nt]=__builtin_amdgcn_mfma_f32_16x16x32_bf16(a,bfr,acc[nt],0,0,0);
    }
  }
  const int rowb=m0+wv*16+l4*4;
  #pragma unroll
  for(int nt=0;nt<24;nt++){
    int col=nt*16+l15;
    #pragma unroll
    for(int r=0;r<4;r++){
      int row=rowb+r; f32 v=acc[nt][r];
      if(col<192) xh_raw[(size_t)row*192+col]=v;
      else        z[(size_t)row*192+(col-192)]=siluf(v);
    }
  }
}

// ---------------- Kernel B: depthwise 3x3 conv + bias + silu --------------------
__global__ __launch_bounds__(256) void k_conv(const f32* __restrict__ xh_raw, const f32* __restrict__ cw,
                                              const f32* __restrict__ cb, f32* __restrict__ xh){
  __shared__ f32 wsm[192][9];
  __shared__ f32 bsm[192];
  const int tid=threadIdx.x;
  for(int i=tid;i<1728;i+=256) wsm[i/9][i%9]=cw[i];
  for(int i=tid;i<192;i+=256) bsm[i]=cb[i];
  __syncthreads();
  const int idx=blockIdx.x*256+tid;
  const int c4=idx%48, j=(idx/48)&63, ii0=(idx/3072)&63, b=idx/196608;
  const int c0=c4*4;
  f32 acc[4]={bsm[c0],bsm[c0+1],bsm[c0+2],bsm[c0+3]};
  #pragma unroll
  for(int a=0;a<3;a++){
    int ii=ii0+a-1; if(ii<0||ii>63) continue;
    #pragma unroll
    for(int bb=0;bb<3;bb++){
      int jj=j+bb-1; if(jj<0||jj>63) continue;
      float4 v=*(const float4*)&xh_raw[((size_t)(b*4096)+(ii*64+jj))*192 + c0];
      int t=a*3+bb;
      acc[0]+=v.x*wsm[c0][t]; acc[1]+=v.y*wsm[c0+1][t];
      acc[2]+=v.z*wsm[c0+2][t]; acc[3]+=v.w*wsm[c0+3][t];
    }
  }
  float4 o; o.x=siluf(acc[0]); o.y=siluf(acc[1]); o.z=siluf(acc[2]); o.w=siluf(acc[3]);
  ((float4*)xh)[idx]=o;
}

// ---------------- Kernel C (MFMA): x_dbl = xh @ Wx^T -> dt(softplus), B, C -----
__global__ __launch_bounds__(256) void k_xdbl(const f32* __restrict__ xh, const unsigned short* __restrict__ Wfrag,
                                              const f32* __restrict__ dtb, f32* __restrict__ dt_sp,
                                              f32* __restrict__ Bg, f32* __restrict__ Cg){
  __shared__ unsigned short Ald[24*64*8];      // 24 KB
  const int m0=blockIdx.x*64;
  const int tid=threadIdx.x;
  for(int i=tid;i<1536;i+=256){
    int r=i&63, g=i>>6;
    const f32* p=&xh[(size_t)(m0+r)*192 + g*8];
    float4 v0=*(const float4*)p, v1=*(const float4*)(p+4);
    u16x8 w={f2bf(v0.x),f2bf(v0.y),f2bf(v0.z),f2bf(v0.w),
             f2bf(v1.x),f2bf(v1.y),f2bf(v1.z),f2bf(v1.w)};
    *(u16x8*)&Ald[(size_t)(g*64+r)*8]=w;
  }
  __syncthreads();
  const int wv=tid>>6, lane=tid&63, l15=lane&15, l4=lane>>4;
  f32x4 acc[10];
  #pragma unroll
  for(int nt=0;nt<10;nt++){ f32x4 zz={0.f,0.f,0.f,0.f}; acc[nt]=zz; }
  #pragma unroll
  for(int ks=0;ks<6;ks++){
    const int g=ks*4+l4;
    bf16x8 a=*(const bf16x8*)&Ald[(size_t)(g*64 + wv*16 + l15)*8];
    #pragma unroll
    for(int nt=0;nt<10;nt++){
      bf16x8 bfr=*(const bf16x8*)&Wfrag[((size_t)(nt*24+g)*16+l15)*8];
      acc[nt]=__builtin_amdgcn_mfma_f32_16x16x32_bf16(a,bfr,acc[nt],0,0,0);
    }
  }
  const int rowb=m0 + wv*16 + l4*4;
  #pragma unroll
  for(int nt=0;nt<10;nt++){
    int n=nt*16+l15, dir=n/40, cc=n-dir*40;
    if(cc>=38) continue;
    #pragma unroll
    for(int r=0;r<4;r++){
      size_t pix=(size_t)(rowb+r);
      f32 v=acc[nt][r];
      if(cc<6){ f32 xv=v+dtb[dir*6+cc]; dt_sp[pix*24+dir*6+cc]=(xv>20.f)? xv : log1pf(__expf(xv)); }
      else if(cc<22){ Bg[(pix*4+dir)*16+(cc-6)]=v; }
      else          { Cg[(pix*4+dir)*16+(cc-22)]=v; }
    }
  }
}

// ---------------- Kernel D1 (MFMA): S_loc = e63 * (B' @ Bt^T) ------------------
#define LDK1 72
__global__ __launch_bounds__(384) void k_chunk1(const f32* __restrict__ xh, const f32* __restrict__ Bg,
      const f32* __restrict__ dt_sp, const f32* __restrict__ Alogs, f32* __restrict__ S, f32* __restrict__ ach){
  __shared__ unsigned short Bp[192*LDK1];
  __shared__ unsigned short BtT[16*LDK1];
  __shared__ f32 dtl[64][6], w1l[64][6];
  __shared__ f32 e63[6];
  const int c=blockIdx.x, dir=blockIdx.y, b=blockIdx.z, c0=c*64, tid=threadIdx.x;
  { int r=tid/6, q=tid-r*6; size_t pix=(size_t)b*4096+pos_of(dir,c0+r);
    dtl[r][q]=dt_sp[pix*24+dir*6+q]; }
  if(tid<256){
    int r=tid>>2,q=tid&3; size_t pix=(size_t)b*4096+pos_of(dir,c0+r);
    float4 bv=*(const float4*)&Bg[(pix*4+dir)*16+q*4];
    BtT[(4*q+0)*LDK1+r]=f2bf(bv.x); BtT[(4*q+1)*LDK1+r]=f2bf(bv.y);
    BtT[(4*q+2)*LDK1+r]=f2bf(bv.z); BtT[(4*q+3)*LDK1+r]=f2bf(bv.w);
  }
  __syncthreads();
  const int wv=tid>>6, lane=tid&63;
  {
    f32 A=-__expf(Alogs[dir*6+wv]);
    f32 dv=dtl[lane][wv];
    f32 v=wave_iscan(dv*A,lane);
    w1l[lane][wv]=__expf(-v)*dv;
    if(lane==63){
      f32 e=__expf(v);
      e63[wv]=e;
      ach[((size_t)(b*64+c))*24+dir*6+wv]=e;
    }
  }
  __syncthreads();
  for(int u=tid;u<768;u+=384){
    int sg=u/48, q=u-sg*48, head=q>>3;
    f32 vv[4][4];
    #pragma unroll
    for(int j=0;j<4;j++){
      int s=sg*4+j;
      float4 xv=((const float4*)&xh[(size_t)(b*4096+pos_of(dir,c0+s))*192])[q];
      f32 w1=w1l[s][head];
      vv[j][0]=xv.x*w1; vv[j][1]=xv.y*w1; vv[j][2]=xv.z*w1; vv[j][3]=xv.w*w1;
    }
    #pragma unroll
    for(int cc=0;cc<4;cc++){
      u16x4 w={f2bf(vv[0][cc]),f2bf(vv[1][cc]),f2bf(vv[2][cc]),f2bf(vv[3][cc])};
      *(u16x4*)&Bp[(4*q+cc)*LDK1+sg*4]=w;
    }
  }
  __syncthreads();
  const int l15=lane&15, l4=lane>>4;
  f32x4 acc[2];
  { f32x4 zz={0.f,0.f,0.f,0.f}; acc[0]=zz; acc[1]=zz; }
  #pragma unroll
  for(int i=0;i<2;i++){
    int mt=wv+6*i;
    #pragma unroll
    for(int ks=0;ks<2;ks++){
      int kg=ks*4+l4;
      bf16x8 a=*(const bf16x8*)&Bp[(size_t)(mt*16+l15)*LDK1+kg*8];
      bf16x8 bb=*(const bf16x8*)&BtT[(size_t)l15*LDK1+kg*8];
      acc[i]=__builtin_amdgcn_mfma_f32_16x16x32_bf16(a,bb,acc[i],0,0,0);
    }
  }
  const size_t base=(((size_t)(b*64+c))*24+dir*6)*512;
  #pragma unroll
  for(int i=0;i<2;i++){
    int mt=wv+6*i;
    #pragma unroll
    for(int r=0;r<4;r++){
      int ch=mt*16+l4*4+r, head=ch>>5, d=ch&31;
      S[base+(size_t)head*512+d*16+l15]=acc[i][r]*e63[head];
    }
  }
}

// ---------------- Kernel D2: serial inter-chunk scan (in-place S -> prev) ------
__global__ __launch_bounds__(256) void k_scan(f32* __restrict__ S, const f32* __restrict__ ach){
  const int g=blockIdx.x*256+threadIdx.x;
  const int b=g/12288, rem=g%12288, h=rem/512;
  size_t base=(size_t)b*786432 + rem;
  const f32* ap=&ach[(size_t)b*1536 + h];
  f32 st=0.f;
  for(int c=0;c<64;c++){
    f32 a=ap[c*24];
    f32 s=S[base+(size_t)c*12288];
    S[base+(size_t)c*12288]=st;
    st=a*st+s;
  }
}

// ---------------- Kernel D3 (MFMA, merged dirs): both paired dirs per block -----
// grid (64 c, 8 b, 4 = pair*2+half), 384 thr = 6 waves.
// pair 0 = dirs {0,2} (row tiles) -> ym0 ; pair 1 = dirs {1,3} (col tiles) -> ym1.
// dir pair+2 handled in pixel order via suffix scan + upper-triangle mask.
// B' built from global fp32 xh (single bf16 rounding); D*x reconstructed from Blds.
#define LDK 104
__global__ __launch_bounds__(384) void k_chunk2(const f32* __restrict__ xh, const f32* __restrict__ Bg,
      const f32* __restrict__ Cg, const f32* __restrict__ dt_sp, const f32* __restrict__ Sprev,
      const f32* __restrict__ Alogs, const f32* __restrict__ Dsw,
      f32* __restrict__ ym0, f32* __restrict__ ym1){
  __shared__ unsigned short Alds[64*LDK];   // 13.3 KB: [CBtri | Ct | 0]
  __shared__ unsigned short Blds[96*LDK];   // 20.0 KB: [x*w1 ; prevT ; 0]
  __shared__ unsigned short Btf[64*32];     // 4 KB (16 real k + 16 zero)
  __shared__ f32 dtl[64][6], w1l[64][6], erowl[64][6];
  const int c=blockIdx.x, b=blockIdx.y, pair=blockIdx.z>>1, half=blockIdx.z&1;
  const int c0=c*64, tid=threadIdx.x;
  f32* __restrict__ ym = pair? ym1 : ym0;
  const int wv=tid>>6, lane=tid&63, l15=lane&15, l4=lane>>4;
  f32 vsum[4][4];
  #pragma unroll
  for(int mt=0;mt<4;mt++){
    #pragma unroll
    for(int r=0;r<4;r++) vsum[mt][r]=0.f;
  }
  const int lch=wv*16+l15, gch=half*96+lch, ohead=gch>>5;
  #pragma unroll
  for(int d=0;d<2;d++){
    const int dir=pair+d*2;
    const int cd=d? (63-c) : c;
    if(d) __syncthreads();   // previous iteration's LDS reads done
    // stage dt (pixel order)
    { int r=tid/6, q=tid-r*6;
      size_t pix=(size_t)b*4096 + (pair==0 ? (c0+r) : (r*64+c));
      dtl[r][q]=dt_sp[pix*24+dir*6+q]; }
    // stage B->Btf, C->Alds cols 64..95 (pixel order)
    if(tid<256){
      int r=tid>>2,q=tid&3;
      size_t pix=(size_t)b*4096 + (pair==0 ? (c0+r) : (r*64+c));
      float4 bv=*(const float4*)&Bg[(pix*4+dir)*16+q*4];
      float4 cv=*(const float4*)&Cg[(pix*4+dir)*16+q*4];
      u16x4 wb={f2bf(bv.x),f2bf(bv.y),f2bf(bv.z),f2bf(bv.w)};
      u16x4 wc={f2bf(cv.x),f2bf(cv.y),f2bf(cv.z),f2bf(cv.w)};
      u16x4 zz={0,0,0,0};
      *(u16x4*)&Btf[r*32+q*4]=wb;      *(u16x4*)&Btf[r*32+16+q*4]=zz;
      *(u16x4*)&Alds[r*LDK+64+q*4]=wc; *(u16x4*)&Alds[r*LDK+80+q*4]=zz;
    }
    // stage prevT (chunk cd of this dir)
    {
      const size_t pbase=(((size_t)(b*64+cd))*24+dir*6)*512;
      int lr=tid>>2, ng=tid&3, g2=half*96+lr, hh=g2>>5, dd=g2&31;
      float4 pv=*(const float4*)&Sprev[pbase+(size_t)hh*512+dd*16+ng*4];
      u16x4 w={f2bf(pv.x),f2bf(pv.y),f2bf(pv.z),f2bf(pv.w)};
      u16x4 zz={0,0,0,0};
      *(u16x4*)&Blds[lr*LDK+64+ng*4]=w;
      *(u16x4*)&Blds[lr*LDK+80+ng*4]=zz;
    }
    __syncthreads();
    // per-head scan: prefix for dir A (seq order = pixel order), suffix for dir B
    {
      f32 Aa=-__expf(Alogs[dir*6+wv]);
      f32 dv=dtl[lane][wv];
      f32 sc = d? wave_sscan(dv*Aa,lane) : wave_iscan(dv*Aa,lane);
      w1l[lane][wv]=__expf(-sc)*dv;
      erowl[lane][wv]=__expf(sc);
    }
    __syncthreads();
    // CB = Ct@Bt^T via MFMA (A-frag read from Alds cols 64..95), masked write
    #pragma unroll
    for(int tt=0;tt<3;tt++){
      int tile=wv+6*tt;
      if(tile<16){
        int mt=tile>>2, nt=tile&3;
        f32x4 a4={0.f,0.f,0.f,0.f};
        bf16x8 af=*(const bf16x8*)&Alds[(mt*16+l15)*LDK+64+l4*8];
        bf16x8 bfr=*(const bf16x8*)&Btf[(nt*16+l15)*32+l4*8];
        a4=__builtin_amdgcn_mfma_f32_16x16x32_bf16(af,bfr,a4,0,0,0);
        #pragma unroll
        for(int r=0;r<4;r++){
          int t=mt*16+l4*4+r, s=nt*16+l15;
          bool keep = d? (s>=t) : (s<=t);
          Alds[t*LDK+s]= keep? f2bf(a4[r]) : (unsigned short)0;
        }
      }
    }
    // B' = x (global fp32) * w1, transposed write (single bf16 rounding)
    {
      int sg=tid/24, ql=tid-sg*24;
      int head=(half*96+ql*4)>>5;
      f32 vv[4][4];
      #pragma unroll
      for(int j=0;j<4;j++){
        int s=sg*4+j;
        size_t pix=(size_t)b*4096 + (pair==0 ? (c0+s) : (s*64+c));
        float4 xv=*(const float4*)&xh[pix*192 + half*96 + ql*4];
        f32 w1=w1l[s][head];
        vv[j][0]=xv.x*w1; vv[j][1]=xv.y*w1; vv[j][2]=xv.z*w1; vv[j][3]=xv.w*w1;
      }
      #pragma unroll
      for(int cc=0;cc<4;cc++){
        u16x4 w={f2bf(vv[0][cc]),f2bf(vv[1][cc]),f2bf(vv[2][cc]),f2bf(vv[3][cc])};
        *(u16x4*)&Blds[(4*ql+cc)*LDK+sg*4]=w;
      }
    }
    __syncthreads();
    // main MFMA 64x96x96 + epilogue accumulate
    f32x4 acc[4];
    #pragma unroll
    for(int mt=0;mt<4;mt++){ f32x4 zz={0.f,0.f,0.f,0.f}; acc[mt]=zz; }
    #pragma unroll
    for(int ks=0;ks<3;ks++){
      const int kg=ks*4+l4;
      bf16x8 bfr=*(const bf16x8*)&Blds[(wv*16+l15)*LDK+kg*8];
      #pragma unroll
      for(int mt=0;mt<4;mt++){
        bf16x8 af=*(const bf16x8*)&Alds[(mt*16+l15)*LDK+kg*8];
        acc[mt]=__builtin_amdgcn_mfma_f32_16x16x32_bf16(af,bfr,acc[mt],0,0,0);
      }
    }
    const f32 Dv=Dsw[dir*192+gch];
    #pragma unroll
    for(int mt=0;mt<4;mt++){
      #pragma unroll
      for(int r=0;r<4;r++){
        int t=mt*16+l4*4+r;
        f32 er=erowl[t][ohead];
        f32 xv=bfr2f(Blds[lch*LDK+t])*er/dtl[t][ohead];   // = x (w1*er/dt == 1)
        vsum[mt][r]+=acc[mt][r]*er + Dv*xv;
      }
    }
  }
  // single store (no RMW)
  #pragma unroll
  for(int mt=0;mt<4;mt++){
    #pragma unroll
    for(int r=0;r<4;r++){
      int t=mt*16+l4*4+r;
      size_t pix=(size_t)b*4096 + (pair==0 ? (c0+t) : (t*64+c));
      ym[pix*192+gch]=vsum[mt][r];
    }
  }
}

// ---------------- Kernel F (MFMA, fused LN+gate): out = LN(ym0+ym1)*z @ Wo^T ---
__global__ __launch_bounds__(256) void k_outproj(const f32* __restrict__ ym0, const f32* __restrict__ ym1,
                                                 const f32* __restrict__ z,
                                                 const f32* __restrict__ lw, const f32* __restrict__ lb,
                                                 const unsigned short* __restrict__ Wo, f32* __restrict__ out){
  __shared__ unsigned short Ald[24*64*8];      // 24 KB
  __shared__ f32 lws[192], lbs[192];
  const int m0=blockIdx.x*64, tid=threadIdx.x;
  for(int i=tid;i<192;i+=256){ lws[i]=lw[i]; lbs[i]=lb[i]; }
  __syncthreads();
  const int r=tid>>2, sub=tid&3;
  const size_t base=(size_t)(m0+r)*192 + sub*48;
  f32 y[48];
  f32 s=0.f;
  #pragma unroll
  for(int j=0;j<48;j+=4){
    float4 a=*(const float4*)&ym0[base+j];
    float4 bb=*(const float4*)&ym1[base+j];
    y[j]=a.x+bb.x; y[j+1]=a.y+bb.y; y[j+2]=a.z+bb.z; y[j+3]=a.w+bb.w;
    s+=y[j]+y[j+1]+y[j+2]+y[j+3];
  }
  s+=__shfl_xor(s,1,64); s+=__shfl_xor(s,2,64);
  const f32 mu=s*(1.f/192.f);
  f32 q=0.f;
  #pragma unroll
  for(int j=0;j<48;j++){ f32 dd=y[j]-mu; q+=dd*dd; }
  q+=__shfl_xor(q,1,64); q+=__shfl_xor(q,2,64);
  const f32 rs=rsqrtf(q*(1.f/192.f)+1e-5f);
  #pragma unroll
  for(int j=0;j<48;j+=8){
    float4 z0=*(const float4*)&z[base+j];
    float4 z1=*(const float4*)&z[base+j+4];
    int col=sub*48+j;
    u16x8 w;
    w[0]=f2bf(((y[j+0]-mu)*rs*lws[col+0]+lbs[col+0])*z0.x);
    w[1]=f2bf(((y[j+1]-mu)*rs*lws[col+1]+lbs[col+1])*z0.y);
    w[2]=f2bf(((y[j+2]-mu)*rs*lws[col+2]+lbs[col+2])*z0.z);
    w[3]=f2bf(((y[j+3]-mu)*rs*lws[col+3]+lbs[col+3])*z0.w);
    w[4]=f2bf(((y[j+4]-mu)*rs*lws[col+4]+lbs[col+4])*z1.x);
    w[5]=f2bf(((y[j+5]-mu)*rs*lws[col+5]+lbs[col+5])*z1.y);
    w[6]=f2bf(((y[j+6]-mu)*rs*lws[col+6]+lbs[col+6])*z1.z);
    w[7]=f2bf(((y[j+7]-mu)*rs*lws[col+7]+lbs[col+7])*z1.w);
    int g=col>>3;
    *(u16x8*)&Ald[((size_t)g*64+r)*8]=w;
  }
  __syncthreads();
  const int wv=tid>>6, lane=tid&63, l15=lane&15, l4=lane>>4;
  f32x4 acc[6];
  #pragma unroll
  for(int nt=0;nt<6;nt++){ f32x4 zz={0.f,0.f,0.f,0.f}; acc[nt]=zz; }
  #pragma unroll
  for(int ks=0;ks<6;ks++){
    const int g=ks*4+l4;
    bf16x8 a=*(const bf16x8*)&Ald[(size_t)(g*64+wv*16+l15)*8];
    #pragma unroll
    for(int nt=0;nt<6;nt++){
      bf16x8 bfr=*(const bf16x8*)&Wo[((size_t)(nt*24+g)*16+l15)*8];
      acc[nt]=__builtin_amdgcn_mfma_f32_16x16x32_bf16(a,bfr,acc[nt],0,0,0);
    }
  }
  const int rowb=m0+wv*16+l4*4;
  #pragma unroll
  for(int nt=0;nt<6;nt++){
    int col=nt*16+l15;
    #pragma unroll
    for(int r2=0;r2<4;r2++){
      out[(size_t)(rowb+r2)*96+col]=acc[nt][r2];
    }
  }
}

extern "C" void kernel_launch(void* const* d_in, const int* in_sizes, int n_in,
                              void* d_out, int out_size, void* d_ws, size_t ws_size,
                              hipStream_t stream){
  const f32* x  =(const f32*)d_in[0];
  const f32* ipw=(const f32*)d_in[1];
  const f32* cw =(const f32*)d_in[2];
  const f32* cb =(const f32*)d_in[3];
  const f32* xpw=(const f32*)d_in[4];
  const f32* alg=(const f32*)d_in[5];
  const f32* dsw=(const f32*)d_in[6];
  const f32* dtb=(const f32*)d_in[7];
  const f32* lw =(const f32*)d_in[8];
  const f32* lb =(const f32*)d_in[9];
  const f32* opw=(const f32*)d_in[10];
  f32* out=(f32*)d_out;
  f32* ws=(f32*)d_ws;

  f32* xh_raw=ws;               // 6291456 floats (reused as ym0)
  f32* z     =ws+ 6291456;      // 6291456
  f32* xh    =ws+12582912;      // 6291456
  f32* dt_sp =ws+18874368;      //  786432
  f32* Bg    =ws+19660800;      // 2097152
  f32* Cg    =ws+21757952;      // 2097152
  f32* S     =ws+23855104;      // 6291456
  f32* ach   =ws+30146560;      //   12288
  f32* ym1   =ws+30158848;      // 6291456
  unsigned short* Wx=(unsigned short*)(ws+36450304);
  unsigned short* Wi=(unsigned short*)(ws+36465664);
  unsigned short* Wo=(unsigned short*)(ws+36484096);
  f32* ym0=xh_raw;

  k_wcvt_all<<<42,256,0,stream>>>(xpw,ipw,opw,Wx,Wi,Wo);
  k_inproj<<<512,256,0,stream>>>(x,Wi,xh_raw,z);
  k_conv<<<6144,256,0,stream>>>(xh_raw,cw,cb,xh);
  k_xdbl<<<dim3(512),256,0,stream>>>(xh,Wx,dtb,dt_sp,Bg,Cg);
  k_chunk1<<<dim3(64,4,8),384,0,stream>>>(xh,Bg,dt_sp,alg,S,ach);
  k_scan<<<384,256,0,stream>>>(S,ach);
  k_chunk2<<<dim3(64,8,4),384,0,stream>>>(xh,Bg,Cg,dt_sp,S,alg,dsw,ym0,ym1);
  k_outproj<<<512,256,0,stream>>>(ym0,ym1,z,lw,lb,Wo,out);
}

// Round 11
// 189.111 us; speedup vs baseline: 3.0158x; 1.0010x over previous
//
#include <hip/hip_runtime.h>
#include <hip/hip_bf16.h>

using bf16 = __hip_bfloat16;
typedef float f32;
typedef __attribute__((ext_vector_type(8))) short bf16x8;
typedef __attribute__((ext_vector_type(4))) float f32x4;
typedef __attribute__((ext_vector_type(4))) unsigned short u16x4;
typedef __attribute__((ext_vector_type(8))) unsigned short u16x8;

static __device__ __forceinline__ f32 siluf(f32 v){ return v / (1.f + __expf(-v)); }
static __device__ __forceinline__ unsigned short f2bf(f32 v){
  __hip_bfloat16 h=__float2bfloat16(v); return *(unsigned short*)&h;
}
static __device__ __forceinline__ f32 bfr2f(unsigned short u){
  unsigned int x=((unsigned int)u)<<16; return __uint_as_float(x);
}

// spatial position of sequence index p for scan direction dir (H=W=64, L=4096)
static __device__ __forceinline__ int pos_of(int dir, int p){
  if(dir==0) return p;
  if(dir==1) return ((p&63)<<6) | (p>>6);
  if(dir==2) return 4095-p;
  int q = 4095-p; return ((q&63)<<6) | (q>>6);
}

// inclusive wave-64 prefix scan
static __device__ __forceinline__ f32 wave_iscan(f32 v, int lane){
  #pragma unroll
  for(int off=1; off<64; off<<=1){
    f32 u=__shfl_up(v,off,64);
    if(lane>=off) v+=u;
  }
  return v;
}
// inclusive wave-64 suffix scan (v[lane] = sum_{j>=lane})
static __device__ __forceinline__ f32 wave_sscan(f32 v, int lane){
  #pragma unroll
  for(int off=1; off<64; off<<=1){
    f32 u=__shfl_down(v,off,64);
    if(lane<64-off) v+=u;
  }
  return v;
}

// ---------------- Kernel W: weights -> bf16 fragment layout + Dsum -------------
__global__ __launch_bounds__(256) void k_wcvt_all(const f32* __restrict__ xpw, const f32* __restrict__ ipw,
                                                  const f32* __restrict__ opw, const f32* __restrict__ dsw,
                                                  unsigned short* __restrict__ Wx, unsigned short* __restrict__ Wi,
                                                  unsigned short* __restrict__ Wo, f32* __restrict__ Dsum){
  const int t=blockIdx.x*256+threadIdx.x;
  if(t<3840){
    const int g=t%24, n=t/24, nt=n>>4, l=n&15;
    const int dir=n/40, cc=n-dir*40;
    u16x8 w={0,0,0,0,0,0,0,0};
    if(cc<38){
      const f32* p=&xpw[(size_t)dir*7296+cc*192+g*8];
      #pragma unroll
      for(int j=0;j<8;j++) w[j]=f2bf(p[j]);
    }
    *(u16x8*)&Wx[((size_t)(nt*24+g)*16+l)*8]=w;
  } else if(t<8448){
    const int i=t-3840, g=i%12, n=i/12, nt=n>>4, l=n&15;
    const f32* p=&ipw[(size_t)n*96+g*8];
    u16x8 w;
    #pragma unroll
    for(int j=0;j<8;j++) w[j]=f2bf(p[j]);
    *(u16x8*)&Wi[((size_t)(nt*12+g)*16+l)*8]=w;
  } else if(t<10752){
    const int i=t-8448, g=i%24, n=i/24, nt=n>>4, l=n&15;
    const f32* p=&opw[(size_t)n*192+g*8];
    u16x8 w;
    #pragma unroll
    for(int j=0;j<8;j++) w[j]=f2bf(p[j]);
    *(u16x8*)&Wo[((size_t)(nt*24+g)*16+l)*8]=w;
  } else if(t<10944){
    const int ch=t-10752;
    Dsum[ch]=dsw[ch]+dsw[192+ch]+dsw[384+ch]+dsw[576+ch];
  }
}

// ---------------- Kernel A (MFMA): xz = x @ in_proj_w.T ; split, silu ----------
__global__ __launch_bounds__(256) void k_inproj(const f32* __restrict__ x, const unsigned short* __restrict__ Wi,
                                                f32* __restrict__ xh_raw, f32* __restrict__ z){
  __shared__ unsigned short Ald[12*64*8];      // 12 KB
  const int m0=blockIdx.x*64, tid=threadIdx.x;
  for(int i=tid;i<768;i+=256){
    int r=i&63, g=i>>6;
    const f32* p=&x[(size_t)(m0+r)*96+g*8];
    float4 v0=*(const float4*)p, v1=*(const float4*)(p+4);
    u16x8 w={f2bf(v0.x),f2bf(v0.y),f2bf(v0.z),f2bf(v0.w),
             f2bf(v1.x),f2bf(v1.y),f2bf(v1.z),f2bf(v1.w)};
    *(u16x8*)&Ald[(size_t)(g*64+r)*8]=w;
  }
  __syncthreads();
  const int wv=tid>>6, lane=tid&63, l15=lane&15, l4=lane>>4;
  f32x4 acc[24];
  #pragma unroll
  for(int nt=0;nt<24;nt++){ f32x4 zz={0.f,0.f,0.f,0.f}; acc[nt]=zz; }
  #pragma unroll
  for(int ks=0;ks<3;ks++){
    const int g=ks*4+l4;
    bf16x8 a=*(const bf16x8*)&Ald[(size_t)(g*64+wv*16+l15)*8];
    #pragma unroll
    for(int nt=0;nt<24;nt++){
      bf16x8 bfr=*(const bf16x8*)&Wi[((size_t)(nt*12+g)*16+l15)*8];
      acc[nt]=__builtin_amdgcn_mfma_f32_16x16x32_bf16(a,bfr,acc[nt],0,0,0);
    }
  }
  const int rowb=m0+wv*16+l4*4;
  #pragma unroll
  for(int nt=0;nt<24;nt++){
    int col=nt*16+l15;
    #pragma unroll
    for(int r=0;r<4;r++){
      int row=rowb+r; f32 v=acc[nt][r];
      if(col<192) xh_raw[(size_t)row*192+col]=v;
      else        z[(size_t)row*192+(col-192)]=siluf(v);
    }
  }
}

// ---------------- Kernel B: depthwise 3x3 conv + bias + silu --------------------
__global__ __launch_bounds__(256) void k_conv(const f32* __restrict__ xh_raw, const f32* __restrict__ cw,
                                              const f32* __restrict__ cb, f32* __restrict__ xh){
  __shared__ f32 wsm[192][9];
  __shared__ f32 bsm[192];
  const int tid=threadIdx.x;
  for(int i=tid;i<1728;i+=256) wsm[i/9][i%9]=cw[i];
  for(int i=tid;i<192;i+=256) bsm[i]=cb[i];
  __syncthreads();
  const int idx=blockIdx.x*256+tid;
  const int c4=idx%48, j=(idx/48)&63, ii0=(idx/3072)&63, b=idx/196608;
  const int c0=c4*4;
  f32 acc[4]={bsm[c0],bsm[c0+1],bsm[c0+2],bsm[c0+3]};
  #pragma unroll
  for(int a=0;a<3;a++){
    int ii=ii0+a-1; if(ii<0||ii>63) continue;
    #pragma unroll
    for(int bb=0;bb<3;bb++){
      int jj=j+bb-1; if(jj<0||jj>63) continue;
      float4 v=*(const float4*)&xh_raw[((size_t)(b*4096)+(ii*64+jj))*192 + c0];
      int t=a*3+bb;
      acc[0]+=v.x*wsm[c0][t]; acc[1]+=v.y*wsm[c0+1][t];
      acc[2]+=v.z*wsm[c0+2][t]; acc[3]+=v.w*wsm[c0+3][t];
    }
  }
  float4 o; o.x=siluf(acc[0]); o.y=siluf(acc[1]); o.z=siluf(acc[2]); o.w=siluf(acc[3]);
  ((float4*)xh)[idx]=o;
}

// ---------------- Kernel C (MFMA): x_dbl = xh @ Wx^T -> dt(softplus), B, C -----
__global__ __launch_bounds__(256) void k_xdbl(const f32* __restrict__ xh, const unsigned short* __restrict__ Wfrag,
                                              const f32* __restrict__ dtb, f32* __restrict__ dt_sp,
                                              f32* __restrict__ Bg, f32* __restrict__ Cg){
  __shared__ unsigned short Ald[24*64*8];      // 24 KB
  const int m0=blockIdx.x*64;
  const int tid=threadIdx.x;
  for(int i=tid;i<1536;i+=256){
    int r=i&63, g=i>>6;
    const f32* p=&xh[(size_t)(m0+r)*192 + g*8];
    float4 v0=*(const float4*)p, v1=*(const float4*)(p+4);
    u16x8 w={f2bf(v0.x),f2bf(v0.y),f2bf(v0.z),f2bf(v0.w),
             f2bf(v1.x),f2bf(v1.y),f2bf(v1.z),f2bf(v1.w)};
    *(u16x8*)&Ald[(size_t)(g*64+r)*8]=w;
  }
  __syncthreads();
  const int wv=tid>>6, lane=tid&63, l15=lane&15, l4=lane>>4;
  f32x4 acc[10];
  #pragma unroll
  for(int nt=0;nt<10;nt++){ f32x4 zz={0.f,0.f,0.f,0.f}; acc[nt]=zz; }
  #pragma unroll
  for(int ks=0;ks<6;ks++){
    const int g=ks*4+l4;
    bf16x8 a=*(const bf16x8*)&Ald[(size_t)(g*64 + wv*16 + l15)*8];
    #pragma unroll
    for(int nt=0;nt<10;nt++){
      bf16x8 bfr=*(const bf16x8*)&Wfrag[((size_t)(nt*24+g)*16+l15)*8];
      acc[nt]=__builtin_amdgcn_mfma_f32_16x16x32_bf16(a,bfr,acc[nt],0,0,0);
    }
  }
  const int rowb=m0 + wv*16 + l4*4;
  #pragma unroll
  for(int nt=0;nt<10;nt++){
    int n=nt*16+l15, dir=n/40, cc=n-dir*40;
    if(cc>=38) continue;
    #pragma unroll
    for(int r=0;r<4;r++){
      size_t pix=(size_t)(rowb+r);
      f32 v=acc[nt][r];
      if(cc<6){ f32 xv=v+dtb[dir*6+cc]; dt_sp[pix*24+dir*6+cc]=(xv>20.f)? xv : log1pf(__expf(xv)); }
      else if(cc<22){ Bg[(pix*4+dir)*16+(cc-6)]=v; }
      else          { Cg[(pix*4+dir)*16+(cc-22)]=v; }
    }
  }
}

// ---------------- Kernel D1 (MFMA): S_loc = e63 * (B' @ Bt^T) ------------------
#define LDK1 72
__global__ __launch_bounds__(384) void k_chunk1(const f32* __restrict__ xh, const f32* __restrict__ Bg,
      const f32* __restrict__ dt_sp, const f32* __restrict__ Alogs, f32* __restrict__ S, f32* __restrict__ ach){
  __shared__ unsigned short Bp[192*LDK1];
  __shared__ unsigned short BtT[16*LDK1];
  __shared__ f32 dtl[64][6], w1l[64][6];
  __shared__ f32 e63[6];
  const int c=blockIdx.x, dir=blockIdx.y, b=blockIdx.z, c0=c*64, tid=threadIdx.x;
  { int r=tid/6, q=tid-r*6; size_t pix=(size_t)b*4096+pos_of(dir,c0+r);
    dtl[r][q]=dt_sp[pix*24+dir*6+q]; }
  if(tid<256){
    int r=tid>>2,q=tid&3; size_t pix=(size_t)b*4096+pos_of(dir,c0+r);
    float4 bv=*(const float4*)&Bg[(pix*4+dir)*16+q*4];
    BtT[(4*q+0)*LDK1+r]=f2bf(bv.x); BtT[(4*q+1)*LDK1+r]=f2bf(bv.y);
    BtT[(4*q+2)*LDK1+r]=f2bf(bv.z); BtT[(4*q+3)*LDK1+r]=f2bf(bv.w);
  }
  __syncthreads();
  const int wv=tid>>6, lane=tid&63;
  {
    f32 A=-__expf(Alogs[dir*6+wv]);
    f32 dv=dtl[lane][wv];
    f32 v=wave_iscan(dv*A,lane);
    w1l[lane][wv]=__expf(-v)*dv;
    if(lane==63){
      f32 e=__expf(v);
      e63[wv]=e;
      ach[((size_t)(b*64+c))*24+dir*6+wv]=e;
    }
  }
  __syncthreads();
  for(int u=tid;u<768;u+=384){
    int sg=u/48, q=u-sg*48, head=q>>3;
    f32 vv[4][4];
    #pragma unroll
    for(int j=0;j<4;j++){
      int s=sg*4+j;
      float4 xv=((const float4*)&xh[(size_t)(b*4096+pos_of(dir,c0+s))*192])[q];
      f32 w1=w1l[s][head];
      vv[j][0]=xv.x*w1; vv[j][1]=xv.y*w1; vv[j][2]=xv.z*w1; vv[j][3]=xv.w*w1;
    }
    #pragma unroll
    for(int cc=0;cc<4;cc++){
      u16x4 w={f2bf(vv[0][cc]),f2bf(vv[1][cc]),f2bf(vv[2][cc]),f2bf(vv[3][cc])};
      *(u16x4*)&Bp[(4*q+cc)*LDK1+sg*4]=w;
    }
  }
  __syncthreads();
  const int l15=lane&15, l4=lane>>4;
  f32x4 acc[2];
  { f32x4 zz={0.f,0.f,0.f,0.f}; acc[0]=zz; acc[1]=zz; }
  #pragma unroll
  for(int i=0;i<2;i++){
    int mt=wv+6*i;
    #pragma unroll
    for(int ks=0;ks<2;ks++){
      int kg=ks*4+l4;
      bf16x8 a=*(const bf16x8*)&Bp[(size_t)(mt*16+l15)*LDK1+kg*8];
      bf16x8 bb=*(const bf16x8*)&BtT[(size_t)l15*LDK1+kg*8];
      acc[i]=__builtin_amdgcn_mfma_f32_16x16x32_bf16(a,bb,acc[i],0,0,0);
    }
  }
  const size_t base=(((size_t)(b*64+c))*24+dir*6)*512;
  #pragma unroll
  for(int i=0;i<2;i++){
    int mt=wv+6*i;
    #pragma unroll
    for(int r=0;r<4;r++){
      int ch=mt*16+l4*4+r, head=ch>>5, d=ch&31;
      S[base+(size_t)head*512+d*16+l15]=acc[i][r]*e63[head];
    }
  }
}

// ---------------- Kernel D2: serial inter-chunk scan (in-place S -> prev) ------
__global__ __launch_bounds__(256) void k_scan(f32* __restrict__ S, const f32* __restrict__ ach){
  const int g=blockIdx.x*256+threadIdx.x;
  const int b=g/12288, rem=g%12288, h=rem/512;
  size_t base=(size_t)b*786432 + rem;
  const f32* ap=&ach[(size_t)b*1536 + h];
  f32 st=0.f;
  for(int c=0;c<64;c++){
    f32 a=ap[c*24];
    f32 s=S[base+(size_t)c*12288];
    S[base+(size_t)c*12288]=st;
    st=a*st+s;
  }
}

// ---------------- Kernel D3 (MFMA, merged dirs): both paired dirs per block -----
// grid (64 c, 8 b, 4 = pair*2+half), 384 thr = 6 waves. D*x handled in outproj.
#define LDK 104
__global__ __launch_bounds__(384) void k_chunk2(const f32* __restrict__ xh, const f32* __restrict__ Bg,
      const f32* __restrict__ Cg, const f32* __restrict__ dt_sp, const f32* __restrict__ Sprev,
      const f32* __restrict__ Alogs,
      f32* __restrict__ ym0, f32* __restrict__ ym1){
  __shared__ unsigned short Alds[64*LDK];   // 13.3 KB: [CBtri | Ct | 0]
  __shared__ unsigned short Blds[96*LDK];   // 20.0 KB: [x*w1 ; prevT ; 0]
  __shared__ unsigned short Btf[64*32];     // 4 KB
  __shared__ f32 w1l[64][6], erowl[64][6];  // 3 KB   (total 40448 B -> 4 blk/CU)
  const int c=blockIdx.x, b=blockIdx.y, pair=blockIdx.z>>1, half=blockIdx.z&1;
  const int c0=c*64, tid=threadIdx.x;
  f32* __restrict__ ym = pair? ym1 : ym0;
  const int wv=tid>>6, lane=tid&63, l15=lane&15, l4=lane>>4;
  f32 vsum[4][4];
  #pragma unroll
  for(int mt=0;mt<4;mt++){
    #pragma unroll
    for(int r=0;r<4;r++) vsum[mt][r]=0.f;
  }
  const int gch=half*96+wv*16+l15, ohead=gch>>5;
  #pragma unroll
  for(int d=0;d<2;d++){
    const int dir=pair+d*2;
    const int cd=d? (63-c) : c;
    if(d) __syncthreads();   // previous iteration's LDS reads done
    // phase 1 (parallel): stage Btf/C/prevT  +  per-head scan from global dt
    if(tid<256){
      int r=tid>>2,q=tid&3;
      size_t pix=(size_t)b*4096 + (pair==0 ? (c0+r) : (r*64+c));
      float4 bv=*(const float4*)&Bg[(pix*4+dir)*16+q*4];
      float4 cv=*(const float4*)&Cg[(pix*4+dir)*16+q*4];
      u16x4 wb={f2bf(bv.x),f2bf(bv.y),f2bf(bv.z),f2bf(bv.w)};
      u16x4 wc={f2bf(cv.x),f2bf(cv.y),f2bf(cv.z),f2bf(cv.w)};
      u16x4 zz={0,0,0,0};
      *(u16x4*)&Btf[r*32+q*4]=wb;      *(u16x4*)&Btf[r*32+16+q*4]=zz;
      *(u16x4*)&Alds[r*LDK+64+q*4]=wc; *(u16x4*)&Alds[r*LDK+80+q*4]=zz;
    }
    {
      const size_t pbase=(((size_t)(b*64+cd))*24+dir*6)*512;
      int lr=tid>>2, ng=tid&3, g2=half*96+lr, hh=g2>>5, dd=g2&31;
      float4 pv=*(const float4*)&Sprev[pbase+(size_t)hh*512+dd*16+ng*4];
      u16x4 w={f2bf(pv.x),f2bf(pv.y),f2bf(pv.z),f2bf(pv.w)};
      u16x4 zz={0,0,0,0};
      *(u16x4*)&Blds[lr*LDK+64+ng*4]=w;
      *(u16x4*)&Blds[lr*LDK+80+ng*4]=zz;
    }
    {
      f32 Aa=-__expf(Alogs[dir*6+wv]);
      size_t pixL=(size_t)b*4096 + (pair==0 ? (c0+lane) : (lane*64+c));
      f32 dv=dt_sp[pixL*24+dir*6+wv];
      f32 sc = d? wave_sscan(dv*Aa,lane) : wave_iscan(dv*Aa,lane);
      w1l[lane][wv]=__expf(-sc)*dv;
      erowl[lane][wv]=__expf(sc);
    }
    __syncthreads();
    // phase 2 (parallel): CB = Ct@Bt^T via MFMA (masked)  +  B' = x*w1
    #pragma unroll
    for(int tt=0;tt<3;tt++){
      int tile=wv+6*tt;
      if(tile<16){
        int mt=tile>>2, nt=tile&3;
        f32x4 a4={0.f,0.f,0.f,0.f};
        bf16x8 af=*(const bf16x8*)&Alds[(mt*16+l15)*LDK+64+l4*8];
        bf16x8 bfr=*(const bf16x8*)&Btf[(nt*16+l15)*32+l4*8];
        a4=__builtin_amdgcn_mfma_f32_16x16x32_bf16(af,bfr,a4,0,0,0);
        #pragma unroll
        for(int r=0;r<4;r++){
          int t=mt*16+l4*4+r, s=nt*16+l15;
          bool keep = d? (s>=t) : (s<=t);
          Alds[t*LDK+s]= keep? f2bf(a4[r]) : (unsigned short)0;
        }
      }
    }
    {
      int sg=tid/24, ql=tid-sg*24;
      int head=(half*96+ql*4)>>5;
      f32 vv[4][4];
      #pragma unroll
      for(int j=0;j<4;j++){
        int s=sg*4+j;
        size_t pix=(size_t)b*4096 + (pair==0 ? (c0+s) : (s*64+c));
        float4 xv=*(const float4*)&xh[pix*192 + half*96 + ql*4];
        f32 w1=w1l[s][head];
        vv[j][0]=xv.x*w1; vv[j][1]=xv.y*w1; vv[j][2]=xv.z*w1; vv[j][3]=xv.w*w1;
      }
      #pragma unroll
      for(int cc=0;cc<4;cc++){
        u16x4 w={f2bf(vv[0][cc]),f2bf(vv[1][cc]),f2bf(vv[2][cc]),f2bf(vv[3][cc])};
        *(u16x4*)&Blds[(4*ql+cc)*LDK+sg*4]=w;
      }
    }
    __syncthreads();
    // phase 3: main MFMA 64x96x96 + row-scale accumulate
    f32x4 acc[4];
    #pragma unroll
    for(int mt=0;mt<4;mt++){ f32x4 zz={0.f,0.f,0.f,0.f}; acc[mt]=zz; }
    #pragma unroll
    for(int ks=0;ks<3;ks++){
      const int kg=ks*4+l4;
      bf16x8 bfr=*(const bf16x8*)&Blds[(wv*16+l15)*LDK+kg*8];
      #pragma unroll
      for(int mt=0;mt<4;mt++){
        bf16x8 af=*(const bf16x8*)&Alds[(mt*16+l15)*LDK+kg*8];
        acc[mt]=__builtin_amdgcn_mfma_f32_16x16x32_bf16(af,bfr,acc[mt],0,0,0);
      }
    }
    #pragma unroll
    for(int mt=0;mt<4;mt++){
      #pragma unroll
      for(int r=0;r<4;r++){
        int t=mt*16+l4*4+r;
        vsum[mt][r]+=acc[mt][r]*erowl[t][ohead];
      }
    }
  }
  // single store (no RMW)
  #pragma unroll
  for(int mt=0;mt<4;mt++){
    #pragma unroll
    for(int r=0;r<4;r++){
      int t=mt*16+l4*4+r;
      size_t pix=(size_t)b*4096 + (pair==0 ? (c0+t) : (t*64+c));
      ym[pix*192+gch]=vsum[mt][r];
    }
  }
}

// ---------------- Kernel F (MFMA): out = LN(ym0+ym1+x*Dsum)*z @ Wo^T -----------
__global__ __launch_bounds__(256) void k_outproj(const f32* __restrict__ ym0, const f32* __restrict__ ym1,
                                                 const f32* __restrict__ xh, const f32* __restrict__ Dsum,
                                                 const f32* __restrict__ z,
                                                 const f32* __restrict__ lw, const f32* __restrict__ lb,
                                                 const unsigned short* __restrict__ Wo, f32* __restrict__ out){
  __shared__ unsigned short Ald[24*64*8];      // 24 KB
  __shared__ f32 lws[192], lbs[192], dss[192];
  const int m0=blockIdx.x*64, tid=threadIdx.x;
  for(int i=tid;i<192;i+=256){ lws[i]=lw[i]; lbs[i]=lb[i]; dss[i]=Dsum[i]; }
  __syncthreads();
  const int r=tid>>2, sub=tid&3;
  const size_t base=(size_t)(m0+r)*192 + sub*48;
  f32 y[48];
  f32 s=0.f;
  #pragma unroll
  for(int j=0;j<48;j+=4){
    float4 a=*(const float4*)&ym0[base+j];
    float4 bb=*(const float4*)&ym1[base+j];
    float4 xv=*(const float4*)&xh[base+j];
    int col=sub*48+j;
    y[j]  =a.x+bb.x+xv.x*dss[col];
    y[j+1]=a.y+bb.y+xv.y*dss[col+1];
    y[j+2]=a.z+bb.z+xv.z*dss[col+2];
    y[j+3]=a.w+bb.w+xv.w*dss[col+3];
    s+=y[j]+y[j+1]+y[j+2]+y[j+3];
  }
  s+=__shfl_xor(s,1,64); s+=__shfl_xor(s,2,64);
  const f32 mu=s*(1.f/192.f);
  f32 q=0.f;
  #pragma unroll
  for(int j=0;j<48;j++){ f32 dd=y[j]-mu; q+=dd*dd; }
  q+=__shfl_xor(q,1,64); q+=__shfl_xor(q,2,64);
  const f32 rs=rsqrtf(q*(1.f/192.f)+1e-5f);
  #pragma unroll
  for(int j=0;j<48;j+=8){
    float4 z0=*(const float4*)&z[base+j];
    float4 z1=*(const float4*)&z[base+j+4];
    int col=sub*48+j;
    u16x8 w;
    w[0]=f2bf(((y[j+0]-mu)*rs*lws[col+0]+lbs[col+0])*z0.x);
    w[1]=f2bf(((y[j+1]-mu)*rs*lws[col+1]+lbs[col+1])*z0.y);
    w[2]=f2bf(((y[j+2]-mu)*rs*lws[col+2]+lbs[col+2])*z0.z);
    w[3]=f2bf(((y[j+3]-mu)*rs*lws[col+3]+lbs[col+3])*z0.w);
    w[4]=f2bf(((y[j+4]-mu)*rs*lws[col+4]+lbs[col+4])*z1.x);
    w[5]=f2bf(((y[j+5]-mu)*rs*lws[col+5]+lbs[col+5])*z1.y);
    w[6]=f2bf(((y[j+6]-mu)*rs*lws[col+6]+lbs[col+6])*z1.z);
    w[7]=f2bf(((y[j+7]-mu)*rs*lws[col+7]+lbs[col+7])*z1.w);
    int g=col>>3;
    *(u16x8*)&Ald[((size_t)g*64+r)*8]=w;
  }
  __syncthreads();
  const int wv=tid>>6, lane=tid&63, l15=lane&15, l4=lane>>4;
  f32x4 acc[6];
  #pragma unroll
  for(int nt=0;nt<6;nt++){ f32x4 zz={0.f,0.f,0.f,0.f}; acc[nt]=zz; }
  #pragma unroll
  for(int ks=0;ks<6;ks++){
    const int g=ks*4+l4;
    bf16x8 a=*(const bf16x8*)&Ald[(size_t)(g*64+wv*16+l15)*8];
    #pragma unroll
    for(int nt=0;nt<6;nt++){
      bf16x8 bfr=*(const bf16x8*)&Wo[((size_t)(nt*24+g)*16+l15)*8];
      acc[nt]=__builtin_amdgcn_mfma_f32_16x16x32_bf16(a,bfr,acc[nt],0,0,0);
    }
  }
  const int rowb=m0+wv*16+l4*4;
  #pragma unroll
  for(int nt=0;nt<6;nt++){
    int col=nt*16+l15;
    #pragma unroll
    for(int r2=0;r2<4;r2++){
      out[(size_t)(rowb+r2)*96+col]=acc[nt][r2];
    }
  }
}

extern "C" void kernel_launch(void* const* d_in, const int* in_sizes, int n_in,
                              void* d_out, int out_size, void* d_ws, size_t ws_size,
                              hipStream_t stream){
  const f32* x  =(const f32*)d_in[0];
  const f32* ipw=(const f32*)d_in[1];
  const f32* cw =(const f32*)d_in[2];
  const f32* cb =(const f32*)d_in[3];
  const f32* xpw=(const f32*)d_in[4];
  const f32* alg=(const f32*)d_in[5];
  const f32* dsw=(const f32*)d_in[6];
  const f32* dtb=(const f32*)d_in[7];
  const f32* lw =(const f32*)d_in[8];
  const f32* lb =(const f32*)d_in[9];
  const f32* opw=(const f32*)d_in[10];
  f32* out=(f32*)d_out;
  f32* ws=(f32*)d_ws;

  f32* xh_raw=ws;               // 6291456 floats (reused as ym0)
  f32* z     =ws+ 6291456;      // 6291456
  f32* xh    =ws+12582912;      // 6291456
  f32* dt_sp =ws+18874368;      //  786432
  f32* Bg    =ws+19660800;      // 2097152
  f32* Cg    =ws+21757952;      // 2097152
  f32* S     =ws+23855104;      // 6291456
  f32* ach   =ws+30146560;      //   12288
  f32* ym1   =ws+30158848;      // 6291456
  unsigned short* Wx=(unsigned short*)(ws+36450304);
  unsigned short* Wi=(unsigned short*)(ws+36465664);
  unsigned short* Wo=(unsigned short*)(ws+36484096);
  f32* Dsum  =ws+36493312;      //     192
  f32* ym0=xh_raw;

  k_wcvt_all<<<43,256,0,stream>>>(xpw,ipw,opw,dsw,Wx,Wi,Wo,Dsum);
  k_inproj<<<512,256,0,stream>>>(x,Wi,xh_raw,z);
  k_conv<<<6144,256,0,stream>>>(xh_raw,cw,cb,xh);
  k_xdbl<<<dim3(512),256,0,stream>>>(xh,Wx,dtb,dt_sp,Bg,Cg);
  k_chunk1<<<dim3(64,4,8),384,0,stream>>>(xh,Bg,dt_sp,alg,S,ach);
  k_scan<<<384,256,0,stream>>>(S,ach);
  k_chunk2<<<dim3(64,8,4),384,0,stream>>>(xh,Bg,Cg,dt_sp,S,alg,ym0,ym1);
  k_outproj<<<512,256,0,stream>>>(ym0,ym1,xh,Dsum,z,lw,lb,Wo,out);
}

// Round 12
// 188.036 us; speedup vs baseline: 3.0331x; 1.0057x over previous
//
#include <hip/hip_runtime.h>
#include <hip/hip_bf16.h>

using bf16 = __hip_bfloat16;
typedef float f32;
typedef __attribute__((ext_vector_type(8))) short bf16x8;
typedef __attribute__((ext_vector_type(4))) float f32x4;
typedef __attribute__((ext_vector_type(4))) unsigned short u16x4;
typedef __attribute__((ext_vector_type(8))) unsigned short u16x8;

static __device__ __forceinline__ f32 siluf(f32 v){ return v / (1.f + __expf(-v)); }
static __device__ __forceinline__ unsigned short f2bf(f32 v){
  __hip_bfloat16 h=__float2bfloat16(v); return *(unsigned short*)&h;
}
static __device__ __forceinline__ f32 bfr2f(unsigned short u){
  unsigned int x=((unsigned int)u)<<16; return __uint_as_float(x);
}

// spatial position of sequence index p for scan direction dir (H=W=64, L=4096)
static __device__ __forceinline__ int pos_of(int dir, int p){
  if(dir==0) return p;
  if(dir==1) return ((p&63)<<6) | (p>>6);
  if(dir==2) return 4095-p;
  int q = 4095-p; return ((q&63)<<6) | (q>>6);
}

// inclusive wave-64 prefix scan
static __device__ __forceinline__ f32 wave_iscan(f32 v, int lane){
  #pragma unroll
  for(int off=1; off<64; off<<=1){
    f32 u=__shfl_up(v,off,64);
    if(lane>=off) v+=u;
  }
  return v;
}
// inclusive wave-64 suffix scan (v[lane] = sum_{j>=lane})
static __device__ __forceinline__ f32 wave_sscan(f32 v, int lane){
  #pragma unroll
  for(int off=1; off<64; off<<=1){
    f32 u=__shfl_down(v,off,64);
    if(lane<64-off) v+=u;
  }
  return v;
}

// ---------------- Kernel W: weights -> bf16 fragment layout + Dsum -------------
__global__ __launch_bounds__(256) void k_wcvt_all(const f32* __restrict__ xpw, const f32* __restrict__ ipw,
                                                  const f32* __restrict__ opw, const f32* __restrict__ dsw,
                                                  unsigned short* __restrict__ Wx, unsigned short* __restrict__ Wi,
                                                  unsigned short* __restrict__ Wo, f32* __restrict__ Dsum){
  const int t=blockIdx.x*256+threadIdx.x;
  if(t<3840){
    const int g=t%24, n=t/24, nt=n>>4, l=n&15;
    const int dir=n/40, cc=n-dir*40;
    u16x8 w={0,0,0,0,0,0,0,0};
    if(cc<38){
      const f32* p=&xpw[(size_t)dir*7296+cc*192+g*8];
      #pragma unroll
      for(int j=0;j<8;j++) w[j]=f2bf(p[j]);
    }
    *(u16x8*)&Wx[((size_t)(nt*24+g)*16+l)*8]=w;
  } else if(t<8448){
    const int i=t-3840, g=i%12, n=i/12, nt=n>>4, l=n&15;
    const f32* p=&ipw[(size_t)n*96+g*8];
    u16x8 w;
    #pragma unroll
    for(int j=0;j<8;j++) w[j]=f2bf(p[j]);
    *(u16x8*)&Wi[((size_t)(nt*12+g)*16+l)*8]=w;
  } else if(t<10752){
    const int i=t-8448, g=i%24, n=i/24, nt=n>>4, l=n&15;
    const f32* p=&opw[(size_t)n*192+g*8];
    u16x8 w;
    #pragma unroll
    for(int j=0;j<8;j++) w[j]=f2bf(p[j]);
    *(u16x8*)&Wo[((size_t)(nt*24+g)*16+l)*8]=w;
  } else if(t<10944){
    const int ch=t-10752;
    Dsum[ch]=dsw[ch]+dsw[192+ch]+dsw[384+ch]+dsw[576+ch];
  }
}

// ---------------- Kernel A (MFMA): xz = x @ in_proj_w.T ; split, silu ----------
__global__ __launch_bounds__(256) void k_inproj(const f32* __restrict__ x, const unsigned short* __restrict__ Wi,
                                                f32* __restrict__ xh_raw, f32* __restrict__ z){
  __shared__ unsigned short Ald[12*64*8];      // 12 KB
  const int m0=blockIdx.x*64, tid=threadIdx.x;
  for(int i=tid;i<768;i+=256){
    int r=i&63, g=i>>6;
    const f32* p=&x[(size_t)(m0+r)*96+g*8];
    float4 v0=*(const float4*)p, v1=*(const float4*)(p+4);
    u16x8 w={f2bf(v0.x),f2bf(v0.y),f2bf(v0.z),f2bf(v0.w),
             f2bf(v1.x),f2bf(v1.y),f2bf(v1.z),f2bf(v1.w)};
    *(u16x8*)&Ald[(size_t)(g*64+r)*8]=w;
  }
  __syncthreads();
  const int wv=tid>>6, lane=tid&63, l15=lane&15, l4=lane>>4;
  f32x4 acc[24];
  #pragma unroll
  for(int nt=0;nt<24;nt++){ f32x4 zz={0.f,0.f,0.f,0.f}; acc[nt]=zz; }
  #pragma unroll
  for(int ks=0;ks<3;ks++){
    const int g=ks*4+l4;
    bf16x8 a=*(const bf16x8*)&Ald[(size_t)(g*64+wv*16+l15)*8];
    #pragma unroll
    for(int nt=0;nt<24;nt++){
      bf16x8 bfr=*(const bf16x8*)&Wi[((size_t)(nt*12+g)*16+l15)*8];
      acc[nt]=__builtin_amdgcn_mfma_f32_16x16x32_bf16(a,bfr,acc[nt],0,0,0);
    }
  }
  const int rowb=m0+wv*16+l4*4;
  #pragma unroll
  for(int nt=0;nt<24;nt++){
    int col=nt*16+l15;
    #pragma unroll
    for(int r=0;r<4;r++){
      int row=rowb+r; f32 v=acc[nt][r];
      if(col<192) xh_raw[(size_t)row*192+col]=v;
      else        z[(size_t)row*192+(col-192)]=siluf(v);
    }
  }
}

// ---------------- Kernel C (MFMA, fused conv): conv3x3+silu -> xh, then x_dbl ---
// block = one image row (b, irow): 64 pixels. conv halo read from global (L2).
__global__ __launch_bounds__(256) void k_xdblconv(const f32* __restrict__ xh_raw, const f32* __restrict__ cw,
                                              const f32* __restrict__ cb, const unsigned short* __restrict__ Wfrag,
                                              const f32* __restrict__ dtb, f32* __restrict__ xh,
                                              f32* __restrict__ dt_sp, f32* __restrict__ Bg, f32* __restrict__ Cg){
  __shared__ unsigned short Ald[24*64*8];      // 24 KB
  __shared__ f32 wsm[9][200];                  // wsm[tap][ch], padded
  __shared__ f32 bsm[192];
  const int blk=blockIdx.x, m0=blk*64, tid=threadIdx.x;
  const int b=blk>>6, irow=blk&63;
  for(int i=tid;i<1728;i+=256){ int ch=i/9, t=i-ch*9; wsm[t][ch]=cw[i]; }
  for(int i=tid;i<192;i+=256) bsm[i]=cb[i];
  __syncthreads();
  for(int i=tid;i<1536;i+=256){
    int r=i&63, g=i>>6;                        // pixel col j=r, channel granule g
    f32 acc[8];
    #pragma unroll
    for(int k=0;k<8;k++) acc[k]=bsm[g*8+k];
    #pragma unroll
    for(int a=0;a<3;a++){
      int ii=irow+a-1; if(ii<0||ii>63) continue;
      #pragma unroll
      for(int bb=0;bb<3;bb++){
        int jj=r+bb-1; if(jj<0||jj>63) continue;
        const f32* p=&xh_raw[((size_t)(b*4096)+(ii*64+jj))*192+g*8];
        float4 v0=*(const float4*)p, v1=*(const float4*)(p+4);
        int t=a*3+bb;
        acc[0]+=v0.x*wsm[t][g*8+0]; acc[1]+=v0.y*wsm[t][g*8+1];
        acc[2]+=v0.z*wsm[t][g*8+2]; acc[3]+=v0.w*wsm[t][g*8+3];
        acc[4]+=v1.x*wsm[t][g*8+4]; acc[5]+=v1.y*wsm[t][g*8+5];
        acc[6]+=v1.z*wsm[t][g*8+6]; acc[7]+=v1.w*wsm[t][g*8+7];
      }
    }
    f32 o[8];
    u16x8 w;
    #pragma unroll
    for(int k=0;k<8;k++){ o[k]=siluf(acc[k]); w[k]=f2bf(o[k]); }
    f32* op=&xh[(size_t)(m0+r)*192+g*8];
    float4 o0={o[0],o[1],o[2],o[3]}, o1={o[4],o[5],o[6],o[7]};
    *(float4*)op=o0; *(float4*)(op+4)=o1;
    *(u16x8*)&Ald[(size_t)(g*64+r)*8]=w;
  }
  __syncthreads();
  const int wv=tid>>6, lane=tid&63, l15=lane&15, l4=lane>>4;
  f32x4 acc[10];
  #pragma unroll
  for(int nt=0;nt<10;nt++){ f32x4 zz={0.f,0.f,0.f,0.f}; acc[nt]=zz; }
  #pragma unroll
  for(int ks=0;ks<6;ks++){
    const int g=ks*4+l4;
    bf16x8 a=*(const bf16x8*)&Ald[(size_t)(g*64 + wv*16 + l15)*8];
    #pragma unroll
    for(int nt=0;nt<10;nt++){
      bf16x8 bfr=*(const bf16x8*)&Wfrag[((size_t)(nt*24+g)*16+l15)*8];
      acc[nt]=__builtin_amdgcn_mfma_f32_16x16x32_bf16(a,bfr,acc[nt],0,0,0);
    }
  }
  const int rowb=m0 + wv*16 + l4*4;
  #pragma unroll
  for(int nt=0;nt<10;nt++){
    int n=nt*16+l15, dir=n/40, cc=n-dir*40;
    if(cc>=38) continue;
    #pragma unroll
    for(int r=0;r<4;r++){
      size_t pix=(size_t)(rowb+r);
      f32 v=acc[nt][r];
      if(cc<6){ f32 xv=v+dtb[dir*6+cc]; dt_sp[pix*24+dir*6+cc]=(xv>20.f)? xv : log1pf(__expf(xv)); }
      else if(cc<22){ Bg[(pix*4+dir)*16+(cc-6)]=v; }
      else          { Cg[(pix*4+dir)*16+(cc-22)]=v; }
    }
  }
}

// ---------------- Kernel D1 (MFMA): S_loc = e63 * (B' @ Bt^T) ------------------
#define LDK1 72
__global__ __launch_bounds__(384) void k_chunk1(const f32* __restrict__ xh, const f32* __restrict__ Bg,
      const f32* __restrict__ dt_sp, const f32* __restrict__ Alogs, f32* __restrict__ S, f32* __restrict__ ach){
  __shared__ unsigned short Bp[192*LDK1];
  __shared__ unsigned short BtT[16*LDK1];
  __shared__ f32 dtl[64][6], w1l[64][6];
  __shared__ f32 e63[6];
  const int c=blockIdx.x, dir=blockIdx.y, b=blockIdx.z, c0=c*64, tid=threadIdx.x;
  { int r=tid/6, q=tid-r*6; size_t pix=(size_t)b*4096+pos_of(dir,c0+r);
    dtl[r][q]=dt_sp[pix*24+dir*6+q]; }
  if(tid<256){
    int r=tid>>2,q=tid&3; size_t pix=(size_t)b*4096+pos_of(dir,c0+r);
    float4 bv=*(const float4*)&Bg[(pix*4+dir)*16+q*4];
    BtT[(4*q+0)*LDK1+r]=f2bf(bv.x); BtT[(4*q+1)*LDK1+r]=f2bf(bv.y);
    BtT[(4*q+2)*LDK1+r]=f2bf(bv.z); BtT[(4*q+3)*LDK1+r]=f2bf(bv.w);
  }
  __syncthreads();
  const int wv=tid>>6, lane=tid&63;
  {
    f32 A=-__expf(Alogs[dir*6+wv]);
    f32 dv=dtl[lane][wv];
    f32 v=wave_iscan(dv*A,lane);
    w1l[lane][wv]=__expf(-v)*dv;
    if(lane==63){
      f32 e=__expf(v);
      e63[wv]=e;
      ach[((size_t)(b*64+c))*24+dir*6+wv]=e;
    }
  }
  __syncthreads();
  for(int u=tid;u<768;u+=384){
    int sg=u/48, q=u-sg*48, head=q>>3;
    f32 vv[4][4];
    #pragma unroll
    for(int j=0;j<4;j++){
      int s=sg*4+j;
      float4 xv=((const float4*)&xh[(size_t)(b*4096+pos_of(dir,c0+s))*192])[q];
      f32 w1=w1l[s][head];
      vv[j][0]=xv.x*w1; vv[j][1]=xv.y*w1; vv[j][2]=xv.z*w1; vv[j][3]=xv.w*w1;
    }
    #pragma unroll
    for(int cc=0;cc<4;cc++){
      u16x4 w={f2bf(vv[0][cc]),f2bf(vv[1][cc]),f2bf(vv[2][cc]),f2bf(vv[3][cc])};
      *(u16x4*)&Bp[(4*q+cc)*LDK1+sg*4]=w;
    }
  }
  __syncthreads();
  const int l15=lane&15, l4=lane>>4;
  f32x4 acc[2];
  { f32x4 zz={0.f,0.f,0.f,0.f}; acc[0]=zz; acc[1]=zz; }
  #pragma unroll
  for(int i=0;i<2;i++){
    int mt=wv+6*i;
    #pragma unroll
    for(int ks=0;ks<2;ks++){
      int kg=ks*4+l4;
      bf16x8 a=*(const bf16x8*)&Bp[(size_t)(mt*16+l15)*LDK1+kg*8];
      bf16x8 bb=*(const bf16x8*)&BtT[(size_t)l15*LDK1+kg*8];
      acc[i]=__builtin_amdgcn_mfma_f32_16x16x32_bf16(a,bb,acc[i],0,0,0);
    }
  }
  const size_t base=(((size_t)(b*64+c))*24+dir*6)*512;
  #pragma unroll
  for(int i=0;i<2;i++){
    int mt=wv+6*i;
    #pragma unroll
    for(int r=0;r<4;r++){
      int ch=mt*16+l4*4+r, head=ch>>5, d=ch&31;
      S[base+(size_t)head*512+d*16+l15]=acc[i][r]*e63[head];
    }
  }
}

// ---------------- Kernel D2: serial inter-chunk scan (in-place S -> prev) ------
__global__ __launch_bounds__(256) void k_scan(f32* __restrict__ S, const f32* __restrict__ ach){
  const int g=blockIdx.x*256+threadIdx.x;
  const int b=g/12288, rem=g%12288, h=rem/512;
  size_t base=(size_t)b*786432 + rem;
  const f32* ap=&ach[(size_t)b*1536 + h];
  f32 st=0.f;
  for(int c=0;c<64;c++){
    f32 a=ap[c*24];
    f32 s=S[base+(size_t)c*12288];
    S[base+(size_t)c*12288]=st;
    st=a*st+s;
  }
}

// ---------------- Kernel D3 (MFMA, merged dirs+halves): 768 thr = 12 waves ------
// grid (64 c, 8 b, 2 pair). pair 0 = dirs {0,2} -> ym0 ; pair 1 = dirs {1,3} -> ym1.
// Upfront: both dirs' scans (12 waves = 2 dirs x 6 heads). Then per dir: stage,
// CB via MFMA (masked tri), B' build (all 192 ch), 64x192x96 MFMA, accumulate.
#define LDK 104
__global__ __launch_bounds__(768) void k_chunk2(const f32* __restrict__ xh, const f32* __restrict__ Bg,
      const f32* __restrict__ Cg, const f32* __restrict__ dt_sp, const f32* __restrict__ Sprev,
      const f32* __restrict__ Alogs,
      f32* __restrict__ ym0, f32* __restrict__ ym1){
  __shared__ unsigned short Alds[64*LDK];   // 13.3 KB: [CBtri | Ct | 0]
  __shared__ unsigned short Blds[192*LDK];  // 39.9 KB: [x*w1 ; prevT ; 0]
  __shared__ unsigned short Btf[64*32];     // 4 KB
  __shared__ f32 w1l[2][64][6], erowl[2][64][6];  // 6 KB  (total 63.5 KB -> 2 blk/CU)
  const int c=blockIdx.x, b=blockIdx.y, pair=blockIdx.z;
  const int c0=c*64, tid=threadIdx.x;
  f32* __restrict__ ym = pair? ym1 : ym0;
  const int wv=tid>>6, lane=tid&63, l15=lane&15, l4=lane>>4;
  // upfront scans for both dirs
  {
    int ds=(wv>=6)?1:0, head=ds? wv-6 : wv;
    int dirs=pair+2*ds;
    f32 Aa=-__expf(Alogs[dirs*6+head]);
    size_t pixL=(size_t)b*4096 + (pair==0 ? (c0+lane) : (lane*64+c));
    f32 dv=dt_sp[pixL*24+dirs*6+head];
    f32 sc = ds? wave_sscan(dv*Aa,lane) : wave_iscan(dv*Aa,lane);
    w1l[ds][lane][head]=__expf(-sc)*dv;
    erowl[ds][lane][head]=__expf(sc);
  }
  f32 vsum[4][4];
  #pragma unroll
  for(int mt=0;mt<4;mt++){
    #pragma unroll
    for(int r=0;r<4;r++) vsum[mt][r]=0.f;
  }
  const int gch=wv*16+l15, ohead=gch>>5;
  #pragma unroll
  for(int d=0;d<2;d++){
    const int dir=pair+d*2;
    const int cd=d? (63-c) : c;
    if(d) __syncthreads();   // previous iteration's LDS reads done
    // stage B->Btf, C->Alds cols 64..95 (pixel order)
    if(tid<256){
      int r=tid>>2,q=tid&3;
      size_t pix=(size_t)b*4096 + (pair==0 ? (c0+r) : (r*64+c));
      float4 bv=*(const float4*)&Bg[(pix*4+dir)*16+q*4];
      float4 cv=*(const float4*)&Cg[(pix*4+dir)*16+q*4];
      u16x4 wb={f2bf(bv.x),f2bf(bv.y),f2bf(bv.z),f2bf(bv.w)};
      u16x4 wc={f2bf(cv.x),f2bf(cv.y),f2bf(cv.z),f2bf(cv.w)};
      u16x4 zz={0,0,0,0};
      *(u16x4*)&Btf[r*32+q*4]=wb;      *(u16x4*)&Btf[r*32+16+q*4]=zz;
      *(u16x4*)&Alds[r*LDK+64+q*4]=wc; *(u16x4*)&Alds[r*LDK+80+q*4]=zz;
    }
    // stage prevT (chunk cd of this dir), all 192 rows
    {
      const size_t pbase=(((size_t)(b*64+cd))*24+dir*6)*512;
      int lr=tid>>2, ng=tid&3, hh=lr>>5, dd=lr&31;
      float4 pv=*(const float4*)&Sprev[pbase+(size_t)hh*512+dd*16+ng*4];
      u16x4 w={f2bf(pv.x),f2bf(pv.y),f2bf(pv.z),f2bf(pv.w)};
      u16x4 zz={0,0,0,0};
      *(u16x4*)&Blds[lr*LDK+64+ng*4]=w;
      *(u16x4*)&Blds[lr*LDK+80+ng*4]=zz;
    }
    __syncthreads();
    // CB = Ct@Bt^T via MFMA (masked): tiles wv and wv+12
    #pragma unroll
    for(int tt=0;tt<2;tt++){
      int tile=wv+12*tt;
      if(tile<16){
        int mt=tile>>2, nt=tile&3;
        f32x4 a4={0.f,0.f,0.f,0.f};
        bf16x8 af=*(const bf16x8*)&Alds[(mt*16+l15)*LDK+64+l4*8];
        bf16x8 bfr=*(const bf16x8*)&Btf[(nt*16+l15)*32+l4*8];
        a4=__builtin_amdgcn_mfma_f32_16x16x32_bf16(af,bfr,a4,0,0,0);
        #pragma unroll
        for(int r=0;r<4;r++){
          int t=mt*16+l4*4+r, s=nt*16+l15;
          bool keep = d? (s>=t) : (s<=t);
          Alds[t*LDK+s]= keep? f2bf(a4[r]) : (unsigned short)0;
        }
      }
    }
    // B' = x (global fp32) * w1, transposed write — all 192 ch, 768 tasks
    {
      int sg=tid/48, q=tid-sg*48;
      int head=q>>3;
      f32 vv[4][4];
      #pragma unroll
      for(int j=0;j<4;j++){
        int s=sg*4+j;
        size_t pix=(size_t)b*4096 + (pair==0 ? (c0+s) : (s*64+c));
        float4 xv=*(const float4*)&xh[pix*192 + q*4];
        f32 w1=w1l[d][s][head];
        vv[j][0]=xv.x*w1; vv[j][1]=xv.y*w1; vv[j][2]=xv.z*w1; vv[j][3]=xv.w*w1;
      }
      #pragma unroll
      for(int cc=0;cc<4;cc++){
        u16x4 w={f2bf(vv[0][cc]),f2bf(vv[1][cc]),f2bf(vv[2][cc]),f2bf(vv[3][cc])};
        *(u16x4*)&Blds[(4*q+cc)*LDK+sg*4]=w;
      }
    }
    __syncthreads();
    // main MFMA 64x192x96: wave strip = gch 16 cols
    f32x4 acc[4];
    #pragma unroll
    for(int mt=0;mt<4;mt++){ f32x4 zz={0.f,0.f,0.f,0.f}; acc[mt]=zz; }
    #pragma unroll
    for(int ks=0;ks<3;ks++){
      const int kg=ks*4+l4;
      bf16x8 bfr=*(const bf16x8*)&Blds[(wv*16+l15)*LDK+kg*8];
      #pragma unroll
      for(int mt=0;mt<4;mt++){
        bf16x8 af=*(const bf16x8*)&Alds[(mt*16+l15)*LDK+kg*8];
        acc[mt]=__builtin_amdgcn_mfma_f32_16x16x32_bf16(af,bfr,acc[mt],0,0,0);
      }
    }
    #pragma unroll
    for(int mt=0;mt<4;mt++){
      #pragma unroll
      for(int r=0;r<4;r++){
        int t=mt*16+l4*4+r;
        vsum[mt][r]+=acc[mt][r]*erowl[d][t][ohead];
      }
    }
  }
  // single store (no RMW)
  #pragma unroll
  for(int mt=0;mt<4;mt++){
    #pragma unroll
    for(int r=0;r<4;r++){
      int t=mt*16+l4*4+r;
      size_t pix=(size_t)b*4096 + (pair==0 ? (c0+t) : (t*64+c));
      ym[pix*192+gch]=vsum[mt][r];
    }
  }
}

// ---------------- Kernel F (MFMA): out = LN(ym0+ym1+x*Dsum)*z @ Wo^T -----------
__global__ __launch_bounds__(256) void k_outproj(const f32* __restrict__ ym0, const f32* __restrict__ ym1,
                                                 const f32* __restrict__ xh, const f32* __restrict__ Dsum,
                                                 const f32* __restrict__ z,
                                                 const f32* __restrict__ lw, const f32* __restrict__ lb,
                                                 const unsigned short* __restrict__ Wo, f32* __restrict__ out){
  __shared__ unsigned short Ald[24*64*8];      // 24 KB
  __shared__ f32 lws[192], lbs[192], dss[192];
  const int m0=blockIdx.x*64, tid=threadIdx.x;
  for(int i=tid;i<192;i+=256){ lws[i]=lw[i]; lbs[i]=lb[i]; dss[i]=Dsum[i]; }
  __syncthreads();
  const int r=tid>>2, sub=tid&3;
  const size_t base=(size_t)(m0+r)*192 + sub*48;
  f32 y[48];
  f32 s=0.f;
  #pragma unroll
  for(int j=0;j<48;j+=4){
    float4 a=*(const float4*)&ym0[base+j];
    float4 bb=*(const float4*)&ym1[base+j];
    float4 xv=*(const float4*)&xh[base+j];
    int col=sub*48+j;
    y[j]  =a.x+bb.x+xv.x*dss[col];
    y[j+1]=a.y+bb.y+xv.y*dss[col+1];
    y[j+2]=a.z+bb.z+xv.z*dss[col+2];
    y[j+3]=a.w+bb.w+xv.w*dss[col+3];
    s+=y[j]+y[j+1]+y[j+2]+y[j+3];
  }
  s+=__shfl_xor(s,1,64); s+=__shfl_xor(s,2,64);
  const f32 mu=s*(1.f/192.f);
  f32 q=0.f;
  #pragma unroll
  for(int j=0;j<48;j++){ f32 dd=y[j]-mu; q+=dd*dd; }
  q+=__shfl_xor(q,1,64); q+=__shfl_xor(q,2,64);
  const f32 rs=rsqrtf(q*(1.f/192.f)+1e-5f);
  #pragma unroll
  for(int j=0;j<48;j+=8){
    float4 z0=*(const float4*)&z[base+j];
    float4 z1=*(const float4*)&z[base+j+4];
    int col=sub*48+j;
    u16x8 w;
    w[0]=f2bf(((y[j+0]-mu)*rs*lws[col+0]+lbs[col+0])*z0.x);
    w[1]=f2bf(((y[j+1]-mu)*rs*lws[col+1]+lbs[col+1])*z0.y);
    w[2]=f2bf(((y[j+2]-mu)*rs*lws[col+2]+lbs[col+2])*z0.z);
    w[3]=f2bf(((y[j+3]-mu)*rs*lws[col+3]+lbs[col+3])*z0.w);
    w[4]=f2bf(((y[j+4]-mu)*rs*lws[col+4]+lbs[col+4])*z1.x);
    w[5]=f2bf(((y[j+5]-mu)*rs*lws[col+5]+lbs[col+5])*z1.y);
    w[6]=f2bf(((y[j+6]-mu)*rs*lws[col+6]+lbs[col+6])*z1.z);
    w[7]=f2bf(((y[j+7]-mu)*rs*lws[col+7]+lbs[col+7])*z1.w);
    int g=col>>3;
    *(u16x8*)&Ald[((size_t)g*64+r)*8]=w;
  }
  __syncthreads();
  const int wv=tid>>6, lane=tid&63, l15=lane&15, l4=lane>>4;
  f32x4 acc[6];
  #pragma unroll
  for(int nt=0;nt<6;nt++){ f32x4 zz={0.f,0.f,0.f,0.f}; acc[nt]=zz; }
  #pragma unroll
  for(int ks=0;ks<6;ks++){
    const int g=ks*4+l4;
    bf16x8 a=*(const bf16x8*)&Ald[(size_t)(g*64+wv*16+l15)*8];
    #pragma unroll
    for(int nt=0;nt<6;nt++){
      bf16x8 bfr=*(const bf16x8*)&Wo[((size_t)(nt*24+g)*16+l15)*8];
      acc[nt]=__builtin_amdgcn_mfma_f32_16x16x32_bf16(a,bfr,acc[nt],0,0,0);
    }
  }
  const int rowb=m0+wv*16+l4*4;
  #pragma unroll
  for(int nt=0;nt<6;nt++){
    int col=nt*16+l15;
    #pragma unroll
    for(int r2=0;r2<4;r2++){
      out[(size_t)(rowb+r2)*96+col]=acc[nt][r2];
    }
  }
}

extern "C" void kernel_launch(void* const* d_in, const int* in_sizes, int n_in,
                              void* d_out, int out_size, void* d_ws, size_t ws_size,
                              hipStream_t stream){
  const f32* x  =(const f32*)d_in[0];
  const f32* ipw=(const f32*)d_in[1];
  const f32* cw =(const f32*)d_in[2];
  const f32* cb =(const f32*)d_in[3];
  const f32* xpw=(const f32*)d_in[4];
  const f32* alg=(const f32*)d_in[5];
  const f32* dsw=(const f32*)d_in[6];
  const f32* dtb=(const f32*)d_in[7];
  const f32* lw =(const f32*)d_in[8];
  const f32* lb =(const f32*)d_in[9];
  const f32* opw=(const f32*)d_in[10];
  f32* out=(f32*)d_out;
  f32* ws=(f32*)d_ws;

  f32* xh_raw=ws;               // 6291456 floats (reused as ym0)
  f32* z     =ws+ 6291456;      // 6291456
  f32* xh    =ws+12582912;      // 6291456
  f32* dt_sp =ws+18874368;      //  786432
  f32* Bg    =ws+19660800;      // 2097152
  f32* Cg    =ws+21757952;      // 2097152
  f32* S     =ws+23855104;      // 6291456
  f32* ach   =ws+30146560;      //   12288
  f32* ym1   =ws+30158848;      // 6291456
  unsigned short* Wx=(unsigned short*)(ws+36450304);
  unsigned short* Wi=(unsigned short*)(ws+36465664);
  unsigned short* Wo=(unsigned short*)(ws+36484096);
  f32* Dsum  =ws+36493312;      //     192
  f32* ym0=xh_raw;

  k_wcvt_all<<<43,256,0,stream>>>(xpw,ipw,opw,dsw,Wx,Wi,Wo,Dsum);
  k_inproj<<<512,256,0,stream>>>(x,Wi,xh_raw,z);
  k_xdblconv<<<512,256,0,stream>>>(xh_raw,cw,cb,Wx,dtb,xh,dt_sp,Bg,Cg);
  k_chunk1<<<dim3(64,4,8),384,0,stream>>>(xh,Bg,dt_sp,alg,S,ach);
  k_scan<<<384,256,0,stream>>>(S,ach);
  k_chunk2<<<dim3(64,8,2),768,0,stream>>>(xh,Bg,Cg,dt_sp,S,alg,ym0,ym1);
  k_outproj<<<512,256,0,stream>>>(ym0,ym1,xh,Dsum,z,lw,lb,Wo,out);
}

// Round 13
// 178.942 us; speedup vs baseline: 3.1872x; 1.0508x over previous
//
#include <hip/hip_runtime.h>
#include <hip/hip_bf16.h>

using bf16 = __hip_bfloat16;
typedef float f32;
typedef __attribute__((ext_vector_type(8))) short bf16x8;
typedef __attribute__((ext_vector_type(4))) float f32x4;
typedef __attribute__((ext_vector_type(4))) unsigned short u16x4;
typedef __attribute__((ext_vector_type(8))) unsigned short u16x8;

static __device__ __forceinline__ f32 siluf(f32 v){ return v / (1.f + __expf(-v)); }
static __device__ __forceinline__ unsigned short f2bf(f32 v){
  __hip_bfloat16 h=__float2bfloat16(v); return *(unsigned short*)&h;
}
static __device__ __forceinline__ f32 bfr2f(unsigned short u){
  unsigned int x=((unsigned int)u)<<16; return __uint_as_float(x);
}

// spatial position of sequence index p for scan direction dir (H=W=64, L=4096)
static __device__ __forceinline__ int pos_of(int dir, int p){
  if(dir==0) return p;
  if(dir==1) return ((p&63)<<6) | (p>>6);
  if(dir==2) return 4095-p;
  int q = 4095-p; return ((q&63)<<6) | (q>>6);
}

// inclusive wave-64 prefix scan
static __device__ __forceinline__ f32 wave_iscan(f32 v, int lane){
  #pragma unroll
  for(int off=1; off<64; off<<=1){
    f32 u=__shfl_up(v,off,64);
    if(lane>=off) v+=u;
  }
  return v;
}
// inclusive wave-64 suffix scan (v[lane] = sum_{j>=lane})
static __device__ __forceinline__ f32 wave_sscan(f32 v, int lane){
  #pragma unroll
  for(int off=1; off<64; off<<=1){
    f32 u=__shfl_down(v,off,64);
    if(lane<64-off) v+=u;
  }
  return v;
}

// ---------------- Kernel W: weights -> bf16 fragment layout + Dsum -------------
__global__ __launch_bounds__(256) void k_wcvt_all(const f32* __restrict__ xpw, const f32* __restrict__ ipw,
                                                  const f32* __restrict__ opw, const f32* __restrict__ dsw,
                                                  unsigned short* __restrict__ Wx, unsigned short* __restrict__ Wi,
                                                  unsigned short* __restrict__ Wo, f32* __restrict__ Dsum){
  const int t=blockIdx.x*256+threadIdx.x;
  if(t<3840){
    const int g=t%24, n=t/24, nt=n>>4, l=n&15;
    const int dir=n/40, cc=n-dir*40;
    u16x8 w={0,0,0,0,0,0,0,0};
    if(cc<38){
      const f32* p=&xpw[(size_t)dir*7296+cc*192+g*8];
      #pragma unroll
      for(int j=0;j<8;j++) w[j]=f2bf(p[j]);
    }
    *(u16x8*)&Wx[((size_t)(nt*24+g)*16+l)*8]=w;
  } else if(t<8448){
    const int i=t-3840, g=i%12, n=i/12, nt=n>>4, l=n&15;
    const f32* p=&ipw[(size_t)n*96+g*8];
    u16x8 w;
    #pragma unroll
    for(int j=0;j<8;j++) w[j]=f2bf(p[j]);
    *(u16x8*)&Wi[((size_t)(nt*12+g)*16+l)*8]=w;
  } else if(t<10752){
    const int i=t-8448, g=i%24, n=i/24, nt=n>>4, l=n&15;
    const f32* p=&opw[(size_t)n*192+g*8];
    u16x8 w;
    #pragma unroll
    for(int j=0;j<8;j++) w[j]=f2bf(p[j]);
    *(u16x8*)&Wo[((size_t)(nt*24+g)*16+l)*8]=w;
  } else if(t<10944){
    const int ch=t-10752;
    Dsum[ch]=dsw[ch]+dsw[192+ch]+dsw[384+ch]+dsw[576+ch];
  }
}

// ---------------- Kernel A (MFMA): xz = x @ in_proj_w.T ; split, silu ----------
// BM=32, 1024 blocks (4 blk/CU). Wave: mt=wv&1, nt strip (wv>>1)*12.
__global__ __launch_bounds__(256) void k_inproj(const f32* __restrict__ x, const unsigned short* __restrict__ Wi,
                                                f32* __restrict__ xh_raw, f32* __restrict__ z){
  __shared__ unsigned short Ald[12*32*8];      // 6 KB
  const int m0=blockIdx.x*32, tid=threadIdx.x;
  for(int i=tid;i<384;i+=256){
    int r=i&31, g=i>>5;
    const f32* p=&x[(size_t)(m0+r)*96+g*8];
    float4 v0=*(const float4*)p, v1=*(const float4*)(p+4);
    u16x8 w={f2bf(v0.x),f2bf(v0.y),f2bf(v0.z),f2bf(v0.w),
             f2bf(v1.x),f2bf(v1.y),f2bf(v1.z),f2bf(v1.w)};
    *(u16x8*)&Ald[(size_t)(g*32+r)*8]=w;
  }
  __syncthreads();
  const int wv=tid>>6, lane=tid&63, l15=lane&15, l4=lane>>4;
  const int mt=wv&1, ntb=(wv>>1)*12;
  f32x4 acc[12];
  #pragma unroll
  for(int j=0;j<12;j++){ f32x4 zz={0.f,0.f,0.f,0.f}; acc[j]=zz; }
  #pragma unroll
  for(int ks=0;ks<3;ks++){
    const int g=ks*4+l4;
    bf16x8 a=*(const bf16x8*)&Ald[(size_t)(g*32+mt*16+l15)*8];
    #pragma unroll
    for(int j=0;j<12;j++){
      bf16x8 bfr=*(const bf16x8*)&Wi[((size_t)((ntb+j)*12+g)*16+l15)*8];
      acc[j]=__builtin_amdgcn_mfma_f32_16x16x32_bf16(a,bfr,acc[j],0,0,0);
    }
  }
  const int rowb=m0+mt*16+l4*4;
  #pragma unroll
  for(int j=0;j<12;j++){
    int col=(ntb+j)*16+l15;
    #pragma unroll
    for(int r=0;r<4;r++){
      int row=rowb+r; f32 v=acc[j][r];
      if(col<192) xh_raw[(size_t)row*192+col]=v;
      else        z[(size_t)row*192+(col-192)]=siluf(v);
    }
  }
}

// ---------------- Kernel B: depthwise 3x3 conv + bias + silu --------------------
__global__ __launch_bounds__(256) void k_conv(const f32* __restrict__ xh_raw, const f32* __restrict__ cw,
                                              const f32* __restrict__ cb, f32* __restrict__ xh){
  __shared__ f32 wsm[192][9];
  __shared__ f32 bsm[192];
  const int tid=threadIdx.x;
  for(int i=tid;i<1728;i+=256) wsm[i/9][i%9]=cw[i];
  for(int i=tid;i<192;i+=256) bsm[i]=cb[i];
  __syncthreads();
  const int idx=blockIdx.x*256+tid;
  const int c4=idx%48, j=(idx/48)&63, ii0=(idx/3072)&63, b=idx/196608;
  const int c0=c4*4;
  f32 acc[4]={bsm[c0],bsm[c0+1],bsm[c0+2],bsm[c0+3]};
  #pragma unroll
  for(int a=0;a<3;a++){
    int ii=ii0+a-1; if(ii<0||ii>63) continue;
    #pragma unroll
    for(int bb=0;bb<3;bb++){
      int jj=j+bb-1; if(jj<0||jj>63) continue;
      float4 v=*(const float4*)&xh_raw[((size_t)(b*4096)+(ii*64+jj))*192 + c0];
      int t=a*3+bb;
      acc[0]+=v.x*wsm[c0][t]; acc[1]+=v.y*wsm[c0+1][t];
      acc[2]+=v.z*wsm[c0+2][t]; acc[3]+=v.w*wsm[c0+3][t];
    }
  }
  float4 o; o.x=siluf(acc[0]); o.y=siluf(acc[1]); o.z=siluf(acc[2]); o.w=siluf(acc[3]);
  ((float4*)xh)[idx]=o;
}

// ---------------- Kernel C (MFMA): x_dbl = xh @ Wx^T -> dt(softplus), B, C -----
// BM=32, 1024 blocks (4 blk/CU). Wave: mt=wv&1, nt strip (wv>>1)*5.
__global__ __launch_bounds__(256) void k_xdbl(const f32* __restrict__ xh, const unsigned short* __restrict__ Wfrag,
                                              const f32* __restrict__ dtb, f32* __restrict__ dt_sp,
                                              f32* __restrict__ Bg, f32* __restrict__ Cg){
  __shared__ unsigned short Ald[24*32*8];      // 12 KB
  const int m0=blockIdx.x*32;
  const int tid=threadIdx.x;
  for(int i=tid;i<768;i+=256){
    int r=i&31, g=i>>5;
    const f32* p=&xh[(size_t)(m0+r)*192 + g*8];
    float4 v0=*(const float4*)p, v1=*(const float4*)(p+4);
    u16x8 w={f2bf(v0.x),f2bf(v0.y),f2bf(v0.z),f2bf(v0.w),
             f2bf(v1.x),f2bf(v1.y),f2bf(v1.z),f2bf(v1.w)};
    *(u16x8*)&Ald[(size_t)(g*32+r)*8]=w;
  }
  __syncthreads();
  const int wv=tid>>6, lane=tid&63, l15=lane&15, l4=lane>>4;
  const int mt=wv&1, ntb=(wv>>1)*5;
  f32x4 acc[5];
  #pragma unroll
  for(int j=0;j<5;j++){ f32x4 zz={0.f,0.f,0.f,0.f}; acc[j]=zz; }
  #pragma unroll
  for(int ks=0;ks<6;ks++){
    const int g=ks*4+l4;
    bf16x8 a=*(const bf16x8*)&Ald[(size_t)(g*32 + mt*16 + l15)*8];
    #pragma unroll
    for(int j=0;j<5;j++){
      bf16x8 bfr=*(const bf16x8*)&Wfrag[((size_t)((ntb+j)*24+g)*16+l15)*8];
      acc[j]=__builtin_amdgcn_mfma_f32_16x16x32_bf16(a,bfr,acc[j],0,0,0);
    }
  }
  const int rowb=m0 + mt*16 + l4*4;
  #pragma unroll
  for(int j=0;j<5;j++){
    int n=(ntb+j)*16+l15, dir=n/40, cc=n-dir*40;
    if(cc>=38) continue;
    #pragma unroll
    for(int r=0;r<4;r++){
      size_t pix=(size_t)(rowb+r);
      f32 v=acc[j][r];
      if(cc<6){ f32 xv=v+dtb[dir*6+cc]; dt_sp[pix*24+dir*6+cc]=(xv>20.f)? xv : log1pf(__expf(xv)); }
      else if(cc<22){ Bg[(pix*4+dir)*16+(cc-6)]=v; }
      else          { Cg[(pix*4+dir)*16+(cc-22)]=v; }
    }
  }
}

// ---------------- Kernel D1 (MFMA): S_loc = e63 * (B' @ Bt^T) ------------------
#define LDK1 72
__global__ __launch_bounds__(384) void k_chunk1(const f32* __restrict__ xh, const f32* __restrict__ Bg,
      const f32* __restrict__ dt_sp, const f32* __restrict__ Alogs, f32* __restrict__ S, f32* __restrict__ ach){
  __shared__ unsigned short Bp[192*LDK1];
  __shared__ unsigned short BtT[16*LDK1];
  __shared__ f32 dtl[64][6], w1l[64][6];
  __shared__ f32 e63[6];
  const int c=blockIdx.x, dir=blockIdx.y, b=blockIdx.z, c0=c*64, tid=threadIdx.x;
  { int r=tid/6, q=tid-r*6; size_t pix=(size_t)b*4096+pos_of(dir,c0+r);
    dtl[r][q]=dt_sp[pix*24+dir*6+q]; }
  if(tid<256){
    int r=tid>>2,q=tid&3; size_t pix=(size_t)b*4096+pos_of(dir,c0+r);
    float4 bv=*(const float4*)&Bg[(pix*4+dir)*16+q*4];
    BtT[(4*q+0)*LDK1+r]=f2bf(bv.x); BtT[(4*q+1)*LDK1+r]=f2bf(bv.y);
    BtT[(4*q+2)*LDK1+r]=f2bf(bv.z); BtT[(4*q+3)*LDK1+r]=f2bf(bv.w);
  }
  __syncthreads();
  const int wv=tid>>6, lane=tid&63;
  {
    f32 A=-__expf(Alogs[dir*6+wv]);
    f32 dv=dtl[lane][wv];
    f32 v=wave_iscan(dv*A,lane);
    w1l[lane][wv]=__expf(-v)*dv;
    if(lane==63){
      f32 e=__expf(v);
      e63[wv]=e;
      ach[((size_t)(b*64+c))*24+dir*6+wv]=e;
    }
  }
  __syncthreads();
  for(int u=tid;u<768;u+=384){
    int sg=u/48, q=u-sg*48, head=q>>3;
    f32 vv[4][4];
    #pragma unroll
    for(int j=0;j<4;j++){
      int s=sg*4+j;
      float4 xv=((const float4*)&xh[(size_t)(b*4096+pos_of(dir,c0+s))*192])[q];
      f32 w1=w1l[s][head];
      vv[j][0]=xv.x*w1; vv[j][1]=xv.y*w1; vv[j][2]=xv.z*w1; vv[j][3]=xv.w*w1;
    }
    #pragma unroll
    for(int cc=0;cc<4;cc++){
      u16x4 w={f2bf(vv[0][cc]),f2bf(vv[1][cc]),f2bf(vv[2][cc]),f2bf(vv[3][cc])};
      *(u16x4*)&Bp[(4*q+cc)*LDK1+sg*4]=w;
    }
  }
  __syncthreads();
  const int l15=lane&15, l4=lane>>4;
  f32x4 acc[2];
  { f32x4 zz={0.f,0.f,0.f,0.f}; acc[0]=zz; acc[1]=zz; }
  #pragma unroll
  for(int i=0;i<2;i++){
    int mt=wv+6*i;
    #pragma unroll
    for(int ks=0;ks<2;ks++){
      int kg=ks*4+l4;
      bf16x8 a=*(const bf16x8*)&Bp[(size_t)(mt*16+l15)*LDK1+kg*8];
      bf16x8 bb=*(const bf16x8*)&BtT[(size_t)l15*LDK1+kg*8];
      acc[i]=__builtin_amdgcn_mfma_f32_16x16x32_bf16(a,bb,acc[i],0,0,0);
    }
  }
  const size_t base=(((size_t)(b*64+c))*24+dir*6)*512;
  #pragma unroll
  for(int i=0;i<2;i++){
    int mt=wv+6*i;
    #pragma unroll
    for(int r=0;r<4;r++){
      int ch=mt*16+l4*4+r, head=ch>>5, d=ch&31;
      S[base+(size_t)head*512+d*16+l15]=acc[i][r]*e63[head];
    }
  }
}

// ---------------- Kernel D2: serial inter-chunk scan (in-place S -> prev) ------
__global__ __launch_bounds__(256) void k_scan(f32* __restrict__ S, const f32* __restrict__ ach){
  const int g=blockIdx.x*256+threadIdx.x;
  const int b=g/12288, rem=g%12288, h=rem/512;
  size_t base=(size_t)b*786432 + rem;
  const f32* ap=&ach[(size_t)b*1536 + h];
  f32 st=0.f;
  for(int c=0;c<64;c++){
    f32 a=ap[c*24];
    f32 s=S[base+(size_t)c*12288];
    S[base+(size_t)c*12288]=st;
    st=a*st+s;
  }
}

// ---------------- Kernel D3 (MFMA, merged dirs+halves): 768 thr = 12 waves ------
#define LDK 104
__global__ __launch_bounds__(768) void k_chunk2(const f32* __restrict__ xh, const f32* __restrict__ Bg,
      const f32* __restrict__ Cg, const f32* __restrict__ dt_sp, const f32* __restrict__ Sprev,
      const f32* __restrict__ Alogs,
      f32* __restrict__ ym0, f32* __restrict__ ym1){
  __shared__ unsigned short Alds[64*LDK];   // 13.3 KB: [CBtri | Ct | 0]
  __shared__ unsigned short Blds[192*LDK];  // 39.9 KB: [x*w1 ; prevT ; 0]
  __shared__ unsigned short Btf[64*32];     // 4 KB
  __shared__ f32 w1l[2][64][6], erowl[2][64][6];  // 6 KB  (total 63.5 KB -> 2 blk/CU)
  const int c=blockIdx.x, b=blockIdx.y, pair=blockIdx.z;
  const int c0=c*64, tid=threadIdx.x;
  f32* __restrict__ ym = pair? ym1 : ym0;
  const int wv=tid>>6, lane=tid&63, l15=lane&15, l4=lane>>4;
  // upfront scans for both dirs
  {
    int ds=(wv>=6)?1:0, head=ds? wv-6 : wv;
    int dirs=pair+2*ds;
    f32 Aa=-__expf(Alogs[dirs*6+head]);
    size_t pixL=(size_t)b*4096 + (pair==0 ? (c0+lane) : (lane*64+c));
    f32 dv=dt_sp[pixL*24+dirs*6+head];
    f32 sc = ds? wave_sscan(dv*Aa,lane) : wave_iscan(dv*Aa,lane);
    w1l[ds][lane][head]=__expf(-sc)*dv;
    erowl[ds][lane][head]=__expf(sc);
  }
  f32 vsum[4][4];
  #pragma unroll
  for(int mt=0;mt<4;mt++){
    #pragma unroll
    for(int r=0;r<4;r++) vsum[mt][r]=0.f;
  }
  const int gch=wv*16+l15, ohead=gch>>5;
  #pragma unroll
  for(int d=0;d<2;d++){
    const int dir=pair+d*2;
    const int cd=d? (63-c) : c;
    if(d) __syncthreads();
    if(tid<256){
      int r=tid>>2,q=tid&3;
      size_t pix=(size_t)b*4096 + (pair==0 ? (c0+r) : (r*64+c));
      float4 bv=*(const float4*)&Bg[(pix*4+dir)*16+q*4];
      float4 cv=*(const float4*)&Cg[(pix*4+dir)*16+q*4];
      u16x4 wb={f2bf(bv.x),f2bf(bv.y),f2bf(bv.z),f2bf(bv.w)};
      u16x4 wc={f2bf(cv.x),f2bf(cv.y),f2bf(cv.z),f2bf(cv.w)};
      u16x4 zz={0,0,0,0};
      *(u16x4*)&Btf[r*32+q*4]=wb;      *(u16x4*)&Btf[r*32+16+q*4]=zz;
      *(u16x4*)&Alds[r*LDK+64+q*4]=wc; *(u16x4*)&Alds[r*LDK+80+q*4]=zz;
    }
    {
      const size_t pbase=(((size_t)(b*64+cd))*24+dir*6)*512;
      int lr=tid>>2, ng=tid&3, hh=lr>>5, dd=lr&31;
      float4 pv=*(const float4*)&Sprev[pbase+(size_t)hh*512+dd*16+ng*4];
      u16x4 w={f2bf(pv.x),f2bf(pv.y),f2bf(pv.z),f2bf(pv.w)};
      u16x4 zz={0,0,0,0};
      *(u16x4*)&Blds[lr*LDK+64+ng*4]=w;
      *(u16x4*)&Blds[lr*LDK+80+ng*4]=zz;
    }
    __syncthreads();
    #pragma unroll
    for(int tt=0;tt<2;tt++){
      int tile=wv+12*tt;
      if(tile<16){
        int mt=tile>>2, nt=tile&3;
        f32x4 a4={0.f,0.f,0.f,0.f};
        bf16x8 af=*(const bf16x8*)&Alds[(mt*16+l15)*LDK+64+l4*8];
        bf16x8 bfr=*(const bf16x8*)&Btf[(nt*16+l15)*32+l4*8];
        a4=__builtin_amdgcn_mfma_f32_16x16x32_bf16(af,bfr,a4,0,0,0);
        #pragma unroll
        for(int r=0;r<4;r++){
          int t=mt*16+l4*4+r, s=nt*16+l15;
          bool keep = d? (s>=t) : (s<=t);
          Alds[t*LDK+s]= keep? f2bf(a4[r]) : (unsigned short)0;
        }
      }
    }
    {
      int sg=tid/48, q=tid-sg*48;
      int head=q>>3;
      f32 vv[4][4];
      #pragma unroll
      for(int j=0;j<4;j++){
        int s=sg*4+j;
        size_t pix=(size_t)b*4096 + (pair==0 ? (c0+s) : (s*64+c));
        float4 xv=*(const float4*)&xh[pix*192 + q*4];
        f32 w1=w1l[d][s][head];
        vv[j][0]=xv.x*w1; vv[j][1]=xv.y*w1; vv[j][2]=xv.z*w1; vv[j][3]=xv.w*w1;
      }
      #pragma unroll
      for(int cc=0;cc<4;cc++){
        u16x4 w={f2bf(vv[0][cc]),f2bf(vv[1][cc]),f2bf(vv[2][cc]),f2bf(vv[3][cc])};
        *(u16x4*)&Blds[(4*q+cc)*LDK+sg*4]=w;
      }
    }
    __syncthreads();
    f32x4 acc[4];
    #pragma unroll
    for(int mt=0;mt<4;mt++){ f32x4 zz={0.f,0.f,0.f,0.f}; acc[mt]=zz; }
    #pragma unroll
    for(int ks=0;ks<3;ks++){
      const int kg=ks*4+l4;
      bf16x8 bfr=*(const bf16x8*)&Blds[(wv*16+l15)*LDK+kg*8];
      #pragma unroll
      for(int mt=0;mt<4;mt++){
        bf16x8 af=*(const bf16x8*)&Alds[(mt*16+l15)*LDK+kg*8];
        acc[mt]=__builtin_amdgcn_mfma_f32_16x16x32_bf16(af,bfr,acc[mt],0,0,0);
      }
    }
    #pragma unroll
    for(int mt=0;mt<4;mt++){
      #pragma unroll
      for(int r=0;r<4;r++){
        int t=mt*16+l4*4+r;
        vsum[mt][r]+=acc[mt][r]*erowl[d][t][ohead];
      }
    }
  }
  #pragma unroll
  for(int mt=0;mt<4;mt++){
    #pragma unroll
    for(int r=0;r<4;r++){
      int t=mt*16+l4*4+r;
      size_t pix=(size_t)b*4096 + (pair==0 ? (c0+t) : (t*64+c));
      ym[pix*192+gch]=vsum[mt][r];
    }
  }
}

// ---------------- Kernel F (MFMA): out = LN(ym0+ym1+x*Dsum)*z @ Wo^T -----------
__global__ __launch_bounds__(256) void k_outproj(const f32* __restrict__ ym0, const f32* __restrict__ ym1,
                                                 const f32* __restrict__ xh, const f32* __restrict__ Dsum,
                                                 const f32* __restrict__ z,
                                                 const f32* __restrict__ lw, const f32* __restrict__ lb,
                                                 const unsigned short* __restrict__ Wo, f32* __restrict__ out){
  __shared__ unsigned short Ald[24*64*8];      // 24 KB
  __shared__ f32 lws[192], lbs[192], dss[192];
  const int m0=blockIdx.x*64, tid=threadIdx.x;
  for(int i=tid;i<192;i+=256){ lws[i]=lw[i]; lbs[i]=lb[i]; dss[i]=Dsum[i]; }
  __syncthreads();
  const int r=tid>>2, sub=tid&3;
  const size_t base=(size_t)(m0+r)*192 + sub*48;
  f32 y[48];
  f32 s=0.f;
  #pragma unroll
  for(int j=0;j<48;j+=4){
    float4 a=*(const float4*)&ym0[base+j];
    float4 bb=*(const float4*)&ym1[base+j];
    float4 xv=*(const float4*)&xh[base+j];
    int col=sub*48+j;
    y[j]  =a.x+bb.x+xv.x*dss[col];
    y[j+1]=a.y+bb.y+xv.y*dss[col+1];
    y[j+2]=a.z+bb.z+xv.z*dss[col+2];
    y[j+3]=a.w+bb.w+xv.w*dss[col+3];
    s+=y[j]+y[j+1]+y[j+2]+y[j+3];
  }
  s+=__shfl_xor(s,1,64); s+=__shfl_xor(s,2,64);
  const f32 mu=s*(1.f/192.f);
  f32 q=0.f;
  #pragma unroll
  for(int j=0;j<48;j++){ f32 dd=y[j]-mu; q+=dd*dd; }
  q+=__shfl_xor(q,1,64); q+=__shfl_xor(q,2,64);
  const f32 rs=rsqrtf(q*(1.f/192.f)+1e-5f);
  #pragma unroll
  for(int j=0;j<48;j+=8){
    float4 z0=*(const float4*)&z[base+j];
    float4 z1=*(const float4*)&z[base+j+4];
    int col=sub*48+j;
    u16x8 w;
    w[0]=f2bf(((y[j+0]-mu)*rs*lws[col+0]+lbs[col+0])*z0.x);
    w[1]=f2bf(((y[j+1]-mu)*rs*lws[col+1]+lbs[col+1])*z0.y);
    w[2]=f2bf(((y[j+2]-mu)*rs*lws[col+2]+lbs[col+2])*z0.z);
    w[3]=f2bf(((y[j+3]-mu)*rs*lws[col+3]+lbs[col+3])*z0.w);
    w[4]=f2bf(((y[j+4]-mu)*rs*lws[col+4]+lbs[col+4])*z1.x);
    w[5]=f2bf(((y[j+5]-mu)*rs*lws[col+5]+lbs[col+5])*z1.y);
    w[6]=f2bf(((y[j+6]-mu)*rs*lws[col+6]+lbs[col+6])*z1.z);
    w[7]=f2bf(((y[j+7]-mu)*rs*lws[col+7]+lbs[col+7])*z1.w);
    int g=col>>3;
    *(u16x8*)&Ald[((size_t)g*64+r)*8]=w;
  }
  __syncthreads();
  const int wv=tid>>6, lane=tid&63, l15=lane&15, l4=lane>>4;
  f32x4 acc[6];
  #pragma unroll
  for(int nt=0;nt<6;nt++){ f32x4 zz={0.f,0.f,0.f,0.f}; acc[nt]=zz; }
  #pragma unroll
  for(int ks=0;ks<6;ks++){
    const int g=ks*4+l4;
    bf16x8 a=*(const bf16x8*)&Ald[(size_t)(g*64+wv*16+l15)*8];
    #pragma unroll
    for(int nt=0;nt<6;nt++){
      bf16x8 bfr=*(const bf16x8*)&Wo[((size_t)(nt*24+g)*16+l15)*8];
      acc[nt]=__builtin_amdgcn_mfma_f32_16x16x32_bf16(a,bfr,acc[nt],0,0,0);
    }
  }
  const int rowb=m0+wv*16+l4*4;
  #pragma unroll
  for(int nt=0;nt<6;nt++){
    int col=nt*16+l15;
    #pragma unroll
    for(int r2=0;r2<4;r2++){
      out[(size_t)(rowb+r2)*96+col]=acc[nt][r2];
    }
  }
}

extern "C" void kernel_launch(void* const* d_in, const int* in_sizes, int n_in,
                              void* d_out, int out_size, void* d_ws, size_t ws_size,
                              hipStream_t stream){
  const f32* x  =(const f32*)d_in[0];
  const f32* ipw=(const f32*)d_in[1];
  const f32* cw =(const f32*)d_in[2];
  const f32* cb =(const f32*)d_in[3];
  const f32* xpw=(const f32*)d_in[4];
  const f32* alg=(const f32*)d_in[5];
  const f32* dsw=(const f32*)d_in[6];
  const f32* dtb=(const f32*)d_in[7];
  const f32* lw =(const f32*)d_in[8];
  const f32* lb =(const f32*)d_in[9];
  const f32* opw=(const f32*)d_in[10];
  f32* out=(f32*)d_out;
  f32* ws=(f32*)d_ws;

  f32* xh_raw=ws;               // 6291456 floats (reused as ym0)
  f32* z     =ws+ 6291456;      // 6291456
  f32* xh    =ws+12582912;      // 6291456
  f32* dt_sp =ws+18874368;      //  786432
  f32* Bg    =ws+19660800;      // 2097152
  f32* Cg    =ws+21757952;      // 2097152
  f32* S     =ws+23855104;      // 6291456
  f32* ach   =ws+30146560;      //   12288
  f32* ym1   =ws+30158848;      // 6291456
  unsigned short* Wx=(unsigned short*)(ws+36450304);
  unsigned short* Wi=(unsigned short*)(ws+36465664);
  unsigned short* Wo=(unsigned short*)(ws+36484096);
  f32* Dsum  =ws+36493312;      //     192
  f32* ym0=xh_raw;

  k_wcvt_all<<<43,256,0,stream>>>(xpw,ipw,opw,dsw,Wx,Wi,Wo,Dsum);
  k_inproj<<<1024,256,0,stream>>>(x,Wi,xh_raw,z);
  k_conv<<<6144,256,0,stream>>>(xh_raw,cw,cb,xh);
  k_xdbl<<<1024,256,0,stream>>>(xh,Wx,dtb,dt_sp,Bg,Cg);
  k_chunk1<<<dim3(64,4,8),384,0,stream>>>(xh,Bg,dt_sp,alg,S,ach);
  k_scan<<<384,256,0,stream>>>(S,ach);
  k_chunk2<<<dim3(64,8,2),768,0,stream>>>(xh,Bg,Cg,dt_sp,S,alg,ym0,ym1);
  k_outproj<<<512,256,0,stream>>>(ym0,ym1,xh,Dsum,z,lw,lb,Wo,out);
}

// Round 14
// 177.870 us; speedup vs baseline: 3.2064x; 1.0060x over previous
//
#include <hip/hip_runtime.h>
#include <hip/hip_bf16.h>

using bf16 = __hip_bfloat16;
typedef float f32;
typedef __attribute__((ext_vector_type(8))) short bf16x8;
typedef __attribute__((ext_vector_type(4))) float f32x4;
typedef __attribute__((ext_vector_type(4))) unsigned short u16x4;
typedef __attribute__((ext_vector_type(8))) unsigned short u16x8;

static __device__ __forceinline__ f32 siluf(f32 v){ return v / (1.f + __expf(-v)); }
static __device__ __forceinline__ unsigned short f2bf(f32 v){
  __hip_bfloat16 h=__float2bfloat16(v); return *(unsigned short*)&h;
}
static __device__ __forceinline__ f32 bfr2f(unsigned short u){
  unsigned int x=((unsigned int)u)<<16; return __uint_as_float(x);
}

// spatial position of sequence index p for scan direction dir (H=W=64, L=4096)
static __device__ __forceinline__ int pos_of(int dir, int p){
  if(dir==0) return p;
  if(dir==1) return ((p&63)<<6) | (p>>6);
  if(dir==2) return 4095-p;
  int q = 4095-p; return ((q&63)<<6) | (q>>6);
}

// inclusive wave-64 prefix scan
static __device__ __forceinline__ f32 wave_iscan(f32 v, int lane){
  #pragma unroll
  for(int off=1; off<64; off<<=1){
    f32 u=__shfl_up(v,off,64);
    if(lane>=off) v+=u;
  }
  return v;
}
// inclusive wave-64 suffix scan (v[lane] = sum_{j>=lane})
static __device__ __forceinline__ f32 wave_sscan(f32 v, int lane){
  #pragma unroll
  for(int off=1; off<64; off<<=1){
    f32 u=__shfl_down(v,off,64);
    if(lane<64-off) v+=u;
  }
  return v;
}

// ---------------- Kernel W: weights -> bf16 fragment layout + Dsum -------------
__global__ __launch_bounds__(256) void k_wcvt_all(const f32* __restrict__ xpw, const f32* __restrict__ ipw,
                                                  const f32* __restrict__ opw, const f32* __restrict__ dsw,
                                                  unsigned short* __restrict__ Wx, unsigned short* __restrict__ Wi,
                                                  unsigned short* __restrict__ Wo, f32* __restrict__ Dsum){
  const int t=blockIdx.x*256+threadIdx.x;
  if(t<3840){
    const int g=t%24, n=t/24, nt=n>>4, l=n&15;
    const int dir=n/40, cc=n-dir*40;
    u16x8 w={0,0,0,0,0,0,0,0};
    if(cc<38){
      const f32* p=&xpw[(size_t)dir*7296+cc*192+g*8];
      #pragma unroll
      for(int j=0;j<8;j++) w[j]=f2bf(p[j]);
    }
    *(u16x8*)&Wx[((size_t)(nt*24+g)*16+l)*8]=w;
  } else if(t<8448){
    const int i=t-3840, g=i%12, n=i/12, nt=n>>4, l=n&15;
    const f32* p=&ipw[(size_t)n*96+g*8];
    u16x8 w;
    #pragma unroll
    for(int j=0;j<8;j++) w[j]=f2bf(p[j]);
    *(u16x8*)&Wi[((size_t)(nt*12+g)*16+l)*8]=w;
  } else if(t<10752){
    const int i=t-8448, g=i%24, n=i/24, nt=n>>4, l=n&15;
    const f32* p=&opw[(size_t)n*192+g*8];
    u16x8 w;
    #pragma unroll
    for(int j=0;j<8;j++) w[j]=f2bf(p[j]);
    *(u16x8*)&Wo[((size_t)(nt*24+g)*16+l)*8]=w;
  } else if(t<10944){
    const int ch=t-10752;
    Dsum[ch]=dsw[ch]+dsw[192+ch]+dsw[384+ch]+dsw[576+ch];
  }
}

// ---------------- Kernel A (MFMA): xz = x @ in_proj_w.T ; split, silu ----------
// BM=32, 1024 blocks (4 blk/CU). Wave: mt=wv&1, nt strip (wv>>1)*12.
__global__ __launch_bounds__(256) void k_inproj(const f32* __restrict__ x, const unsigned short* __restrict__ Wi,
                                                f32* __restrict__ xh_raw, f32* __restrict__ z){
  __shared__ unsigned short Ald[12*32*8];      // 6 KB
  const int m0=blockIdx.x*32, tid=threadIdx.x;
  for(int i=tid;i<384;i+=256){
    int r=i&31, g=i>>5;
    const f32* p=&x[(size_t)(m0+r)*96+g*8];
    float4 v0=*(const float4*)p, v1=*(const float4*)(p+4);
    u16x8 w={f2bf(v0.x),f2bf(v0.y),f2bf(v0.z),f2bf(v0.w),
             f2bf(v1.x),f2bf(v1.y),f2bf(v1.z),f2bf(v1.w)};
    *(u16x8*)&Ald[(size_t)(g*32+r)*8]=w;
  }
  __syncthreads();
  const int wv=tid>>6, lane=tid&63, l15=lane&15, l4=lane>>4;
  const int mt=wv&1, ntb=(wv>>1)*12;
  f32x4 acc[12];
  #pragma unroll
  for(int j=0;j<12;j++){ f32x4 zz={0.f,0.f,0.f,0.f}; acc[j]=zz; }
  #pragma unroll
  for(int ks=0;ks<3;ks++){
    const int g=ks*4+l4;
    bf16x8 a=*(const bf16x8*)&Ald[(size_t)(g*32+mt*16+l15)*8];
    #pragma unroll
    for(int j=0;j<12;j++){
      bf16x8 bfr=*(const bf16x8*)&Wi[((size_t)((ntb+j)*12+g)*16+l15)*8];
      acc[j]=__builtin_amdgcn_mfma_f32_16x16x32_bf16(a,bfr,acc[j],0,0,0);
    }
  }
  const int rowb=m0+mt*16+l4*4;
  #pragma unroll
  for(int j=0;j<12;j++){
    int col=(ntb+j)*16+l15;
    #pragma unroll
    for(int r=0;r<4;r++){
      int row=rowb+r; f32 v=acc[j][r];
      if(col<192) xh_raw[(size_t)row*192+col]=v;
      else        z[(size_t)row*192+(col-192)]=siluf(v);
    }
  }
}

// ---------------- Kernel B: depthwise 3x3 conv + bias + silu --------------------
__global__ __launch_bounds__(256) void k_conv(const f32* __restrict__ xh_raw, const f32* __restrict__ cw,
                                              const f32* __restrict__ cb, f32* __restrict__ xh){
  __shared__ f32 wsm[192][9];
  __shared__ f32 bsm[192];
  const int tid=threadIdx.x;
  for(int i=tid;i<1728;i+=256) wsm[i/9][i%9]=cw[i];
  for(int i=tid;i<192;i+=256) bsm[i]=cb[i];
  __syncthreads();
  const int idx=blockIdx.x*256+tid;
  const int c4=idx%48, j=(idx/48)&63, ii0=(idx/3072)&63, b=idx/196608;
  const int c0=c4*4;
  f32 acc[4]={bsm[c0],bsm[c0+1],bsm[c0+2],bsm[c0+3]};
  #pragma unroll
  for(int a=0;a<3;a++){
    int ii=ii0+a-1; if(ii<0||ii>63) continue;
    #pragma unroll
    for(int bb=0;bb<3;bb++){
      int jj=j+bb-1; if(jj<0||jj>63) continue;
      float4 v=*(const float4*)&xh_raw[((size_t)(b*4096)+(ii*64+jj))*192 + c0];
      int t=a*3+bb;
      acc[0]+=v.x*wsm[c0][t]; acc[1]+=v.y*wsm[c0+1][t];
      acc[2]+=v.z*wsm[c0+2][t]; acc[3]+=v.w*wsm[c0+3][t];
    }
  }
  float4 o; o.x=siluf(acc[0]); o.y=siluf(acc[1]); o.z=siluf(acc[2]); o.w=siluf(acc[3]);
  ((float4*)xh)[idx]=o;
}

// ---------------- Kernel C (MFMA): x_dbl = xh @ Wx^T ; also dump bf16 xh -> xhb -
// BM=32, 1024 blocks. Wave: mt=wv&1, nt strip (wv>>1)*5.
__global__ __launch_bounds__(256) void k_xdbl(const f32* __restrict__ xh, const unsigned short* __restrict__ Wfrag,
                                              const f32* __restrict__ dtb, f32* __restrict__ dt_sp,
                                              f32* __restrict__ Bg, f32* __restrict__ Cg,
                                              unsigned short* __restrict__ xhb){
  __shared__ unsigned short Ald[24*32*8];      // 12 KB
  const int m0=blockIdx.x*32;
  const int tid=threadIdx.x;
  for(int i=tid;i<768;i+=256){
    int r=i&31, g=i>>5;
    const f32* p=&xh[(size_t)(m0+r)*192 + g*8];
    float4 v0=*(const float4*)p, v1=*(const float4*)(p+4);
    u16x8 w={f2bf(v0.x),f2bf(v0.y),f2bf(v0.z),f2bf(v0.w),
             f2bf(v1.x),f2bf(v1.y),f2bf(v1.z),f2bf(v1.w)};
    *(u16x8*)&Ald[(size_t)(g*32+r)*8]=w;
    *(u16x8*)&xhb[(size_t)(m0+r)*192+g*8]=w;
  }
  __syncthreads();
  const int wv=tid>>6, lane=tid&63, l15=lane&15, l4=lane>>4;
  const int mt=wv&1, ntb=(wv>>1)*5;
  f32x4 acc[5];
  #pragma unroll
  for(int j=0;j<5;j++){ f32x4 zz={0.f,0.f,0.f,0.f}; acc[j]=zz; }
  #pragma unroll
  for(int ks=0;ks<6;ks++){
    const int g=ks*4+l4;
    bf16x8 a=*(const bf16x8*)&Ald[(size_t)(g*32 + mt*16 + l15)*8];
    #pragma unroll
    for(int j=0;j<5;j++){
      bf16x8 bfr=*(const bf16x8*)&Wfrag[((size_t)((ntb+j)*24+g)*16+l15)*8];
      acc[j]=__builtin_amdgcn_mfma_f32_16x16x32_bf16(a,bfr,acc[j],0,0,0);
    }
  }
  const int rowb=m0 + mt*16 + l4*4;
  #pragma unroll
  for(int j=0;j<5;j++){
    int n=(ntb+j)*16+l15, dir=n/40, cc=n-dir*40;
    if(cc>=38) continue;
    #pragma unroll
    for(int r=0;r<4;r++){
      size_t pix=(size_t)(rowb+r);
      f32 v=acc[j][r];
      if(cc<6){ f32 xv=v+dtb[dir*6+cc]; dt_sp[pix*24+dir*6+cc]=(xv>20.f)? xv : log1pf(__expf(xv)); }
      else if(cc<22){ Bg[(pix*4+dir)*16+(cc-6)]=v; }
      else          { Cg[(pix*4+dir)*16+(cc-22)]=v; }
    }
  }
}

// ---------------- Kernel D1 (MFMA): S_loc = e63 * (B' @ Bt^T) ------------------
#define LDK1 72
__global__ __launch_bounds__(384) void k_chunk1(const unsigned short* __restrict__ xhb, const f32* __restrict__ Bg,
      const f32* __restrict__ dt_sp, const f32* __restrict__ Alogs, f32* __restrict__ S, f32* __restrict__ ach){
  __shared__ unsigned short Bp[192*LDK1];
  __shared__ unsigned short BtT[16*LDK1];
  __shared__ f32 dtl[64][6], w1l[64][6];
  __shared__ f32 e63[6];
  const int c=blockIdx.x, dir=blockIdx.y, b=blockIdx.z, c0=c*64, tid=threadIdx.x;
  { int r=tid/6, q=tid-r*6; size_t pix=(size_t)b*4096+pos_of(dir,c0+r);
    dtl[r][q]=dt_sp[pix*24+dir*6+q]; }
  if(tid<256){
    int r=tid>>2,q=tid&3; size_t pix=(size_t)b*4096+pos_of(dir,c0+r);
    float4 bv=*(const float4*)&Bg[(pix*4+dir)*16+q*4];
    BtT[(4*q+0)*LDK1+r]=f2bf(bv.x); BtT[(4*q+1)*LDK1+r]=f2bf(bv.y);
    BtT[(4*q+2)*LDK1+r]=f2bf(bv.z); BtT[(4*q+3)*LDK1+r]=f2bf(bv.w);
  }
  __syncthreads();
  const int wv=tid>>6, lane=tid&63;
  {
    f32 A=-__expf(Alogs[dir*6+wv]);
    f32 dv=dtl[lane][wv];
    f32 v=wave_iscan(dv*A,lane);
    w1l[lane][wv]=__expf(-v)*dv;
    if(lane==63){
      f32 e=__expf(v);
      e63[wv]=e;
      ach[((size_t)(b*64+c))*24+dir*6+wv]=e;
    }
  }
  __syncthreads();
  for(int u=tid;u<768;u+=384){
    int sg=u/48, q=u-sg*48, head=q>>3;
    f32 vv[4][4];
    #pragma unroll
    for(int j=0;j<4;j++){
      int s=sg*4+j;
      u16x4 xv=*(const u16x4*)&xhb[(size_t)(b*4096+pos_of(dir,c0+s))*192+q*4];
      f32 w1=w1l[s][head];
      vv[j][0]=bfr2f(xv[0])*w1; vv[j][1]=bfr2f(xv[1])*w1;
      vv[j][2]=bfr2f(xv[2])*w1; vv[j][3]=bfr2f(xv[3])*w1;
    }
    #pragma unroll
    for(int cc=0;cc<4;cc++){
      u16x4 w={f2bf(vv[0][cc]),f2bf(vv[1][cc]),f2bf(vv[2][cc]),f2bf(vv[3][cc])};
      *(u16x4*)&Bp[(4*q+cc)*LDK1+sg*4]=w;
    }
  }
  __syncthreads();
  const int l15=lane&15, l4=lane>>4;
  f32x4 acc[2];
  { f32x4 zz={0.f,0.f,0.f,0.f}; acc[0]=zz; acc[1]=zz; }
  #pragma unroll
  for(int i=0;i<2;i++){
    int mt=wv+6*i;
    #pragma unroll
    for(int ks=0;ks<2;ks++){
      int kg=ks*4+l4;
      bf16x8 a=*(const bf16x8*)&Bp[(size_t)(mt*16+l15)*LDK1+kg*8];
      bf16x8 bb=*(const bf16x8*)&BtT[(size_t)l15*LDK1+kg*8];
      acc[i]=__builtin_amdgcn_mfma_f32_16x16x32_bf16(a,bb,acc[i],0,0,0);
    }
  }
  const size_t base=(((size_t)(b*64+c))*24+dir*6)*512;
  #pragma unroll
  for(int i=0;i<2;i++){
    int mt=wv+6*i;
    #pragma unroll
    for(int r=0;r<4;r++){
      int ch=mt*16+l4*4+r, head=ch>>5, d=ch&31;
      S[base+(size_t)head*512+d*16+l15]=acc[i][r]*e63[head];
    }
  }
}

// ---------------- Kernel D2: serial inter-chunk scan (4x unrolled prefetch) ----
__global__ __launch_bounds__(256) void k_scan(f32* __restrict__ S, const f32* __restrict__ ach){
  const int g=blockIdx.x*256+threadIdx.x;
  const int b=g/12288, rem=g%12288, h=rem/512;
  size_t base=(size_t)b*786432 + rem;
  const f32* ap=&ach[(size_t)b*1536 + h];
  f32 st=0.f;
  #pragma unroll 1
  for(int c=0;c<64;c+=4){
    f32 a0=ap[(c+0)*24], a1=ap[(c+1)*24], a2=ap[(c+2)*24], a3=ap[(c+3)*24];
    f32* p0=&S[base+(size_t)(c+0)*12288];
    f32* p1=&S[base+(size_t)(c+1)*12288];
    f32* p2=&S[base+(size_t)(c+2)*12288];
    f32* p3=&S[base+(size_t)(c+3)*12288];
    f32 s0=*p0, s1=*p1, s2=*p2, s3=*p3;
    *p0=st; st=a0*st+s0;
    *p1=st; st=a1*st+s1;
    *p2=st; st=a2*st+s2;
    *p3=st; st=a3*st+s3;
  }
}

// ---------------- Kernel D3 (MFMA, merged dirs+halves): 768 thr = 12 waves ------
#define LDK 104
__global__ __launch_bounds__(768) void k_chunk2(const f32* __restrict__ xh, const f32* __restrict__ Bg,
      const f32* __restrict__ Cg, const f32* __restrict__ dt_sp, const f32* __restrict__ Sprev,
      const f32* __restrict__ Alogs,
      f32* __restrict__ ym0, f32* __restrict__ ym1){
  __shared__ unsigned short Alds[64*LDK];   // 13.3 KB: [CBtri | Ct | 0]
  __shared__ unsigned short Blds[192*LDK];  // 39.9 KB: [x*w1 ; prevT ; 0]
  __shared__ unsigned short Btf[64*32];     // 4 KB
  __shared__ f32 w1l[2][64][6], erowl[2][64][6];  // 6 KB  (total 63.5 KB -> 2 blk/CU)
  const int c=blockIdx.x, b=blockIdx.y, pair=blockIdx.z;
  const int c0=c*64, tid=threadIdx.x;
  f32* __restrict__ ym = pair? ym1 : ym0;
  const int wv=tid>>6, lane=tid&63, l15=lane&15, l4=lane>>4;
  // upfront scans for both dirs
  {
    int ds=(wv>=6)?1:0, head=ds? wv-6 : wv;
    int dirs=pair+2*ds;
    f32 Aa=-__expf(Alogs[dirs*6+head]);
    size_t pixL=(size_t)b*4096 + (pair==0 ? (c0+lane) : (lane*64+c));
    f32 dv=dt_sp[pixL*24+dirs*6+head];
    f32 sc = ds? wave_sscan(dv*Aa,lane) : wave_iscan(dv*Aa,lane);
    w1l[ds][lane][head]=__expf(-sc)*dv;
    erowl[ds][lane][head]=__expf(sc);
  }
  f32 vsum[4][4];
  #pragma unroll
  for(int mt=0;mt<4;mt++){
    #pragma unroll
    for(int r=0;r<4;r++) vsum[mt][r]=0.f;
  }
  const int gch=wv*16+l15, ohead=gch>>5;
  #pragma unroll
  for(int d=0;d<2;d++){
    const int dir=pair+d*2;
    const int cd=d? (63-c) : c;
    if(d) __syncthreads();
    if(tid<256){
      int r=tid>>2,q=tid&3;
      size_t pix=(size_t)b*4096 + (pair==0 ? (c0+r) : (r*64+c));
      float4 bv=*(const float4*)&Bg[(pix*4+dir)*16+q*4];
      float4 cv=*(const float4*)&Cg[(pix*4+dir)*16+q*4];
      u16x4 wb={f2bf(bv.x),f2bf(bv.y),f2bf(bv.z),f2bf(bv.w)};
      u16x4 wc={f2bf(cv.x),f2bf(cv.y),f2bf(cv.z),f2bf(cv.w)};
      u16x4 zz={0,0,0,0};
      *(u16x4*)&Btf[r*32+q*4]=wb;      *(u16x4*)&Btf[r*32+16+q*4]=zz;
      *(u16x4*)&Alds[r*LDK+64+q*4]=wc; *(u16x4*)&Alds[r*LDK+80+q*4]=zz;
    }
    {
      const size_t pbase=(((size_t)(b*64+cd))*24+dir*6)*512;
      int lr=tid>>2, ng=tid&3, hh=lr>>5, dd=lr&31;
      float4 pv=*(const float4*)&Sprev[pbase+(size_t)hh*512+dd*16+ng*4];
      u16x4 w={f2bf(pv.x),f2bf(pv.y),f2bf(pv.z),f2bf(pv.w)};
      u16x4 zz={0,0,0,0};
      *(u16x4*)&Blds[lr*LDK+64+ng*4]=w;
      *(u16x4*)&Blds[lr*LDK+80+ng*4]=zz;
    }
    __syncthreads();
    #pragma unroll
    for(int tt=0;tt<2;tt++){
      int tile=wv+12*tt;
      if(tile<16){
        int mt=tile>>2, nt=tile&3;
        f32x4 a4={0.f,0.f,0.f,0.f};
        bf16x8 af=*(const bf16x8*)&Alds[(mt*16+l15)*LDK+64+l4*8];
        bf16x8 bfr=*(const bf16x8*)&Btf[(nt*16+l15)*32+l4*8];
        a4=__builtin_amdgcn_mfma_f32_16x16x32_bf16(af,bfr,a4,0,0,0);
        #pragma unroll
        for(int r=0;r<4;r++){
          int t=mt*16+l4*4+r, s=nt*16+l15;
          bool keep = d? (s>=t) : (s<=t);
          Alds[t*LDK+s]= keep? f2bf(a4[r]) : (unsigned short)0;
        }
      }
    }
    {
      int sg=tid/48, q=tid-sg*48;
      int head=q>>3;
      f32 vv[4][4];
      #pragma unroll
      for(int j=0;j<4;j++){
        int s=sg*4+j;
        size_t pix=(size_t)b*4096 + (pair==0 ? (c0+s) : (s*64+c));
        float4 xv=*(const float4*)&xh[pix*192 + q*4];
        f32 w1=w1l[d][s][head];
        vv[j][0]=xv.x*w1; vv[j][1]=xv.y*w1; vv[j][2]=xv.z*w1; vv[j][3]=xv.w*w1;
      }
      #pragma unroll
      for(int cc=0;cc<4;cc++){
        u16x4 w={f2bf(vv[0][cc]),f2bf(vv[1][cc]),f2bf(vv[2][cc]),f2bf(vv[3][cc])};
        *(u16x4*)&Blds[(4*q+cc)*LDK+sg*4]=w;
      }
    }
    __syncthreads();
    f32x4 acc[4];
    #pragma unroll
    for(int mt=0;mt<4;mt++){ f32x4 zz={0.f,0.f,0.f,0.f}; acc[mt]=zz; }
    #pragma unroll
    for(int ks=0;ks<3;ks++){
      const int kg=ks*4+l4;
      bf16x8 bfr=*(const bf16x8*)&Blds[(wv*16+l15)*LDK+kg*8];
      #pragma unroll
      for(int mt=0;mt<4;mt++){
        bf16x8 af=*(const bf16x8*)&Alds[(mt*16+l15)*LDK+kg*8];
        acc[mt]=__builtin_amdgcn_mfma_f32_16x16x32_bf16(af,bfr,acc[mt],0,0,0);
      }
    }
    #pragma unroll
    for(int mt=0;mt<4;mt++){
      #pragma unroll
      for(int r=0;r<4;r++){
        int t=mt*16+l4*4+r;
        vsum[mt][r]+=acc[mt][r]*erowl[d][t][ohead];
      }
    }
  }
  #pragma unroll
  for(int mt=0;mt<4;mt++){
    #pragma unroll
    for(int r=0;r<4;r++){
      int t=mt*16+l4*4+r;
      size_t pix=(size_t)b*4096 + (pair==0 ? (c0+t) : (t*64+c));
      ym[pix*192+gch]=vsum[mt][r];
    }
  }
}

// ---------------- Kernel F (MFMA): out = LN(ym0+ym1+x*Dsum)*z @ Wo^T -----------
__global__ __launch_bounds__(256) void k_outproj(const f32* __restrict__ ym0, const f32* __restrict__ ym1,
                                                 const f32* __restrict__ xh, const f32* __restrict__ Dsum,
                                                 const f32* __restrict__ z,
                                                 const f32* __restrict__ lw, const f32* __restrict__ lb,
                                                 const unsigned short* __restrict__ Wo, f32* __restrict__ out){
  __shared__ unsigned short Ald[24*64*8];      // 24 KB
  __shared__ f32 lws[192], lbs[192], dss[192];
  const int m0=blockIdx.x*64, tid=threadIdx.x;
  for(int i=tid;i<192;i+=256){ lws[i]=lw[i]; lbs[i]=lb[i]; dss[i]=Dsum[i]; }
  __syncthreads();
  const int r=tid>>2, sub=tid&3;
  const size_t base=(size_t)(m0+r)*192 + sub*48;
  f32 y[48];
  f32 s=0.f;
  #pragma unroll
  for(int j=0;j<48;j+=4){
    float4 a=*(const float4*)&ym0[base+j];
    float4 bb=*(const float4*)&ym1[base+j];
    float4 xv=*(const float4*)&xh[base+j];
    int col=sub*48+j;
    y[j]  =a.x+bb.x+xv.x*dss[col];
    y[j+1]=a.y+bb.y+xv.y*dss[col+1];
    y[j+2]=a.z+bb.z+xv.z*dss[col+2];
    y[j+3]=a.w+bb.w+xv.w*dss[col+3];
    s+=y[j]+y[j+1]+y[j+2]+y[j+3];
  }
  s+=__shfl_xor(s,1,64); s+=__shfl_xor(s,2,64);
  const f32 mu=s*(1.f/192.f);
  f32 q=0.f;
  #pragma unroll
  for(int j=0;j<48;j++){ f32 dd=y[j]-mu; q+=dd*dd; }
  q+=__shfl_xor(q,1,64); q+=__shfl_xor(q,2,64);
  const f32 rs=rsqrtf(q*(1.f/192.f)+1e-5f);
  #pragma unroll
  for(int j=0;j<48;j+=8){
    float4 z0=*(const float4*)&z[base+j];
    float4 z1=*(const float4*)&z[base+j+4];
    int col=sub*48+j;
    u16x8 w;
    w[0]=f2bf(((y[j+0]-mu)*rs*lws[col+0]+lbs[col+0])*z0.x);
    w[1]=f2bf(((y[j+1]-mu)*rs*lws[col+1]+lbs[col+1])*z0.y);
    w[2]=f2bf(((y[j+2]-mu)*rs*lws[col+2]+lbs[col+2])*z0.z);
    w[3]=f2bf(((y[j+3]-mu)*rs*lws[col+3]+lbs[col+3])*z0.w);
    w[4]=f2bf(((y[j+4]-mu)*rs*lws[col+4]+lbs[col+4])*z1.x);
    w[5]=f2bf(((y[j+5]-mu)*rs*lws[col+5]+lbs[col+5])*z1.y);
    w[6]=f2bf(((y[j+6]-mu)*rs*lws[col+6]+lbs[col+6])*z1.z);
    w[7]=f2bf(((y[j+7]-mu)*rs*lws[col+7]+lbs[col+7])*z1.w);
    int g=col>>3;
    *(u16x8*)&Ald[((size_t)g*64+r)*8]=w;
  }
  __syncthreads();
  const int wv=tid>>6, lane=tid&63, l15=lane&15, l4=lane>>4;
  f32x4 acc[6];
  #pragma unroll
  for(int nt=0;nt<6;nt++){ f32x4 zz={0.f,0.f,0.f,0.f}; acc[nt]=zz; }
  #pragma unroll
  for(int ks=0;ks<6;ks++){
    const int g=ks*4+l4;
    bf16x8 a=*(const bf16x8*)&Ald[(size_t)(g*64+wv*16+l15)*8];
    #pragma unroll
    for(int nt=0;nt<6;nt++){
      bf16x8 bfr=*(const bf16x8*)&Wo[((size_t)(nt*24+g)*16+l15)*8];
      acc[nt]=__builtin_amdgcn_mfma_f32_16x16x32_bf16(a,bfr,acc[nt],0,0,0);
    }
  }
  const int rowb=m0+wv*16+l4*4;
  #pragma unroll
  for(int nt=0;nt<6;nt++){
    int col=nt*16+l15;
    #pragma unroll
    for(int r2=0;r2<4;r2++){
      out[(size_t)(rowb+r2)*96+col]=acc[nt][r2];
    }
  }
}

extern "C" void kernel_launch(void* const* d_in, const int* in_sizes, int n_in,
                              void* d_out, int out_size, void* d_ws, size_t ws_size,
                              hipStream_t stream){
  const f32* x  =(const f32*)d_in[0];
  const f32* ipw=(const f32*)d_in[1];
  const f32* cw =(const f32*)d_in[2];
  const f32* cb =(const f32*)d_in[3];
  const f32* xpw=(const f32*)d_in[4];
  const f32* alg=(const f32*)d_in[5];
  const f32* dsw=(const f32*)d_in[6];
  const f32* dtb=(const f32*)d_in[7];
  const f32* lw =(const f32*)d_in[8];
  const f32* lb =(const f32*)d_in[9];
  const f32* opw=(const f32*)d_in[10];
  f32* out=(f32*)d_out;
  f32* ws=(f32*)d_ws;

  f32* xh_raw=ws;               // 6291456 floats (reused as ym0)
  f32* z     =ws+ 6291456;      // 6291456
  f32* xh    =ws+12582912;      // 6291456
  f32* dt_sp =ws+18874368;      //  786432
  f32* Bg    =ws+19660800;      // 2097152
  f32* Cg    =ws+21757952;      // 2097152
  f32* S     =ws+23855104;      // 6291456
  f32* ach   =ws+30146560;      //   12288
  f32* ym1   =ws+30158848;      // 6291456 (first half doubles as xhb pre-chunk2)
  unsigned short* Wx=(unsigned short*)(ws+36450304);
  unsigned short* Wi=(unsigned short*)(ws+36465664);
  unsigned short* Wo=(unsigned short*)(ws+36484096);
  f32* Dsum  =ws+36493312;      //     192
  f32* ym0=xh_raw;
  unsigned short* xhb=(unsigned short*)ym1;   // 6291456 u16 = 12.6 MB, dead until chunk2

  k_wcvt_all<<<43,256,0,stream>>>(xpw,ipw,opw,dsw,Wx,Wi,Wo,Dsum);
  k_inproj<<<1024,256,0,stream>>>(x,Wi,xh_raw,z);
  k_conv<<<6144,256,0,stream>>>(xh_raw,cw,cb,xh);
  k_xdbl<<<1024,256,0,stream>>>(xh,Wx,dtb,dt_sp,Bg,Cg,xhb);
  k_chunk1<<<dim3(64,4,8),384,0,stream>>>(xhb,Bg,dt_sp,alg,S,ach);
  k_scan<<<384,256,0,stream>>>(S,ach);
  k_chunk2<<<dim3(64,8,2),768,0,stream>>>(xh,Bg,Cg,dt_sp,S,alg,ym0,ym1);
  k_outproj<<<512,256,0,stream>>>(ym0,ym1,xh,Dsum,z,lw,lb,Wo,out);
}

// Round 15
// 171.690 us; speedup vs baseline: 3.3218x; 1.0360x over previous
//
#include <hip/hip_runtime.h>
#include <hip/hip_bf16.h>

using bf16 = __hip_bfloat16;
typedef float f32;
typedef __attribute__((ext_vector_type(8))) short bf16x8;
typedef __attribute__((ext_vector_type(4))) float f32x4;
typedef __attribute__((ext_vector_type(4))) unsigned short u16x4;
typedef __attribute__((ext_vector_type(8))) unsigned short u16x8;

static __device__ __forceinline__ f32 siluf(f32 v){ return v / (1.f + __expf(-v)); }
static __device__ __forceinline__ unsigned short f2bf(f32 v){
  __hip_bfloat16 h=__float2bfloat16(v); return *(unsigned short*)&h;
}
static __device__ __forceinline__ f32 bfr2f(unsigned short u){
  unsigned int x=((unsigned int)u)<<16; return __uint_as_float(x);
}

// spatial position of sequence index p for scan direction dir (H=W=64, L=4096)
static __device__ __forceinline__ int pos_of(int dir, int p){
  if(dir==0) return p;
  if(dir==1) return ((p&63)<<6) | (p>>6);
  if(dir==2) return 4095-p;
  int q = 4095-p; return ((q&63)<<6) | (q>>6);
}

// inclusive wave-64 prefix scan
static __device__ __forceinline__ f32 wave_iscan(f32 v, int lane){
  #pragma unroll
  for(int off=1; off<64; off<<=1){
    f32 u=__shfl_up(v,off,64);
    if(lane>=off) v+=u;
  }
  return v;
}
// inclusive wave-64 suffix scan (v[lane] = sum_{j>=lane})
static __device__ __forceinline__ f32 wave_sscan(f32 v, int lane){
  #pragma unroll
  for(int off=1; off<64; off<<=1){
    f32 u=__shfl_down(v,off,64);
    if(lane<64-off) v+=u;
  }
  return v;
}

// ---------------- Kernel W: weights -> bf16 fragment layout + Dsum -------------
__global__ __launch_bounds__(256) void k_wcvt_all(const f32* __restrict__ xpw, const f32* __restrict__ ipw,
                                                  const f32* __restrict__ opw, const f32* __restrict__ dsw,
                                                  unsigned short* __restrict__ Wx, unsigned short* __restrict__ Wi,
                                                  unsigned short* __restrict__ Wo, f32* __restrict__ Dsum){
  const int t=blockIdx.x*256+threadIdx.x;
  if(t<3840){
    const int g=t%24, n=t/24, nt=n>>4, l=n&15;
    const int dir=n/40, cc=n-dir*40;
    u16x8 w={0,0,0,0,0,0,0,0};
    if(cc<38){
      const f32* p=&xpw[(size_t)dir*7296+cc*192+g*8];
      #pragma unroll
      for(int j=0;j<8;j++) w[j]=f2bf(p[j]);
    }
    *(u16x8*)&Wx[((size_t)(nt*24+g)*16+l)*8]=w;
  } else if(t<8448){
    const int i=t-3840, g=i%12, n=i/12, nt=n>>4, l=n&15;
    const f32* p=&ipw[(size_t)n*96+g*8];
    u16x8 w;
    #pragma unroll
    for(int j=0;j<8;j++) w[j]=f2bf(p[j]);
    *(u16x8*)&Wi[((size_t)(nt*12+g)*16+l)*8]=w;
  } else if(t<10752){
    const int i=t-8448, g=i%24, n=i/24, nt=n>>4, l=n&15;
    const f32* p=&opw[(size_t)n*192+g*8];
    u16x8 w;
    #pragma unroll
    for(int j=0;j<8;j++) w[j]=f2bf(p[j]);
    *(u16x8*)&Wo[((size_t)(nt*24+g)*16+l)*8]=w;
  } else if(t<10944){
    const int ch=t-10752;
    Dsum[ch]=dsw[ch]+dsw[192+ch]+dsw[384+ch]+dsw[576+ch];
  }
}

// ---------------- Kernel A (MFMA): xz = x @ in_proj_w.T ; split, silu ----------
// BM=32, 1024 blocks (4 blk/CU). Wave: mt=wv&1, nt strip (wv>>1)*12.
__global__ __launch_bounds__(256) void k_inproj(const f32* __restrict__ x, const unsigned short* __restrict__ Wi,
                                                f32* __restrict__ xh_raw, f32* __restrict__ z){
  __shared__ unsigned short Ald[12*32*8];      // 6 KB
  const int m0=blockIdx.x*32, tid=threadIdx.x;
  for(int i=tid;i<384;i+=256){
    int r=i&31, g=i>>5;
    const f32* p=&x[(size_t)(m0+r)*96+g*8];
    float4 v0=*(const float4*)p, v1=*(const float4*)(p+4);
    u16x8 w={f2bf(v0.x),f2bf(v0.y),f2bf(v0.z),f2bf(v0.w),
             f2bf(v1.x),f2bf(v1.y),f2bf(v1.z),f2bf(v1.w)};
    *(u16x8*)&Ald[(size_t)(g*32+r)*8]=w;
  }
  __syncthreads();
  const int wv=tid>>6, lane=tid&63, l15=lane&15, l4=lane>>4;
  const int mt=wv&1, ntb=(wv>>1)*12;
  f32x4 acc[12];
  #pragma unroll
  for(int j=0;j<12;j++){ f32x4 zz={0.f,0.f,0.f,0.f}; acc[j]=zz; }
  #pragma unroll
  for(int ks=0;ks<3;ks++){
    const int g=ks*4+l4;
    bf16x8 a=*(const bf16x8*)&Ald[(size_t)(g*32+mt*16+l15)*8];
    #pragma unroll
    for(int j=0;j<12;j++){
      bf16x8 bfr=*(const bf16x8*)&Wi[((size_t)((ntb+j)*12+g)*16+l15)*8];
      acc[j]=__builtin_amdgcn_mfma_f32_16x16x32_bf16(a,bfr,acc[j],0,0,0);
    }
  }
  const int rowb=m0+mt*16+l4*4;
  #pragma unroll
  for(int j=0;j<12;j++){
    int col=(ntb+j)*16+l15;
    #pragma unroll
    for(int r=0;r<4;r++){
      int row=rowb+r; f32 v=acc[j][r];
      if(col<192) xh_raw[(size_t)row*192+col]=v;
      else        z[(size_t)row*192+(col-192)]=siluf(v);
    }
  }
}

// ---------------- Kernel B: depthwise 3x3 conv + bias + silu -> xh (f32) + xhb --
__global__ __launch_bounds__(256) void k_conv(const f32* __restrict__ xh_raw, const f32* __restrict__ cw,
                                              const f32* __restrict__ cb, f32* __restrict__ xh,
                                              unsigned short* __restrict__ xhb){
  __shared__ f32 wsm[192][9];
  __shared__ f32 bsm[192];
  const int tid=threadIdx.x;
  for(int i=tid;i<1728;i+=256) wsm[i/9][i%9]=cw[i];
  for(int i=tid;i<192;i+=256) bsm[i]=cb[i];
  __syncthreads();
  const int idx=blockIdx.x*256+tid;
  const int c4=idx%48, j=(idx/48)&63, ii0=(idx/3072)&63, b=idx/196608;
  const int c0=c4*4;
  f32 acc[4]={bsm[c0],bsm[c0+1],bsm[c0+2],bsm[c0+3]};
  #pragma unroll
  for(int a=0;a<3;a++){
    int ii=ii0+a-1; if(ii<0||ii>63) continue;
    #pragma unroll
    for(int bb=0;bb<3;bb++){
      int jj=j+bb-1; if(jj<0||jj>63) continue;
      float4 v=*(const float4*)&xh_raw[((size_t)(b*4096)+(ii*64+jj))*192 + c0];
      int t=a*3+bb;
      acc[0]+=v.x*wsm[c0][t]; acc[1]+=v.y*wsm[c0+1][t];
      acc[2]+=v.z*wsm[c0+2][t]; acc[3]+=v.w*wsm[c0+3][t];
    }
  }
  float4 o; o.x=siluf(acc[0]); o.y=siluf(acc[1]); o.z=siluf(acc[2]); o.w=siluf(acc[3]);
  ((float4*)xh)[idx]=o;
  u16x4 w={f2bf(o.x),f2bf(o.y),f2bf(o.z),f2bf(o.w)};
  *(u16x4*)&xhb[(size_t)idx*4]=w;
}

// ---------------- Kernel C (MFMA): x_dbl = xhb @ Wx^T -> dt(softplus), B, C ----
// BM=32, 1024 blocks. Staging = pure bf16 copy from xhb.
__global__ __launch_bounds__(256) void k_xdbl(const unsigned short* __restrict__ xhb,
                                              const unsigned short* __restrict__ Wfrag,
                                              const f32* __restrict__ dtb, f32* __restrict__ dt_sp,
                                              f32* __restrict__ Bg, f32* __restrict__ Cg){
  __shared__ unsigned short Ald[24*32*8];      // 12 KB
  const int m0=blockIdx.x*32;
  const int tid=threadIdx.x;
  for(int i=tid;i<768;i+=256){
    int r=i&31, g=i>>5;
    u16x8 w=*(const u16x8*)&xhb[(size_t)(m0+r)*192+g*8];
    *(u16x8*)&Ald[(size_t)(g*32+r)*8]=w;
  }
  __syncthreads();
  const int wv=tid>>6, lane=tid&63, l15=lane&15, l4=lane>>4;
  const int mt=wv&1, ntb=(wv>>1)*5;
  f32x4 acc[5];
  #pragma unroll
  for(int j=0;j<5;j++){ f32x4 zz={0.f,0.f,0.f,0.f}; acc[j]=zz; }
  #pragma unroll
  for(int ks=0;ks<6;ks++){
    const int g=ks*4+l4;
    bf16x8 a=*(const bf16x8*)&Ald[(size_t)(g*32 + mt*16 + l15)*8];
    #pragma unroll
    for(int j=0;j<5;j++){
      bf16x8 bfr=*(const bf16x8*)&Wfrag[((size_t)((ntb+j)*24+g)*16+l15)*8];
      acc[j]=__builtin_amdgcn_mfma_f32_16x16x32_bf16(a,bfr,acc[j],0,0,0);
    }
  }
  const int rowb=m0 + mt*16 + l4*4;
  #pragma unroll
  for(int j=0;j<5;j++){
    int n=(ntb+j)*16+l15, dir=n/40, cc=n-dir*40;
    if(cc>=38) continue;
    #pragma unroll
    for(int r=0;r<4;r++){
      size_t pix=(size_t)(rowb+r);
      f32 v=acc[j][r];
      if(cc<6){ f32 xv=v+dtb[dir*6+cc]; dt_sp[pix*24+dir*6+cc]=(xv>20.f)? xv : log1pf(__expf(xv)); }
      else if(cc<22){ Bg[(pix*4+dir)*16+(cc-6)]=v; }
      else          { Cg[(pix*4+dir)*16+(cc-22)]=v; }
    }
  }
}

// ---------------- Kernel D1 (MFMA): S_loc = e63 * (B' @ Bt^T) ------------------
#define LDK1 72
__global__ __launch_bounds__(384) void k_chunk1(const unsigned short* __restrict__ xhb, const f32* __restrict__ Bg,
      const f32* __restrict__ dt_sp, const f32* __restrict__ Alogs, f32* __restrict__ S, f32* __restrict__ ach){
  __shared__ unsigned short Bp[192*LDK1];
  __shared__ unsigned short BtT[16*LDK1];
  __shared__ f32 dtl[64][6], w1l[64][6];
  __shared__ f32 e63[6];
  const int c=blockIdx.x, dir=blockIdx.y, b=blockIdx.z, c0=c*64, tid=threadIdx.x;
  { int r=tid/6, q=tid-r*6; size_t pix=(size_t)b*4096+pos_of(dir,c0+r);
    dtl[r][q]=dt_sp[pix*24+dir*6+q]; }
  if(tid<256){
    int r=tid>>2,q=tid&3; size_t pix=(size_t)b*4096+pos_of(dir,c0+r);
    float4 bv=*(const float4*)&Bg[(pix*4+dir)*16+q*4];
    BtT[(4*q+0)*LDK1+r]=f2bf(bv.x); BtT[(4*q+1)*LDK1+r]=f2bf(bv.y);
    BtT[(4*q+2)*LDK1+r]=f2bf(bv.z); BtT[(4*q+3)*LDK1+r]=f2bf(bv.w);
  }
  __syncthreads();
  const int wv=tid>>6, lane=tid&63;
  {
    f32 A=-__expf(Alogs[dir*6+wv]);
    f32 dv=dtl[lane][wv];
    f32 v=wave_iscan(dv*A,lane);
    w1l[lane][wv]=__expf(-v)*dv;
    if(lane==63){
      f32 e=__expf(v);
      e63[wv]=e;
      ach[((size_t)(b*64+c))*24+dir*6+wv]=e;
    }
  }
  __syncthreads();
  for(int u=tid;u<768;u+=384){
    int sg=u/48, q=u-sg*48, head=q>>3;
    f32 vv[4][4];
    #pragma unroll
    for(int j=0;j<4;j++){
      int s=sg*4+j;
      u16x4 xv=*(const u16x4*)&xhb[(size_t)(b*4096+pos_of(dir,c0+s))*192+q*4];
      f32 w1=w1l[s][head];
      vv[j][0]=bfr2f(xv[0])*w1; vv[j][1]=bfr2f(xv[1])*w1;
      vv[j][2]=bfr2f(xv[2])*w1; vv[j][3]=bfr2f(xv[3])*w1;
    }
    #pragma unroll
    for(int cc=0;cc<4;cc++){
      u16x4 w={f2bf(vv[0][cc]),f2bf(vv[1][cc]),f2bf(vv[2][cc]),f2bf(vv[3][cc])};
      *(u16x4*)&Bp[(4*q+cc)*LDK1+sg*4]=w;
    }
  }
  __syncthreads();
  const int l15=lane&15, l4=lane>>4;
  f32x4 acc[2];
  { f32x4 zz={0.f,0.f,0.f,0.f}; acc[0]=zz; acc[1]=zz; }
  #pragma unroll
  for(int i=0;i<2;i++){
    int mt=wv+6*i;
    #pragma unroll
    for(int ks=0;ks<2;ks++){
      int kg=ks*4+l4;
      bf16x8 a=*(const bf16x8*)&Bp[(size_t)(mt*16+l15)*LDK1+kg*8];
      bf16x8 bb=*(const bf16x8*)&BtT[(size_t)l15*LDK1+kg*8];
      acc[i]=__builtin_amdgcn_mfma_f32_16x16x32_bf16(a,bb,acc[i],0,0,0);
    }
  }
  const size_t base=(((size_t)(b*64+c))*24+dir*6)*512;
  #pragma unroll
  for(int i=0;i<2;i++){
    int mt=wv+6*i;
    #pragma unroll
    for(int r=0;r<4;r++){
      int ch=mt*16+l4*4+r, head=ch>>5, d=ch&31;
      S[base+(size_t)head*512+d*16+l15]=acc[i][r]*e63[head];
    }
  }
}

// ---------------- Kernel D2: serial inter-chunk scan (4x unrolled prefetch) ----
__global__ __launch_bounds__(256) void k_scan(f32* __restrict__ S, const f32* __restrict__ ach){
  const int g=blockIdx.x*256+threadIdx.x;
  const int b=g/12288, rem=g%12288, h=rem/512;
  size_t base=(size_t)b*786432 + rem;
  const f32* ap=&ach[(size_t)b*1536 + h];
  f32 st=0.f;
  #pragma unroll 1
  for(int c=0;c<64;c+=4){
    f32 a0=ap[(c+0)*24], a1=ap[(c+1)*24], a2=ap[(c+2)*24], a3=ap[(c+3)*24];
    f32* p0=&S[base+(size_t)(c+0)*12288];
    f32* p1=&S[base+(size_t)(c+1)*12288];
    f32* p2=&S[base+(size_t)(c+2)*12288];
    f32* p3=&S[base+(size_t)(c+3)*12288];
    f32 s0=*p0, s1=*p1, s2=*p2, s3=*p3;
    *p0=st; st=a0*st+s0;
    *p1=st; st=a1*st+s1;
    *p2=st; st=a2*st+s2;
    *p3=st; st=a3*st+s3;
  }
}

// ---------------- Kernel D3 (MFMA, merged dirs+halves): 768 thr = 12 waves ------
#define LDK 104
__global__ __launch_bounds__(768) void k_chunk2(const unsigned short* __restrict__ xhb, const f32* __restrict__ Bg,
      const f32* __restrict__ Cg, const f32* __restrict__ dt_sp, const f32* __restrict__ Sprev,
      const f32* __restrict__ Alogs,
      f32* __restrict__ ym0, f32* __restrict__ ym1){
  __shared__ unsigned short Alds[64*LDK];   // 13.3 KB: [CBtri | Ct | 0]
  __shared__ unsigned short Blds[192*LDK];  // 39.9 KB: [x*w1 ; prevT ; 0]
  __shared__ unsigned short Btf[64*32];     // 4 KB
  __shared__ f32 w1l[2][64][6], erowl[2][64][6];  // 6 KB  (total 63.5 KB -> 2 blk/CU)
  const int c=blockIdx.x, b=blockIdx.y, pair=blockIdx.z;
  const int c0=c*64, tid=threadIdx.x;
  f32* __restrict__ ym = pair? ym1 : ym0;
  const int wv=tid>>6, lane=tid&63, l15=lane&15, l4=lane>>4;
  // upfront scans for both dirs
  {
    int ds=(wv>=6)?1:0, head=ds? wv-6 : wv;
    int dirs=pair+2*ds;
    f32 Aa=-__expf(Alogs[dirs*6+head]);
    size_t pixL=(size_t)b*4096 + (pair==0 ? (c0+lane) : (lane*64+c));
    f32 dv=dt_sp[pixL*24+dirs*6+head];
    f32 sc = ds? wave_sscan(dv*Aa,lane) : wave_iscan(dv*Aa,lane);
    w1l[ds][lane][head]=__expf(-sc)*dv;
    erowl[ds][lane][head]=__expf(sc);
  }
  f32 vsum[4][4];
  #pragma unroll
  for(int mt=0;mt<4;mt++){
    #pragma unroll
    for(int r=0;r<4;r++) vsum[mt][r]=0.f;
  }
  const int gch=wv*16+l15, ohead=gch>>5;
  #pragma unroll
  for(int d=0;d<2;d++){
    const int dir=pair+d*2;
    const int cd=d? (63-c) : c;
    if(d) __syncthreads();
    if(tid<256){
      int r=tid>>2,q=tid&3;
      size_t pix=(size_t)b*4096 + (pair==0 ? (c0+r) : (r*64+c));
      float4 bv=*(const float4*)&Bg[(pix*4+dir)*16+q*4];
      float4 cv=*(const float4*)&Cg[(pix*4+dir)*16+q*4];
      u16x4 wb={f2bf(bv.x),f2bf(bv.y),f2bf(bv.z),f2bf(bv.w)};
      u16x4 wc={f2bf(cv.x),f2bf(cv.y),f2bf(cv.z),f2bf(cv.w)};
      u16x4 zz={0,0,0,0};
      *(u16x4*)&Btf[r*32+q*4]=wb;      *(u16x4*)&Btf[r*32+16+q*4]=zz;
      *(u16x4*)&Alds[r*LDK+64+q*4]=wc; *(u16x4*)&Alds[r*LDK+80+q*4]=zz;
    }
    {
      const size_t pbase=(((size_t)(b*64+cd))*24+dir*6)*512;
      int lr=tid>>2, ng=tid&3, hh=lr>>5, dd=lr&31;
      float4 pv=*(const float4*)&Sprev[pbase+(size_t)hh*512+dd*16+ng*4];
      u16x4 w={f2bf(pv.x),f2bf(pv.y),f2bf(pv.z),f2bf(pv.w)};
      u16x4 zz={0,0,0,0};
      *(u16x4*)&Blds[lr*LDK+64+ng*4]=w;
      *(u16x4*)&Blds[lr*LDK+80+ng*4]=zz;
    }
    __syncthreads();
    #pragma unroll
    for(int tt=0;tt<2;tt++){
      int tile=wv+12*tt;
      if(tile<16){
        int mt=tile>>2, nt=tile&3;
        f32x4 a4={0.f,0.f,0.f,0.f};
        bf16x8 af=*(const bf16x8*)&Alds[(mt*16+l15)*LDK+64+l4*8];
        bf16x8 bfr=*(const bf16x8*)&Btf[(nt*16+l15)*32+l4*8];
        a4=__builtin_amdgcn_mfma_f32_16x16x32_bf16(af,bfr,a4,0,0,0);
        #pragma unroll
        for(int r=0;r<4;r++){
          int t=mt*16+l4*4+r, s=nt*16+l15;
          bool keep = d? (s>=t) : (s<=t);
          Alds[t*LDK+s]= keep? f2bf(a4[r]) : (unsigned short)0;
        }
      }
    }
    {
      int sg=tid/48, q=tid-sg*48;
      int head=q>>3;
      f32 vv[4][4];
      #pragma unroll
      for(int j=0;j<4;j++){
        int s=sg*4+j;
        size_t pix=(size_t)b*4096 + (pair==0 ? (c0+s) : (s*64+c));
        u16x4 xv=*(const u16x4*)&xhb[pix*192 + q*4];
        f32 w1=w1l[d][s][head];
        vv[j][0]=bfr2f(xv[0])*w1; vv[j][1]=bfr2f(xv[1])*w1;
        vv[j][2]=bfr2f(xv[2])*w1; vv[j][3]=bfr2f(xv[3])*w1;
      }
      #pragma unroll
      for(int cc=0;cc<4;cc++){
        u16x4 w={f2bf(vv[0][cc]),f2bf(vv[1][cc]),f2bf(vv[2][cc]),f2bf(vv[3][cc])};
        *(u16x4*)&Blds[(4*q+cc)*LDK+sg*4]=w;
      }
    }
    __syncthreads();
    f32x4 acc[4];
    #pragma unroll
    for(int mt=0;mt<4;mt++){ f32x4 zz={0.f,0.f,0.f,0.f}; acc[mt]=zz; }
    #pragma unroll
    for(int ks=0;ks<3;ks++){
      const int kg=ks*4+l4;
      bf16x8 bfr=*(const bf16x8*)&Blds[(wv*16+l15)*LDK+kg*8];
      #pragma unroll
      for(int mt=0;mt<4;mt++){
        bf16x8 af=*(const bf16x8*)&Alds[(mt*16+l15)*LDK+kg*8];
        acc[mt]=__builtin_amdgcn_mfma_f32_16x16x32_bf16(af,bfr,acc[mt],0,0,0);
      }
    }
    #pragma unroll
    for(int mt=0;mt<4;mt++){
      #pragma unroll
      for(int r=0;r<4;r++){
        int t=mt*16+l4*4+r;
        vsum[mt][r]+=acc[mt][r]*erowl[d][t][ohead];
      }
    }
  }
  #pragma unroll
  for(int mt=0;mt<4;mt++){
    #pragma unroll
    for(int r=0;r<4;r++){
      int t=mt*16+l4*4+r;
      size_t pix=(size_t)b*4096 + (pair==0 ? (c0+t) : (t*64+c));
      ym[pix*192+gch]=vsum[mt][r];
    }
  }
}

// ---------------- Kernel F (MFMA): out = LN(ym0+ym1+x*Dsum)*z @ Wo^T -----------
__global__ __launch_bounds__(256) void k_outproj(const f32* __restrict__ ym0, const f32* __restrict__ ym1,
                                                 const f32* __restrict__ xh, const f32* __restrict__ Dsum,
                                                 const f32* __restrict__ z,
                                                 const f32* __restrict__ lw, const f32* __restrict__ lb,
                                                 const unsigned short* __restrict__ Wo, f32* __restrict__ out){
  __shared__ unsigned short Ald[24*64*8];      // 24 KB
  __shared__ f32 lws[192], lbs[192], dss[192];
  const int m0=blockIdx.x*64, tid=threadIdx.x;
  for(int i=tid;i<192;i+=256){ lws[i]=lw[i]; lbs[i]=lb[i]; dss[i]=Dsum[i]; }
  __syncthreads();
  const int r=tid>>2, sub=tid&3;
  const size_t base=(size_t)(m0+r)*192 + sub*48;
  f32 y[48];
  f32 s=0.f;
  #pragma unroll
  for(int j=0;j<48;j+=4){
    float4 a=*(const float4*)&ym0[base+j];
    float4 bb=*(const float4*)&ym1[base+j];
    float4 xv=*(const float4*)&xh[base+j];
    int col=sub*48+j;
    y[j]  =a.x+bb.x+xv.x*dss[col];
    y[j+1]=a.y+bb.y+xv.y*dss[col+1];
    y[j+2]=a.z+bb.z+xv.z*dss[col+2];
    y[j+3]=a.w+bb.w+xv.w*dss[col+3];
    s+=y[j]+y[j+1]+y[j+2]+y[j+3];
  }
  s+=__shfl_xor(s,1,64); s+=__shfl_xor(s,2,64);
  const f32 mu=s*(1.f/192.f);
  f32 q=0.f;
  #pragma unroll
  for(int j=0;j<48;j++){ f32 dd=y[j]-mu; q+=dd*dd; }
  q+=__shfl_xor(q,1,64); q+=__shfl_xor(q,2,64);
  const f32 rs=rsqrtf(q*(1.f/192.f)+1e-5f);
  #pragma unroll
  for(int j=0;j<48;j+=8){
    float4 z0=*(const float4*)&z[base+j];
    float4 z1=*(const float4*)&z[base+j+4];
    int col=sub*48+j;
    u16x8 w;
    w[0]=f2bf(((y[j+0]-mu)*rs*lws[col+0]+lbs[col+0])*z0.x);
    w[1]=f2bf(((y[j+1]-mu)*rs*lws[col+1]+lbs[col+1])*z0.y);
    w[2]=f2bf(((y[j+2]-mu)*rs*lws[col+2]+lbs[col+2])*z0.z);
    w[3]=f2bf(((y[j+3]-mu)*rs*lws[col+3]+lbs[col+3])*z0.w);
    w[4]=f2bf(((y[j+4]-mu)*rs*lws[col+4]+lbs[col+4])*z1.x);
    w[5]=f2bf(((y[j+5]-mu)*rs*lws[col+5]+lbs[col+5])*z1.y);
    w[6]=f2bf(((y[j+6]-mu)*rs*lws[col+6]+lbs[col+6])*z1.z);
    w[7]=f2bf(((y[j+7]-mu)*rs*lws[col+7]+lbs[col+7])*z1.w);
    int g=col>>3;
    *(u16x8*)&Ald[((size_t)g*64+r)*8]=w;
  }
  __syncthreads();
  const int wv=tid>>6, lane=tid&63, l15=lane&15, l4=lane>>4;
  f32x4 acc[6];
  #pragma unroll
  for(int nt=0;nt<6;nt++){ f32x4 zz={0.f,0.f,0.f,0.f}; acc[nt]=zz; }
  #pragma unroll
  for(int ks=0;ks<6;ks++){
    const int g=ks*4+l4;
    bf16x8 a=*(const bf16x8*)&Ald[(size_t)(g*64+wv*16+l15)*8];
    #pragma unroll
    for(int nt=0;nt<6;nt++){
      bf16x8 bfr=*(const bf16x8*)&Wo[((size_t)(nt*24+g)*16+l15)*8];
      acc[nt]=__builtin_amdgcn_mfma_f32_16x16x32_bf16(a,bfr,acc[nt],0,0,0);
    }
  }
  const int rowb=m0+wv*16+l4*4;
  #pragma unroll
  for(int nt=0;nt<6;nt++){
    int col=nt*16+l15;
    #pragma unroll
    for(int r2=0;r2<4;r2++){
      out[(size_t)(rowb+r2)*96+col]=acc[nt][r2];
    }
  }
}

extern "C" void kernel_launch(void* const* d_in, const int* in_sizes, int n_in,
                              void* d_out, int out_size, void* d_ws, size_t ws_size,
                              hipStream_t stream){
  const f32* x  =(const f32*)d_in[0];
  const f32* ipw=(const f32*)d_in[1];
  const f32* cw =(const f32*)d_in[2];
  const f32* cb =(const f32*)d_in[3];
  const f32* xpw=(const f32*)d_in[4];
  const f32* alg=(const f32*)d_in[5];
  const f32* dsw=(const f32*)d_in[6];
  const f32* dtb=(const f32*)d_in[7];
  const f32* lw =(const f32*)d_in[8];
  const f32* lb =(const f32*)d_in[9];
  const f32* opw=(const f32*)d_in[10];
  f32* out=(f32*)d_out;
  f32* ws=(f32*)d_ws;

  f32* xh_raw=ws;               // 6291456 floats (reused as ym0)
  f32* z     =ws+ 6291456;      // 6291456
  f32* xh    =ws+12582912;      // 6291456
  f32* dt_sp =ws+18874368;      //  786432
  f32* Bg    =ws+19660800;      // 2097152
  f32* Cg    =ws+21757952;      // 2097152
  f32* S     =ws+23855104;      // 6291456
  f32* ach   =ws+30146560;      //   12288
  f32* ym1   =ws+30158848;      // 6291456
  unsigned short* Wx=(unsigned short*)(ws+36450304);   // 30720 u16
  unsigned short* Wi=(unsigned short*)(ws+36465664);   // 36864 u16
  unsigned short* Wo=(unsigned short*)(ws+36484096);   // 18432 u16
  f32* Dsum  =ws+36493312;      //     192
  unsigned short* xhb=(unsigned short*)(ws+36493504);  // 6291456 u16 = 3145728 f32
  f32* ym0=xh_raw;

  k_wcvt_all<<<43,256,0,stream>>>(xpw,ipw,opw,dsw,Wx,Wi,Wo,Dsum);
  k_inproj<<<1024,256,0,stream>>>(x,Wi,xh_raw,z);
  k_conv<<<6144,256,0,stream>>>(xh_raw,cw,cb,xh,xhb);
  k_xdbl<<<1024,256,0,stream>>>(xhb,Wx,dtb,dt_sp,Bg,Cg);
  k_chunk1<<<dim3(64,4,8),384,0,stream>>>(xhb,Bg,dt_sp,alg,S,ach);
  k_scan<<<384,256,0,stream>>>(S,ach);
  k_chunk2<<<dim3(64,8,2),768,0,stream>>>(xhb,Bg,Cg,dt_sp,S,alg,ym0,ym1);
  k_outproj<<<512,256,0,stream>>>(ym0,ym1,xh,Dsum,z,lw,lb,Wo,out);
}